// Round 15
// baseline (927.531 us; speedup 1.0000x reference)
//
#include <hip/hip_runtime.h>
#include <hip/hip_bf16.h>
#include <cstddef>

// Problem constants (Prdnet_3324304687823)
#define NN    8192
#define EE    131072
#define BB    256
#define F_AT  92
#define DD    256
#define HH    8
#define HDIM  32
#define LL    6
#define FCD   512

typedef __hip_bfloat16 bf16;
typedef __attribute__((ext_vector_type(8))) __bf16 bf16x8;
typedef __attribute__((ext_vector_type(4))) float f32x4;

__device__ __forceinline__ float to_f(float x) { return x; }
__device__ __forceinline__ float to_f(bf16 x) { return __bfloat162float(x); }
__device__ __forceinline__ float bfu(unsigned short u) {
    return __uint_as_float(((unsigned)u) << 16);
}
__device__ __forceinline__ unsigned short bfbits(float x) {
    bf16 h = __float2bfloat16(x);
    return *(unsigned short*)&h;
}
__device__ __forceinline__ void store_v(float* p, float v) { *p = v; }
__device__ __forceinline__ void store_v(bf16* p, float v) { *p = __float2bfloat16(v); }

__device__ __forceinline__ float4 load4(const float* p) { return *(const float4*)p; }
__device__ __forceinline__ float4 load4(const bf16* p) {
    const ushort4 r = *(const ushort4*)p;
    return make_float4(bfu(r.x), bfu(r.y), bfu(r.z), bfu(r.w));
}

__device__ __forceinline__ void store_f4(float* p, const float4& f) {
    *(float4*)p = f;
}
__device__ __forceinline__ void store_f4(bf16* p, const float4& f) {
    ushort4 u = {bfbits(f.x), bfbits(f.y), bfbits(f.z), bfbits(f.w)};
    *(ushort4*)p = u;
}

__device__ __forceinline__ bf16x8 ld8(const bf16* p) { return *(const bf16x8*)p; }
__device__ __forceinline__ bf16x8 ld8(const float* p) {
    const float4 f0 = *(const float4*)p;
    const float4 f1 = *(const float4*)(p + 4);
    bf16x8 r;
    r[0] = (__bf16)f0.x; r[1] = (__bf16)f0.y; r[2] = (__bf16)f0.z; r[3] = (__bf16)f0.w;
    r[4] = (__bf16)f1.x; r[5] = (__bf16)f1.y; r[6] = (__bf16)f1.z; r[7] = (__bf16)f1.w;
    return r;
}

// async global->LDS, 16 B per lane; LDS dest = wave-uniform base + lane*16
__device__ __forceinline__ void async_copy16(const void* g, void* l) {
    __builtin_amdgcn_global_load_lds(
        (const __attribute__((address_space(1))) unsigned int*)g,
        (__attribute__((address_space(3))) unsigned int*)l, 16, 0, 0);
}

// ---------------------------------------------------------------------------
// Batched weight transpose: out[midx][n][k] = (bf16) src[midx][k][n]
// midx: 0=rw1 1=rw2 2=rw3 3=aw2, then per layer l: 4+5l+{0:q,1:k,2:v,3:e,4:o}
// R15: within each layer's qkv family (s<3), the K and V weight ROWS are
// written to INTERLEAVED destinations (chunk j of [256..768) = k[4j..4j+3] |
// v[4j..4j+3]) so the qkv GEMM emits the packed layout attn wants, with
// perfectly coalesced writes. Map: k col c -> 256+(c>>2)*8+(c&3),
//                                  v col c -> 256+(c>>2)*8+4+(c&3)  (bijective).
// Slots 34..39 are the combined rw3@We weights (filled by combine_w3e).
// ---------------------------------------------------------------------------
__global__ __launch_bounds__(256) void transpose_weights(
    const float* __restrict__ rw1, const float* __restrict__ rw2,
    const float* __restrict__ rw3, const float* __restrict__ aw2,
    const float* __restrict__ Wq, const float* __restrict__ Wk,
    const float* __restrict__ Wv, const float* __restrict__ We,
    const float* __restrict__ Wo, __bf16* __restrict__ out)
{
    __shared__ float tile[64][65];
    const int midx = blockIdx.y;
    const float* src;
    int fam = 0, s = 0;
    if (midx == 0) src = rw1;
    else if (midx == 1) src = rw2;
    else if (midx == 2) src = rw3;
    else if (midx == 3) src = aw2;
    else {
        fam = (midx - 4) / 5; s = (midx - 4) % 5;
        const float* bases[5] = {Wq, Wk, Wv, We, Wo};
        src = bases[s] + (size_t)fam * 65536;
    }
    const bool isqkv = (midx >= 4) && (s < 3);
    __bf16* dstb = isqkv ? (out + (size_t)(4 + 5 * fam) * 65536)
                         : (out + (size_t)midx * 65536);
    const int k0 = (blockIdx.x >> 2) * 64;
    const int n0 = (blockIdx.x & 3) * 64;
    const int c = threadIdx.x & 63;
    const int r0 = threadIdx.x >> 6;
#pragma unroll
    for (int p = 0; p < 16; ++p) {
        const int r = r0 + p * 4;
        tile[r][c] = src[(size_t)(k0 + r) * 256 + n0 + c];
    }
    __syncthreads();
#pragma unroll
    for (int p = 0; p < 16; ++p) {
        const int n = r0 + p * 4;
        const int gr = n0 + n;
        int row = gr;
        if (isqkv) {
            if (s == 1)      row = 256 + ((gr >> 2) << 3) + (gr & 3);
            else if (s == 2) row = 256 + ((gr >> 2) << 3) + 4 + (gr & 3);
        }
        dstb[(size_t)row * 256 + k0 + c] = (__bf16)tile[c][n];
    }
}

// pack per-layer [bq|bk-interleaved-bv] -> qkvb[l*768 + ...] (same map as
// transpose_weights' qkv family)
__global__ __launch_bounds__(256) void pack_qkv_bias(
    const float* __restrict__ bq, const float* __restrict__ bk,
    const float* __restrict__ bv, float* __restrict__ out)
{
    const int i = blockIdx.x * 256 + threadIdx.x;
    if (i >= LL * 768) return;
    const int l = i / 768, r = i % 768;
    float val; int pos;
    if (r < 256)      { val = bq[l * 256 + r];        pos = r; }
    else if (r < 512) { const int c = r - 256; val = bk[l * 256 + c];
                        pos = 256 + ((c >> 2) << 3) + (c & 3); }
    else              { const int c = r - 512; val = bv[l * 256 + c];
                        pos = 256 + ((c >> 2) << 3) + 4 + (c & 3); }
    out[l * 768 + pos] = val;
}

// ---------------------------------------------------------------------------
// combine_w3e: Wt_out[l][n][k] = bf16( sum_m rw3[k][m] * We[l][m][n] )
// ---------------------------------------------------------------------------
__global__ __launch_bounds__(256) void combine_w3e(
    const float* __restrict__ rw3, const float* __restrict__ We,
    __bf16* __restrict__ Wt_out)
{
    __shared__ float As[16][65];
    __shared__ float Ws[16][65];
    const int l = blockIdx.z;
    const float* W = We + (size_t)l * 65536;
    __bf16* dst = Wt_out + (size_t)l * 65536;
    const int m0 = blockIdx.x * 64;   // k index of combined weight
    const int n0 = blockIdx.y * 64;
    const int tid = threadIdx.x;
    const int tx = tid & 15, ty = tid >> 4;
    float acc[4][4] = {};

    for (int k0 = 0; k0 < 256; k0 += 16) {
        {
            const int ar = tid >> 2;
            const int ac = (tid & 3) * 4;
#pragma unroll
            for (int j = 0; j < 4; ++j)
                As[ac + j][ar] = rw3[(size_t)(m0 + ar) * 256 + k0 + ac + j];
        }
        {
            const int wr = tid >> 4;
            const int wc = (tid & 15) * 4;
#pragma unroll
            for (int j = 0; j < 4; ++j)
                Ws[wr][wc + j] = W[(size_t)(k0 + wr) * 256 + n0 + wc + j];
        }
        __syncthreads();
#pragma unroll
        for (int kk = 0; kk < 16; ++kk) {
            float a[4], b[4];
#pragma unroll
            for (int i = 0; i < 4; ++i) a[i] = As[kk][ty * 4 + i];
#pragma unroll
            for (int j = 0; j < 4; ++j) b[j] = Ws[kk][tx * 4 + j];
#pragma unroll
            for (int i = 0; i < 4; ++i)
#pragma unroll
                for (int j = 0; j < 4; ++j) acc[i][j] += a[i] * b[j];
        }
        __syncthreads();
    }
#pragma unroll
    for (int i = 0; i < 4; ++i) {
        const int gk = m0 + ty * 4 + i;
#pragma unroll
        for (int j = 0; j < 4; ++j) {
            const int gn = n0 + tx * 4 + j;
            dst[(size_t)gn * 256 + gk] = (__bf16)acc[i][j];  // transposed store
        }
    }
}

// be_c[l][n] = sum_m rb3[m] * We[l][m][n] + be[l][n]
__global__ __launch_bounds__(256) void combine_bias(
    const float* __restrict__ rb3, const float* __restrict__ We,
    const float* __restrict__ be, float* __restrict__ out)
{
    const int l = blockIdx.x;
    const int n = threadIdx.x;
    const float* W = We + (size_t)l * 65536;
    float s = be[l * 256 + n];
    for (int m = 0; m < 256; ++m) s += rb3[m] * W[m * 256 + n];
    out[l * 256 + n] = s;
}

// ---------------------------------------------------------------------------
// Fused MFMA GEMM + LayerNorm + SiLU: C = silu(LN(A@W + bias)), Nn=K=256.
// 64x256 tile, both-sides XOR-swizzle, 4 blocks/CU. Coalesced LDS epilogue.
// ---------------------------------------------------------------------------
__global__ __launch_bounds__(256) void mfma_gemm_ln(
    const bf16* __restrict__ A, const __bf16* __restrict__ Wt,
    const float* __restrict__ bias, const float* __restrict__ g,
    const float* __restrict__ b, bf16* __restrict__ C, int do_silu)
{
    __shared__ __align__(16) __bf16 As[64 * 64];
    __shared__ __align__(16) __bf16 Bs[256 * 64];
    const int tid = threadIdx.x;
    const int m0 = blockIdx.x * 64;
    const int wave = tid >> 6, lane = tid & 63;
    const int lm = lane & 15, lq = lane >> 4;
    const int lrow = lane >> 3;
    const int lcolsw = ((lane & 7) ^ lrow) * 8;   // pre-swizzled source col-group

    f32x4 acc[16] = {};

    for (int k0 = 0; k0 < 256; k0 += 64) {
#pragma unroll
        for (int p = 0; p < 2; ++p) {
            const int rbase = wave * 16 + p * 8;   // multiple of 8 -> row&7 == lrow
            async_copy16(A + (size_t)(m0 + rbase + lrow) * 256 + k0 + lcolsw,
                         As + rbase * 64);
        }
#pragma unroll
        for (int p = 0; p < 8; ++p) {
            const int rbase = wave * 64 + p * 8;
            async_copy16(Wt + (size_t)(rbase + lrow) * 256 + k0 + lcolsw,
                         Bs + rbase * 64);
        }
        __syncthreads();
#pragma unroll
        for (int ks = 0; ks < 2; ++ks) {
            const int sw = ((ks * 4 + lq) ^ (lm & 7)) * 8;  // swizzled read slot
            const bf16x8 a = *(const bf16x8*)(As + (wave * 16 + lm) * 64 + sw);
#pragma unroll
            for (int j = 0; j < 16; ++j) {
                const bf16x8 bf = *(const bf16x8*)(Bs + (j * 16 + lm) * 64 + sw);
                acc[j] = __builtin_amdgcn_mfma_f32_16x16x32_bf16(a, bf, acc[j], 0, 0, 0);
            }
        }
        __syncthreads();
    }

    float gg[16], bb[16];
#pragma unroll
    for (int j = 0; j < 16; ++j) {
        const float bv = bias[j * 16 + lm];
        gg[j] = g[j * 16 + lm];
        bb[j] = b[j * 16 + lm];
#pragma unroll
        for (int r = 0; r < 4; ++r) acc[j][r] += bv;
    }

    // each lane holds 4 rows (lq*4+r) x 16 cols (j*16+lm); lanes sharing a row
    // differ only in low-4 bits -> shfl_xor reduce over lm. Results staged to
    // Bs (reused as [64][256] bf16), then one contiguous coalesced write.
#pragma unroll
    for (int r = 0; r < 4; ++r) {
        float s = 0.f, q = 0.f;
#pragma unroll
        for (int j = 0; j < 16; ++j) { const float v = acc[j][r]; s += v; q += v * v; }
#pragma unroll
        for (int msk = 1; msk < 16; msk <<= 1) {
            s += __shfl_xor(s, msk);
            q += __shfl_xor(q, msk);
        }
        const float mean = s * (1.f / 256.f);
        const float var = q * (1.f / 256.f) - mean * mean;
        const float rs = rsqrtf(var + 1e-5f);
        __bf16* erow = Bs + (wave * 16 + lq * 4 + r) * 256;
#pragma unroll
        for (int j = 0; j < 16; ++j) {
            float v = (acc[j][r] - mean) * rs * gg[j] + bb[j];
            if (do_silu) v = v / (1.f + __expf(-v));
            erow[j * 16 + lm] = (__bf16)v;
        }
    }
    __syncthreads();
    {
        __bf16* cbase = (__bf16*)C + (size_t)m0 * 256;   // tile is contiguous
#pragma unroll
        for (int p = 0; p < 8; ++p) {
            const int ofs = (tid + p * 256) * 8;
            *(bf16x8*)(cbase + ofs) = *(const bf16x8*)(Bs + ofs);
        }
    }
}

// ---------------------------------------------------------------------------
// ln1 variant: A = RBF matrix generated ON THE FLY from d_csr (one scalar
// per row) directly into the swizzled LDS slots (R12-verified; saves the
// 64 MB rbf buffer + a launch).
// ---------------------------------------------------------------------------
__global__ __launch_bounds__(256) void mfma_gemm_ln_rbf(
    const float* __restrict__ dcsr, const __bf16* __restrict__ Wt,
    const float* __restrict__ bias, const float* __restrict__ g,
    const float* __restrict__ b, bf16* __restrict__ C)
{
    __shared__ __align__(16) __bf16 As[64 * 64];
    __shared__ __align__(16) __bf16 Bs[256 * 64];
    const int tid = threadIdx.x;
    const int m0 = blockIdx.x * 64;
    const int wave = tid >> 6, lane = tid & 63;
    const int lm = lane & 15, lq = lane >> 4;
    const int lrow = lane >> 3;
    const int lcolsw = ((lane & 7) ^ lrow) * 8;

    const float step = 8.0f / 255.0f;
    const float gamma = 1.0f / (step * step);

    float dv[2];
#pragma unroll
    for (int p = 0; p < 2; ++p)
        dv[p] = dcsr[m0 + wave * 16 + p * 8 + lrow];

    f32x4 acc[16] = {};

    for (int k0 = 0; k0 < 256; k0 += 64) {
#pragma unroll
        for (int p = 0; p < 2; ++p) {
            const int r = wave * 16 + p * 8 + lrow;
            __bf16* dst8 = As + r * 64 + (lane & 7) * 8;
            const int cbase = k0 + lcolsw;
#pragma unroll
            for (int j = 0; j < 8; ++j) {
                const float t = dv[p] - (float)(cbase + j) * step;
                dst8[j] = (__bf16)__expf(-gamma * t * t);
            }
        }
#pragma unroll
        for (int p = 0; p < 8; ++p) {
            const int rbase = wave * 64 + p * 8;
            async_copy16(Wt + (size_t)(rbase + lrow) * 256 + k0 + lcolsw,
                         Bs + rbase * 64);
        }
        __syncthreads();
#pragma unroll
        for (int ks = 0; ks < 2; ++ks) {
            const int sw = ((ks * 4 + lq) ^ (lm & 7)) * 8;
            const bf16x8 a = *(const bf16x8*)(As + (wave * 16 + lm) * 64 + sw);
#pragma unroll
            for (int j = 0; j < 16; ++j) {
                const bf16x8 bf = *(const bf16x8*)(Bs + (j * 16 + lm) * 64 + sw);
                acc[j] = __builtin_amdgcn_mfma_f32_16x16x32_bf16(a, bf, acc[j], 0, 0, 0);
            }
        }
        __syncthreads();
    }

    float gg[16], bb[16];
#pragma unroll
    for (int j = 0; j < 16; ++j) {
        const float bv = bias[j * 16 + lm];
        gg[j] = g[j * 16 + lm];
        bb[j] = b[j * 16 + lm];
#pragma unroll
        for (int r = 0; r < 4; ++r) acc[j][r] += bv;
    }

#pragma unroll
    for (int r = 0; r < 4; ++r) {
        float s = 0.f, q = 0.f;
#pragma unroll
        for (int j = 0; j < 16; ++j) { const float v = acc[j][r]; s += v; q += v * v; }
#pragma unroll
        for (int msk = 1; msk < 16; msk <<= 1) {
            s += __shfl_xor(s, msk);
            q += __shfl_xor(q, msk);
        }
        const float mean = s * (1.f / 256.f);
        const float var = q * (1.f / 256.f) - mean * mean;
        const float rs = rsqrtf(var + 1e-5f);
        __bf16* erow = Bs + (wave * 16 + lq * 4 + r) * 256;
#pragma unroll
        for (int j = 0; j < 16; ++j) {
            float v = (acc[j][r] - mean) * rs * gg[j] + bb[j];
            v = v / (1.f + __expf(-v));   // silu (always on for ln1)
            erow[j * 16 + lm] = (__bf16)v;
        }
    }
    __syncthreads();
    {
        __bf16* cbase = (__bf16*)C + (size_t)m0 * 256;
#pragma unroll
        for (int p = 0; p < 8; ++p) {
            const int ofs = (tid + p * 256) * 8;
            *(bf16x8*)(cbase + ofs) = *(const bf16x8*)(Bs + ofs);
        }
    }
}

// ---------------------------------------------------------------------------
// Fused out-projection: node = LN(A@Wt + bias; g,b) + node (residual, fp32
// in-place). A fp32 (msg), register-staged; B async-staged. 64x256 tile.
// ---------------------------------------------------------------------------
__global__ __launch_bounds__(256) void mfma_gemm_ln_res(
    const float* __restrict__ A, const __bf16* __restrict__ Wt,
    const float* __restrict__ bias, const float* __restrict__ g,
    const float* __restrict__ b, float* __restrict__ node)
{
    __shared__ __align__(16) __bf16 As[64 * 72];   // padded: 2-way max (free)
    __shared__ __align__(16) __bf16 Bs[256 * 64];
    const int tid = threadIdx.x;
    const int m0 = blockIdx.x * 64;
    const int wave = tid >> 6, lane = tid & 63;
    const int lm = lane & 15, lq = lane >> 4;
    const int lrow = lane >> 3;
    const int lcolsw = ((lane & 7) ^ lrow) * 8;

    f32x4 acc[16] = {};
    const int srow = tid >> 3;          // 0..31
    const int scol = (tid & 7) * 8;

    for (int k0 = 0; k0 < 256; k0 += 64) {
#pragma unroll
        for (int p = 0; p < 2; ++p) {
            const int r = srow + 32 * p;
            *(bf16x8*)(As + r * 72 + scol) = ld8(A + (size_t)(m0 + r) * 256 + k0 + scol);
        }
#pragma unroll
        for (int p = 0; p < 8; ++p) {
            const int rbase = wave * 64 + p * 8;   // multiple of 8 -> row&7 == lrow
            async_copy16(Wt + (size_t)(rbase + lrow) * 256 + k0 + lcolsw,
                         Bs + rbase * 64);
        }
        __syncthreads();
#pragma unroll
        for (int ks = 0; ks < 2; ++ks) {
            const int sw = ((ks * 4 + lq) ^ (lm & 7)) * 8;
            const bf16x8 a = *(const bf16x8*)(As + (wave * 16 + lm) * 72 + ks * 32 + lq * 8);
#pragma unroll
            for (int j = 0; j < 16; ++j) {
                const bf16x8 bf = *(const bf16x8*)(Bs + (j * 16 + lm) * 64 + sw);
                acc[j] = __builtin_amdgcn_mfma_f32_16x16x32_bf16(a, bf, acc[j], 0, 0, 0);
            }
        }
        __syncthreads();
    }

    float gg[16], bb[16];
#pragma unroll
    for (int j = 0; j < 16; ++j) {
        const float bv = bias[j * 16 + lm];
        gg[j] = g[j * 16 + lm];
        bb[j] = b[j * 16 + lm];
#pragma unroll
        for (int r = 0; r < 4; ++r) acc[j][r] += bv;
    }

#pragma unroll
    for (int r = 0; r < 4; ++r) {
        float s = 0.f, q = 0.f;
#pragma unroll
        for (int j = 0; j < 16; ++j) { const float v = acc[j][r]; s += v; q += v * v; }
#pragma unroll
        for (int msk = 1; msk < 16; msk <<= 1) {
            s += __shfl_xor(s, msk);
            q += __shfl_xor(q, msk);
        }
        const float mean = s * (1.f / 256.f);
        const float var = q * (1.f / 256.f) - mean * mean;
        const float rs = rsqrtf(var + 1e-5f);
        float* crow = node + (size_t)(m0 + wave * 16 + lq * 4 + r) * 256;
#pragma unroll
        for (int j = 0; j < 16; ++j) {
            const float v = (acc[j][r] - mean) * rs * gg[j] + bb[j];
            crow[j * 16 + lm] += v;   // node = LN(...) + node_old (one lane per elem)
        }
    }
}

// ---------------------------------------------------------------------------
// ee GEMM (A bf16, C bf16): C = A@W + bias, Wt[Nn][K] bf16.
// 128x128 tile, BK=64, 4 waves 2x2, both-sides XOR-swizzle on staging.
// XCD-GROUPED 1D swizzle (R8 verified: FETCH 131->34 MB).
// Epilogue LDS XOR-swizzled (R9: conflicts 2.1e6 -> 0).
// Requires: (M/128) % 8 == 0, Nn % 128 == 0.
// ---------------------------------------------------------------------------
__global__ __launch_bounds__(256) void mfma_gemm_ee(
    const bf16* __restrict__ A, const __bf16* __restrict__ Wt,
    const float* __restrict__ bias, bf16* __restrict__ C,
    int M, int Nn, int K)
{
    __shared__ __align__(16) __bf16 smem[128 * 128];   // staging + epilogue
    __bf16* As = smem;              // [128][64]
    __bf16* Bs = smem + 128 * 64;   // [128][64]
    const int tid = threadIdx.x;

    // XCD-grouped block mapping (1D grid)
    const int nt_n = Nn >> 7;                 // n-tiles per m-panel
    const int xcd = blockIdx.x & 7;
    const int local = blockIdx.x >> 3;
    const int per_xcd = (M >> 7) >> 3;        // m-panels per XCD
    const int m0 = (xcd * per_xcd + local / nt_n) * 128;
    const int n0 = (local % nt_n) * 128;

    const int wave = tid >> 6, lane = tid & 63;
    const int wm = (wave & 1) * 64, wn = (wave >> 1) * 64;
    const int lm = lane & 15, lq = lane >> 4;
    const int lrow = lane >> 3;
    const int lcolsw = ((lane & 7) ^ lrow) * 8;   // pre-swizzled source col-group

    f32x4 acc[4][4] = {};

    for (int k0 = 0; k0 < K; k0 += 64) {
#pragma unroll
        for (int p = 0; p < 4; ++p) {
            const int rbase = wave * 32 + p * 8;
            async_copy16(A  + (size_t)(m0 + rbase + lrow) * K + k0 + lcolsw,
                         As + rbase * 64);
            async_copy16(Wt + (size_t)(n0 + rbase + lrow) * K + k0 + lcolsw,
                         Bs + rbase * 64);
        }
        __syncthreads();
#pragma unroll
        for (int ks = 0; ks < 2; ++ks) {
            const int sw = ((ks * 4 + lq) ^ (lm & 7)) * 8;
            bf16x8 a[4], b[4];
#pragma unroll
            for (int i = 0; i < 4; ++i) {
                a[i] = *(const bf16x8*)(As + (wm + i * 16 + lm) * 64 + sw);
                b[i] = *(const bf16x8*)(Bs + (wn + i * 16 + lm) * 64 + sw);
            }
#pragma unroll
            for (int i = 0; i < 4; ++i)
#pragma unroll
                for (int j = 0; j < 4; ++j)
                    acc[i][j] = __builtin_amdgcn_mfma_f32_16x16x32_bf16(
                        a[i], b[j], acc[i][j], 0, 0, 0);
        }
        __syncthreads();   // also fences last staging reads before epilogue
    }

    // epilogue: acc (+bias) -> smem[128][128] bf16 (XOR-swizzled rows)
    //           -> coalesced global write (inverse XOR on read)
#pragma unroll
    for (int i = 0; i < 4; ++i) {
        const int rl = wm + i * 16 + lq * 4;
#pragma unroll
        for (int j = 0; j < 4; ++j) {
            const int cl = wn + j * 16 + lm;
            const float bb = bias ? bias[n0 + cl] : 0.f;
#pragma unroll
            for (int r = 0; r < 4; ++r) {
                const int row = rl + r;
                smem[row * 128 + (cl ^ ((row & 7) << 3))] =
                    (__bf16)(acc[i][j][r] + bb);
            }
        }
    }
    __syncthreads();
#pragma unroll
    for (int p = 0; p < 8; ++p) {
        const int ch = tid + p * 256;          // 2048 chunks of 8 bf16
        const int row = ch >> 4;
        const int gcol = ch & 15;
        const int sg = gcol ^ (row & 7);       // swizzled source group
        *(bf16x8*)((__bf16*)C + (size_t)(m0 + row) * Nn + n0 + gcol * 8) =
            *(const bf16x8*)(smem + row * 128 + sg * 8);
    }
}

// ---------------------------------------------------------------------------
// MFMA GEMM, 64x128 tile (fp32 A, register-staged): C = A@Wt + bias.
// 4 waves as 2x2 of 32x64 sub-tiles, acc[2][4], 28 KB LDS. (R14 verified:
// qkv 768 blocks = 3/CU, occupancy fix, -29 us total.)
// ---------------------------------------------------------------------------
template <typename CT>
__global__ __launch_bounds__(256) void mfma_gemm64(
    const float* __restrict__ A, const __bf16* __restrict__ Wt,
    const float* __restrict__ bias, CT* __restrict__ C,
    int M, int Nn, int K)
{
    __shared__ __align__(16) __bf16 As[64 * 72];
    __shared__ __align__(16) __bf16 Bs[128 * 72];
    const int tid = threadIdx.x;
    const int m0 = blockIdx.x * 64;
    const int n0 = blockIdx.y * 128;
    const int wave = tid >> 6, lane = tid & 63;
    const int wm = (wave & 1) * 32, wn = (wave >> 1) * 64;
    const int lm = lane & 15, lq = lane >> 4;

    f32x4 acc[2][4] = {};

    const int srow = tid >> 3;          // 0..31
    const int scol = (tid & 7) * 8;

    for (int k0 = 0; k0 < K; k0 += 64) {
#pragma unroll
        for (int p = 0; p < 2; ++p) {
            const int r = srow + 32 * p;
            *(bf16x8*)(As + r * 72 + scol) =
                ld8(A + (size_t)(m0 + r) * K + k0 + scol);
        }
#pragma unroll
        for (int p = 0; p < 4; ++p) {
            const int r = srow + 32 * p;
            *(bf16x8*)(Bs + r * 72 + scol) =
                *(const bf16x8*)(Wt + (size_t)(n0 + r) * K + k0 + scol);
        }
        __syncthreads();
#pragma unroll
        for (int ks = 0; ks < 2; ++ks) {
            bf16x8 a[2], b[4];
#pragma unroll
            for (int i = 0; i < 2; ++i)
                a[i] = *(const bf16x8*)(As + (wm + i * 16 + lm) * 72 + ks * 32 + lq * 8);
#pragma unroll
            for (int j = 0; j < 4; ++j)
                b[j] = *(const bf16x8*)(Bs + (wn + j * 16 + lm) * 72 + ks * 32 + lq * 8);
#pragma unroll
            for (int i = 0; i < 2; ++i)
#pragma unroll
                for (int j = 0; j < 4; ++j)
                    acc[i][j] = __builtin_amdgcn_mfma_f32_16x16x32_bf16(
                        a[i], b[j], acc[i][j], 0, 0, 0);
        }
        __syncthreads();
    }

#pragma unroll
    for (int i = 0; i < 2; ++i) {
        const int gm = m0 + wm + i * 16 + lq * 4;
#pragma unroll
        for (int j = 0; j < 4; ++j) {
            const int gn = n0 + wn + j * 16 + lm;
            const float bv = bias ? bias[gn] : 0.f;
#pragma unroll
            for (int r = 0; r < 4; ++r)
                store_v(&C[(size_t)(gm + r) * Nn + gn], acc[i][j][r] + bv);
        }
    }
}

// ---------------------------------------------------------------------------
// Fallback vector GEMM (K=92 aw1, fc head). Optional cntdiv: A-row gm is
// divided by max(cnt[gm],1) on load (fuses the pooled-mean division).
// ---------------------------------------------------------------------------
template <typename AT, typename CT>
__global__ __launch_bounds__(256) void gemm_bias(
    const AT* __restrict__ A, const float* __restrict__ W,
    const float* __restrict__ bias, CT* __restrict__ C,
    int M, int Nn, int K, const float* __restrict__ cntdiv)
{
    __shared__ float As[16][65];
    __shared__ float Ws[16][65];
    const int m0 = blockIdx.x * 64;
    const int n0 = blockIdx.y * 64;
    const int tid = threadIdx.x;
    const int tx = tid & 15, ty = tid >> 4;
    float acc[4][4] = {};

    for (int k0 = 0; k0 < K; k0 += 16) {
        {
            const int ar = tid >> 2;
            const int ac = (tid & 3) * 4;
            const int gm = m0 + ar;
            float inv = 1.f;
            if (cntdiv && gm < M) {
                float cc = cntdiv[gm];
                if (cc < 1.f) cc = 1.f;
                inv = 1.f / cc;
            }
#pragma unroll
            for (int j = 0; j < 4; ++j) {
                const int gk = k0 + ac + j;
                float v = 0.f;
                if (gm < M && gk < K) v = to_f(A[(size_t)gm * K + gk]) * inv;
                As[ac + j][ar] = v;
            }
        }
        {
            const int wr = tid >> 4;
            const int wc = (tid & 15) * 4;
            const int gk = k0 + wr;
#pragma unroll
            for (int j = 0; j < 4; ++j) {
                float v = 0.f;
                if (gk < K) v = W[(size_t)gk * Nn + n0 + wc + j];
                Ws[wr][wc + j] = v;
            }
        }
        __syncthreads();
#pragma unroll
        for (int kk = 0; kk < 16; ++kk) {
            float a[4], b[4];
#pragma unroll
            for (int i = 0; i < 4; ++i) a[i] = As[kk][ty * 4 + i];
#pragma unroll
            for (int j = 0; j < 4; ++j) b[j] = Ws[kk][tx * 4 + j];
#pragma unroll
            for (int i = 0; i < 4; ++i)
#pragma unroll
                for (int j = 0; j < 4; ++j) acc[i][j] += a[i] * b[j];
        }
        __syncthreads();
    }
#pragma unroll
    for (int i = 0; i < 4; ++i) {
        const int gm = m0 + ty * 4 + i;
        if (gm >= M) continue;
#pragma unroll
        for (int j = 0; j < 4; ++j) {
            const int gn = n0 + tx * 4 + j;
            float v = acc[i][j];
            if (bias) v += bias[gn];
            store_v(&C[(size_t)gm * Nn + gn], v);
        }
    }
}

// ---------------------------------------------------------------------------
// Row LayerNorm (+opt SiLU via __expf, +opt fp32 residual). Node-side only.
// ---------------------------------------------------------------------------
template <typename XT, typename YT>
__global__ __launch_bounds__(256) void ln_act_kernel(
    const XT* __restrict__ X, YT* __restrict__ Y,
    const float* __restrict__ g, const float* __restrict__ b,
    const float* __restrict__ resid, int rows, int do_silu)
{
    const int wave = threadIdx.x >> 6;
    const int lane = threadIdx.x & 63;
    const int r = blockIdx.x * 4 + wave;
    if (r >= rows) return;
    const float4 x = load4(X + (size_t)r * DD + lane * 4);
    float s = x.x + x.y + x.z + x.w;
    float q = x.x * x.x + x.y * x.y + x.z * x.z + x.w * x.w;
    for (int off = 32; off; off >>= 1) {
        s += __shfl_down(s, off);
        q += __shfl_down(q, off);
    }
    s = __shfl(s, 0);
    q = __shfl(q, 0);
    const float mean = s * (1.f / 256.f);
    const float var = q * (1.f / 256.f) - mean * mean;
    const float rs = rsqrtf(var + 1e-5f);
    const int c = lane * 4;
    float xs[4] = {x.x, x.y, x.z, x.w};
    float out[4];
#pragma unroll
    for (int i = 0; i < 4; ++i) {
        float v = (xs[i] - mean) * rs * g[c + i] + b[c + i];
        if (do_silu) v = v / (1.f + __expf(-v));
        out[i] = v;
    }
    if (resid) {
        const float4 rv = load4(resid + (size_t)r * DD + c);
        out[0] += rv.x; out[1] += rv.y; out[2] += rv.z; out[3] += rv.w;
    }
    store_f4(Y + (size_t)r * DD + c, make_float4(out[0], out[1], out[2], out[3]));
}

// ---------------------------------------------------------------------------
// CSR build: histogram, block-scan, fill (emits CSR-ordered src AND CSR
// edge lengths dcsr — dlen fused here)
// ---------------------------------------------------------------------------
__global__ __launch_bounds__(256) void deg_kernel(
    const int* __restrict__ dst, int* __restrict__ deg)
{
    const int e = blockIdx.x * 256 + threadIdx.x;
    if (e < EE) atomicAdd(&deg[dst[e]], 1);
}

__global__ __launch_bounds__(256) void csr_scan(
    const int* __restrict__ deg, int* __restrict__ rowptr)
{
    __shared__ int part[256];
    const int t = threadIdx.x;
    int local[32];
    int s = 0;
#pragma unroll
    for (int i = 0; i < 32; ++i) { local[i] = deg[t * 32 + i]; s += local[i]; }
    part[t] = s;
    __syncthreads();
    if (t == 0) {
        int run = 0;
        for (int i = 0; i < 256; ++i) { const int v = part[i]; part[i] = run; run += v; }
    }
    __syncthreads();
    int run = part[t];
#pragma unroll
    for (int i = 0; i < 32; ++i) { rowptr[t * 32 + i] = run; run += local[i]; }
    if (t == 255) rowptr[NN] = run;
}

__global__ __launch_bounds__(256) void fill_kernel(
    const int* __restrict__ src, const int* __restrict__ dst,
    const float* __restrict__ ea, const int* __restrict__ rowptr,
    int* __restrict__ fill, int* __restrict__ eid,
    int* __restrict__ srcc, float* __restrict__ dcsr)
{
    const int e = blockIdx.x * 256 + threadIdx.x;
    if (e >= EE) return;
    const int d = dst[e];
    const int pos = atomicAdd(&fill[d], 1);
    const int q = rowptr[d] + pos;
    eid[q] = e;
    srcc[q] = src[e];
    const float ax = ea[e * 3 + 0];
    const float ay = ea[e * 3 + 1];
    const float az = ea[e * 3 + 2];
    dcsr[q] = sqrtf(ax * ax + ay * ay + az * az);
}

// ---------------------------------------------------------------------------
// Single-pass fused attention (flash-style online softmax), no atomics.
// CSR-ordered ee (sequential), 4 waves/node (R10-verified optimum).
// R15: qkv K/V stored INTERLEAVED (chunk j = k[4j..4j+3]|v[4j..4j+3]) via
// weight-column permutation at prep -> ONE 16B gather load per edge per lane
// instead of two 8B loads (3 loads -> 2, double transaction width).
// ---------------------------------------------------------------------------
__global__ __launch_bounds__(256) void attn_kernel(
    const bf16* __restrict__ qkv, const bf16* __restrict__ ee, int estride,
    const int* __restrict__ rowptr, const int* __restrict__ srcc,
    float* __restrict__ msg)
{
    const int n = blockIdx.x;
    const int tid = threadIdx.x;
    const int wave = tid >> 6, lane = tid & 63;
    const int e0 = rowptr[n];
    const int deg = rowptr[n + 1] - e0;

    if (deg == 0) {  // uniform branch
        msg[(size_t)n * DD + tid] = 0.f;
        return;
    }

    __shared__ float wm[4][HH];
    __shared__ float wl[4][HH];
    __shared__ float wacc[4][DD];

    const float4 qreg = load4(qkv + (size_t)n * 768 + lane * 4);

    float m = -3.402823466e38f, l = 0.f;
    float4 acc = {0.f, 0.f, 0.f, 0.f};

    int j = wave;
    bf16x8 kvp = {};                      // k[0..3]|v[0..3] packed
    float4 ev = {0.f, 0.f, 0.f, 0.f};
    if (j < deg) {
        const int e = e0 + j;
        const bf16* srow = qkv + (size_t)srcc[e] * 768;
        kvp = ld8(srow + 256 + lane * 8);
        ev = load4(ee + (size_t)e * estride + lane * 4);
    }
    while (j < deg) {
        const int jn = j + 4;
        bf16x8 kvp2 = {};
        float4 ev2 = {0.f, 0.f, 0.f, 0.f};
        if (jn < deg) {
            const int e2 = e0 + jn;
            const bf16* srow2 = qkv + (size_t)srcc[e2] * 768;
            kvp2 = ld8(srow2 + 256 + lane * 8);
            ev2 = load4(ee + (size_t)e2 * estride + lane * 4);
        }
        const float kx = (float)kvp[0], ky = (float)kvp[1];
        const float kz = (float)kvp[2], kw = (float)kvp[3];
        const float vx = (float)kvp[4], vy = (float)kvp[5];
        const float vz = (float)kvp[6], vw = (float)kvp[7];
        float p = qreg.x * (kx + ev.x) + qreg.y * (ky + ev.y) +
                  qreg.z * (kz + ev.z) + qreg.w * (kw + ev.w);
        p += __shfl_down(p, 4);
        p += __shfl_down(p, 2);
        p += __shfl_down(p, 1);
        const float s = __shfl(p, lane & 56) * 0.17677669529663687f;
        const float mnew = fmaxf(m, s);
        const float scale = __expf(m - mnew);
        const float pe = __expf(s - mnew);
        l = l * scale + pe;
        acc.x = acc.x * scale + pe * (vx + ev.x);
        acc.y = acc.y * scale + pe * (vy + ev.y);
        acc.z = acc.z * scale + pe * (vz + ev.z);
        acc.w = acc.w * scale + pe * (vw + ev.w);
        m = mnew;
        kvp = kvp2; ev = ev2;
        j = jn;
    }

    if ((lane & 7) == 0) { wm[wave][lane >> 3] = m; wl[wave][lane >> 3] = l; }
    *(float4*)(&wacc[wave][lane * 4]) = acc;
    __syncthreads();

    {
        const int c = tid, h = tid >> 5;
        float M = wm[0][h];
#pragma unroll
        for (int i = 1; i < 4; ++i) M = fmaxf(M, wm[i][h]);
        float L = 0.f, num = 0.f;
#pragma unroll
        for (int i = 0; i < 4; ++i) {
            const float sc = __expf(wm[i][h] - M);
            L += wl[i][h] * sc;
            num += wacc[i][c] * sc;
        }
        msg[(size_t)n * DD + c] = num / (L + 1e-16f);
    }
}

__global__ __launch_bounds__(256) void zero_kernel(float* __restrict__ p, int n)
{
    const int i = blockIdx.x * 256 + threadIdx.x;
    if (i < n) p[i] = 0.f;
}

__global__ __launch_bounds__(256) void pool_kernel(
    const float* __restrict__ node, const int* __restrict__ batch,
    float* __restrict__ sums, float* __restrict__ cnt)
{
    const int n = blockIdx.x;
    const int c = threadIdx.x;
    const int b = batch[n];
    atomicAdd(&sums[b * DD + c], node[(size_t)n * DD + c]);
    if (c == 0) atomicAdd(&cnt[b], 1.0f);
}

__global__ __launch_bounds__(64) void final_kernel(
    const float* __restrict__ fc, const float* __restrict__ fow,
    const float* __restrict__ fob, float* __restrict__ out)
{
    const int b = blockIdx.x;
    const int lane = threadIdx.x;
    float s = 0.f;
#pragma unroll
    for (int i = lane; i < FCD; i += 64) s += fc[(size_t)b * FCD + i] * fow[i];
    for (int off = 32; off; off >>= 1) s += __shfl_down(s, off);
    if (lane == 0) out[b] = s + fob[0];
}

// ---------------------------------------------------------------------------
extern "C" void kernel_launch(void* const* d_in, const int* in_sizes, int n_in,
                              void* d_out, int out_size, void* d_ws,
                              size_t ws_size, hipStream_t stream)
{
    const float* x         = (const float*)d_in[0];
    const float* edge_attr = (const float*)d_in[1];
    const int*   eidx      = (const int*)d_in[2];
    const int*   batch     = (const int*)d_in[3];
    const float* aw1 = (const float*)d_in[4];
    const float* ab1 = (const float*)d_in[5];
    const float* ag1 = (const float*)d_in[6];
    const float* abt1 = (const float*)d_in[7];
    const float* aw2 = (const float*)d_in[8];
    const float* ab2 = (const float*)d_in[9];
    const float* rw1 = (const float*)d_in[10];
    const float* rb1 = (const float*)d_in[11];
    const float* rg1 = (const float*)d_in[12];
    const float* rbt1 = (const float*)d_in[13];
    const float* rw2 = (const float*)d_in[14];
    const float* rb2 = (const float*)d_in[15];
    const float* rg2 = (const float*)d_in[16];
    const float* rbt2 = (const float*)d_in[17];
    const float* rw3 = (const float*)d_in[18];
    const float* rb3 = (const float*)d_in[19];
    const float* Wq = (const float*)d_in[20];
    const float* bq = (const float*)d_in[21];
    const float* Wk = (const float*)d_in[22];
    const float* bk = (const float*)d_in[23];
    const float* Wv = (const float*)d_in[24];
    const float* bv = (const float*)d_in[25];
    const float* We_ = (const float*)d_in[26];
    const float* be_ = (const float*)d_in[27];
    const float* Wo = (const float*)d_in[28];
    const float* bo = (const float*)d_in[29];
    const float* lng = (const float*)d_in[30];
    const float* lnb = (const float*)d_in[31];
    const float* fw1 = (const float*)d_in[32];
    const float* fb1 = (const float*)d_in[33];
    const float* fow = (const float*)d_in[34];
    const float* fob = (const float*)d_in[35];

    const int* src = eidx;
    const int* dst = eidx + EE;

    // workspace carve-up. Fixed buffers first; the ee slab last with adaptive
    // group size G in {6,3,2,1} (ws_size ~268MB -> G=2 in practice).
    char* w = (char*)d_ws;
    size_t off = 0;
    auto alloc = [&](size_t bytes) -> void* {
        void* p = w + off;
        off += (bytes + 255) & ~(size_t)255;
        return p;
    };
    bf16* t_buf = (bf16*)alloc((size_t)EE * DD * 2);   // 64 MB — persistent edge (CSR order)
    float* node = (float*)alloc((size_t)NN * DD * 4);  // 8 MB
    bf16*  qkv  = (bf16*)alloc((size_t)NN * 768 * 2);  // 12 MB
    float* msg  = (float*)alloc((size_t)NN * DD * 4);  // 8 MB
    float* outb = (float*)alloc((size_t)NN * DD * 4);  // 8 MB
    int* deg    = (int*)alloc((size_t)NN * 4);         // | contiguous zero
    int* fillc  = (int*)alloc((size_t)NN * 4);         // | region (deg+fill)
    int* rowptr = (int*)alloc((size_t)(NN + 1) * 4);
    int* eid    = (int*)alloc((size_t)EE * 4);         // 512 KB
    int* srcc   = (int*)alloc((size_t)EE * 4);         // 512 KB — CSR-ordered src
    float* dcsr = (float*)alloc((size_t)EE * 4);       // 512 KB — CSR edge lengths
    float* sums  = (float*)alloc((size_t)BB * DD * 4); // | contiguous with cnt
    float* cnt   = (float*)alloc((size_t)BB * 4);      // |
    float* fc    = (float*)alloc((size_t)BB * FCD * 4);
    __bf16* Wt  = (__bf16*)alloc((size_t)40 * 65536 * 2);  // 5.25 MB (34 + 6 combined)
    float* qkvb = (float*)alloc((size_t)LL * 768 * 4);     // 18 KB
    float* be_c = (float*)alloc((size_t)LL * 256 * 4);     // 6 KB — combined ee bias

    const size_t avail = (off <= ws_size) ? ws_size - off : 0;
    int G = 1;
    if      (avail >= (size_t)EE * (6 * DD) * 2 + 256) G = 6;
    else if (avail >= (size_t)EE * (3 * DD) * 2 + 256) G = 3;
    else if (avail >= (size_t)EE * (2 * DD) * 2 + 256) G = 2;
    bf16* e_slab = (bf16*)alloc((size_t)EE * (G * DD) * 2);  // also MLP ping buffer
    (void)n_in; (void)in_sizes; (void)out_size;

    const dim3 blk(256);
    auto WT = [&](int i) -> const __bf16* { return Wt + (size_t)i * 65536; };

    // ---- one-time prep: transposes, combined rw3@We, bias pack, CSR ----
    hipLaunchKernelGGL(transpose_weights, dim3(16, 34), blk, 0, stream,
                       rw1, rw2, rw3, aw2, Wq, Wk, Wv, We_, Wo, Wt);
    hipLaunchKernelGGL(combine_w3e, dim3(4, 4, LL), blk, 0, stream, rw3, We_, Wt + (size_t)34 * 65536);
    hipLaunchKernelGGL(combine_bias, dim3(LL), blk, 0, stream, rb3, We_, be_, be_c);
    hipLaunchKernelGGL(pack_qkv_bias, dim3((LL * 768 + 255) / 256), blk, 0, stream, bq, bk, bv, qkvb);
    hipLaunchKernelGGL(zero_kernel, dim3((2 * NN + 255) / 256), blk, 0, stream, (float*)deg, 2 * NN);
    hipLaunchKernelGGL(deg_kernel, dim3(EE / 256), blk, 0, stream, dst, deg);
    hipLaunchKernelGGL(csr_scan, dim3(1), blk, 0, stream, deg, rowptr);
    hipLaunchKernelGGL(fill_kernel, dim3(EE / 256), blk, 0, stream, src, dst, edge_attr, rowptr, fillc, eid, srcc, dcsr);

    // ---- edge MLP in CSR order: d_csr -> [RBF-gen GEMM+LN+SiLU] -> [GEMM+LN+SiLU]
    hipLaunchKernelGGL(mfma_gemm_ln_rbf, dim3(EE / 64), blk, 0, stream, dcsr, WT(0), rb1, rg1, rbt1, e_slab);
    hipLaunchKernelGGL(mfma_gemm_ln, dim3(EE / 64), blk, 0, stream, e_slab, WT(1), rb2, rg2, rbt2, t_buf, 1);
    // t_buf now holds the persistent edge features (pre-rw3), CSR row order

    // ---- atom embedding: x@aw1 -> LN+SiLU -> @aw2 ----
    {
        dim3 gn64(NN / 64, DD / 64);
        hipLaunchKernelGGL((gemm_bias<float, float>), gn64, blk, 0, stream, x, aw1, ab1, outb, NN, DD, F_AT, (const float*)nullptr);
        hipLaunchKernelGGL((ln_act_kernel<float, float>), dim3(NN / 4), blk, 0, stream, outb, outb, ag1, abt1, (const float*)nullptr, NN, 1);
        hipLaunchKernelGGL((mfma_gemm64<float>), dim3(NN / 64, DD / 128), blk, 0, stream, outb, WT(3), ab2, node, NN, DD, DD);
    }

    // ---- L attention layers ----
    for (int l = 0; l < LL; ++l) {
        const size_t bo_ = (size_t)l * DD;
        hipLaunchKernelGGL((mfma_gemm64<bf16>), dim3(NN / 64, 768 / 128), blk, 0, stream,
                           node, WT(4 + 5 * l), qkvb + (size_t)l * 768, qkv, NN, 768, DD);
        if (l % G == 0) {
            // ee for layers l..l+G-1 (1D XCD-grouped grid)
            const int nblocks = (EE / 128) * ((G * DD) / 128);
            hipLaunchKernelGGL(mfma_gemm_ee, dim3(nblocks), blk, 0, stream,
                               t_buf, WT(34 + l), be_c + (size_t)l * 256, e_slab, EE, G * DD, DD);
        }
        const bf16* ee_l = e_slab + (size_t)(l % G) * DD;
        hipLaunchKernelGGL(attn_kernel, dim3(NN), blk, 0, stream, qkv, ee_l, G * DD, rowptr, srcc, msg);
        // fused: node = LN(msg@Wo + bo) + node
        hipLaunchKernelGGL(mfma_gemm_ln_res, dim3(NN / 64), blk, 0, stream,
                           msg, WT(8 + 5 * l), bo + bo_, lng + bo_, lnb + bo_, node);
    }

    // ---- pooling + FC head (pooled-mean division fused into fc GEMM) ----
    const int PZ = BB * DD + BB;
    hipLaunchKernelGGL(zero_kernel, dim3((PZ + 255) / 256), blk, 0, stream, sums, PZ);
    hipLaunchKernelGGL(pool_kernel, dim3(NN), blk, 0, stream, node, batch, sums, cnt);
    {
        dim3 gf(BB / 64, FCD / 64);
        hipLaunchKernelGGL((gemm_bias<float, float>), gf, blk, 0, stream, sums, fw1, fb1, fc, BB, FCD, DD, cnt);
    }
    hipLaunchKernelGGL(final_kernel, dim3(BB), dim3(64), 0, stream, fc, fow, fob, (float*)d_out);
}

// Round 16
// 923.098 us; speedup vs baseline: 1.0048x; 1.0048x over previous
//
#include <hip/hip_runtime.h>
#include <hip/hip_bf16.h>
#include <cstddef>

// Problem constants (Prdnet_3324304687823)
#define NN    8192
#define EE    131072
#define BB    256
#define F_AT  92
#define DD    256
#define HH    8
#define HDIM  32
#define LL    6
#define FCD   512

typedef __hip_bfloat16 bf16;
typedef __attribute__((ext_vector_type(8))) __bf16 bf16x8;
typedef __attribute__((ext_vector_type(4))) float f32x4;

__device__ __forceinline__ float to_f(float x) { return x; }
__device__ __forceinline__ float to_f(bf16 x) { return __bfloat162float(x); }
__device__ __forceinline__ float bfu(unsigned short u) {
    return __uint_as_float(((unsigned)u) << 16);
}
__device__ __forceinline__ unsigned short bfbits(float x) {
    bf16 h = __float2bfloat16(x);
    return *(unsigned short*)&h;
}
__device__ __forceinline__ void store_v(float* p, float v) { *p = v; }
__device__ __forceinline__ void store_v(bf16* p, float v) { *p = __float2bfloat16(v); }

__device__ __forceinline__ float4 load4(const float* p) { return *(const float4*)p; }
__device__ __forceinline__ float4 load4(const bf16* p) {
    const ushort4 r = *(const ushort4*)p;
    return make_float4(bfu(r.x), bfu(r.y), bfu(r.z), bfu(r.w));
}

__device__ __forceinline__ void store_f4(float* p, const float4& f) {
    *(float4*)p = f;
}
__device__ __forceinline__ void store_f4(bf16* p, const float4& f) {
    ushort4 u = {bfbits(f.x), bfbits(f.y), bfbits(f.z), bfbits(f.w)};
    *(ushort4*)p = u;
}

__device__ __forceinline__ bf16x8 ld8(const bf16* p) { return *(const bf16x8*)p; }
__device__ __forceinline__ bf16x8 ld8(const float* p) {
    const float4 f0 = *(const float4*)p;
    const float4 f1 = *(const float4*)(p + 4);
    bf16x8 r;
    r[0] = (__bf16)f0.x; r[1] = (__bf16)f0.y; r[2] = (__bf16)f0.z; r[3] = (__bf16)f0.w;
    r[4] = (__bf16)f1.x; r[5] = (__bf16)f1.y; r[6] = (__bf16)f1.z; r[7] = (__bf16)f1.w;
    return r;
}

// async global->LDS, 16 B per lane; LDS dest = wave-uniform base + lane*16
__device__ __forceinline__ void async_copy16(const void* g, void* l) {
    __builtin_amdgcn_global_load_lds(
        (const __attribute__((address_space(1))) unsigned int*)g,
        (__attribute__((address_space(3))) unsigned int*)l, 16, 0, 0);
}

// ---------------------------------------------------------------------------
// Batched weight transpose: out[midx][n][k] = (bf16) src[midx][k][n]
// midx: 0=rw1 1=rw2 2=rw3 3=aw2, then per layer l: 4+5l+{0:q,1:k,2:v,3:e,4:o}
// K/V weight rows interleaved (R15-verified correct): k col c ->
// 256+(c>>2)*8+(c&3), v col c -> 256+(c>>2)*8+4+(c&3).
// Slots 34..39 are the combined rw3@We weights (filled by combine_w3e).
// ---------------------------------------------------------------------------
__global__ __launch_bounds__(256) void transpose_weights(
    const float* __restrict__ rw1, const float* __restrict__ rw2,
    const float* __restrict__ rw3, const float* __restrict__ aw2,
    const float* __restrict__ Wq, const float* __restrict__ Wk,
    const float* __restrict__ Wv, const float* __restrict__ We,
    const float* __restrict__ Wo, __bf16* __restrict__ out)
{
    __shared__ float tile[64][65];
    const int midx = blockIdx.y;
    const float* src;
    int fam = 0, s = 0;
    if (midx == 0) src = rw1;
    else if (midx == 1) src = rw2;
    else if (midx == 2) src = rw3;
    else if (midx == 3) src = aw2;
    else {
        fam = (midx - 4) / 5; s = (midx - 4) % 5;
        const float* bases[5] = {Wq, Wk, Wv, We, Wo};
        src = bases[s] + (size_t)fam * 65536;
    }
    const bool isqkv = (midx >= 4) && (s < 3);
    __bf16* dstb = isqkv ? (out + (size_t)(4 + 5 * fam) * 65536)
                         : (out + (size_t)midx * 65536);
    const int k0 = (blockIdx.x >> 2) * 64;
    const int n0 = (blockIdx.x & 3) * 64;
    const int c = threadIdx.x & 63;
    const int r0 = threadIdx.x >> 6;
#pragma unroll
    for (int p = 0; p < 16; ++p) {
        const int r = r0 + p * 4;
        tile[r][c] = src[(size_t)(k0 + r) * 256 + n0 + c];
    }
    __syncthreads();
#pragma unroll
    for (int p = 0; p < 16; ++p) {
        const int n = r0 + p * 4;
        const int gr = n0 + n;
        int row = gr;
        if (isqkv) {
            if (s == 1)      row = 256 + ((gr >> 2) << 3) + (gr & 3);
            else if (s == 2) row = 256 + ((gr >> 2) << 3) + 4 + (gr & 3);
        }
        dstb[(size_t)row * 256 + k0 + c] = (__bf16)tile[c][n];
    }
}

// pack per-layer [bq|bk-interleaved-bv] -> qkvb[l*768 + ...]
__global__ __launch_bounds__(256) void pack_qkv_bias(
    const float* __restrict__ bq, const float* __restrict__ bk,
    const float* __restrict__ bv, float* __restrict__ out)
{
    const int i = blockIdx.x * 256 + threadIdx.x;
    if (i >= LL * 768) return;
    const int l = i / 768, r = i % 768;
    float val; int pos;
    if (r < 256)      { val = bq[l * 256 + r];        pos = r; }
    else if (r < 512) { const int c = r - 256; val = bk[l * 256 + c];
                        pos = 256 + ((c >> 2) << 3) + (c & 3); }
    else              { const int c = r - 512; val = bv[l * 256 + c];
                        pos = 256 + ((c >> 2) << 3) + 4 + (c & 3); }
    out[l * 768 + pos] = val;
}

// ---------------------------------------------------------------------------
// combine_w3e: Wt_out[l][n][k] = bf16( sum_m rw3[k][m] * We[l][m][n] )
// ---------------------------------------------------------------------------
__global__ __launch_bounds__(256) void combine_w3e(
    const float* __restrict__ rw3, const float* __restrict__ We,
    __bf16* __restrict__ Wt_out)
{
    __shared__ float As[16][65];
    __shared__ float Ws[16][65];
    const int l = blockIdx.z;
    const float* W = We + (size_t)l * 65536;
    __bf16* dst = Wt_out + (size_t)l * 65536;
    const int m0 = blockIdx.x * 64;   // k index of combined weight
    const int n0 = blockIdx.y * 64;
    const int tid = threadIdx.x;
    const int tx = tid & 15, ty = tid >> 4;
    float acc[4][4] = {};

    for (int k0 = 0; k0 < 256; k0 += 16) {
        {
            const int ar = tid >> 2;
            const int ac = (tid & 3) * 4;
#pragma unroll
            for (int j = 0; j < 4; ++j)
                As[ac + j][ar] = rw3[(size_t)(m0 + ar) * 256 + k0 + ac + j];
        }
        {
            const int wr = tid >> 4;
            const int wc = (tid & 15) * 4;
#pragma unroll
            for (int j = 0; j < 4; ++j)
                Ws[wr][wc + j] = W[(size_t)(k0 + wr) * 256 + n0 + wc + j];
        }
        __syncthreads();
#pragma unroll
        for (int kk = 0; kk < 16; ++kk) {
            float a[4], b[4];
#pragma unroll
            for (int i = 0; i < 4; ++i) a[i] = As[kk][ty * 4 + i];
#pragma unroll
            for (int j = 0; j < 4; ++j) b[j] = Ws[kk][tx * 4 + j];
#pragma unroll
            for (int i = 0; i < 4; ++i)
#pragma unroll
                for (int j = 0; j < 4; ++j) acc[i][j] += a[i] * b[j];
        }
        __syncthreads();
    }
#pragma unroll
    for (int i = 0; i < 4; ++i) {
        const int gk = m0 + ty * 4 + i;
#pragma unroll
        for (int j = 0; j < 4; ++j) {
            const int gn = n0 + tx * 4 + j;
            dst[(size_t)gn * 256 + gk] = (__bf16)acc[i][j];  // transposed store
        }
    }
}

// be_c[l][n] = sum_m rb3[m] * We[l][m][n] + be[l][n]
__global__ __launch_bounds__(256) void combine_bias(
    const float* __restrict__ rb3, const float* __restrict__ We,
    const float* __restrict__ be, float* __restrict__ out)
{
    const int l = blockIdx.x;
    const int n = threadIdx.x;
    const float* W = We + (size_t)l * 65536;
    float s = be[l * 256 + n];
    for (int m = 0; m < 256; ++m) s += rb3[m] * W[m * 256 + n];
    out[l * 256 + n] = s;
}

// ---------------------------------------------------------------------------
// Fused MFMA GEMM + LayerNorm + SiLU: C = silu(LN(A@W + bias)), Nn=K=256.
// 64x256 tile, both-sides XOR-swizzle, 4 blocks/CU. Coalesced LDS epilogue.
// ---------------------------------------------------------------------------
__global__ __launch_bounds__(256) void mfma_gemm_ln(
    const bf16* __restrict__ A, const __bf16* __restrict__ Wt,
    const float* __restrict__ bias, const float* __restrict__ g,
    const float* __restrict__ b, bf16* __restrict__ C, int do_silu)
{
    __shared__ __align__(16) __bf16 As[64 * 64];
    __shared__ __align__(16) __bf16 Bs[256 * 64];
    const int tid = threadIdx.x;
    const int m0 = blockIdx.x * 64;
    const int wave = tid >> 6, lane = tid & 63;
    const int lm = lane & 15, lq = lane >> 4;
    const int lrow = lane >> 3;
    const int lcolsw = ((lane & 7) ^ lrow) * 8;   // pre-swizzled source col-group

    f32x4 acc[16] = {};

    for (int k0 = 0; k0 < 256; k0 += 64) {
#pragma unroll
        for (int p = 0; p < 2; ++p) {
            const int rbase = wave * 16 + p * 8;   // multiple of 8 -> row&7 == lrow
            async_copy16(A + (size_t)(m0 + rbase + lrow) * 256 + k0 + lcolsw,
                         As + rbase * 64);
        }
#pragma unroll
        for (int p = 0; p < 8; ++p) {
            const int rbase = wave * 64 + p * 8;
            async_copy16(Wt + (size_t)(rbase + lrow) * 256 + k0 + lcolsw,
                         Bs + rbase * 64);
        }
        __syncthreads();
#pragma unroll
        for (int ks = 0; ks < 2; ++ks) {
            const int sw = ((ks * 4 + lq) ^ (lm & 7)) * 8;  // swizzled read slot
            const bf16x8 a = *(const bf16x8*)(As + (wave * 16 + lm) * 64 + sw);
#pragma unroll
            for (int j = 0; j < 16; ++j) {
                const bf16x8 bf = *(const bf16x8*)(Bs + (j * 16 + lm) * 64 + sw);
                acc[j] = __builtin_amdgcn_mfma_f32_16x16x32_bf16(a, bf, acc[j], 0, 0, 0);
            }
        }
        __syncthreads();
    }

    float gg[16], bb[16];
#pragma unroll
    for (int j = 0; j < 16; ++j) {
        const float bv = bias[j * 16 + lm];
        gg[j] = g[j * 16 + lm];
        bb[j] = b[j * 16 + lm];
#pragma unroll
        for (int r = 0; r < 4; ++r) acc[j][r] += bv;
    }

    // each lane holds 4 rows (lq*4+r) x 16 cols (j*16+lm); lanes sharing a row
    // differ only in low-4 bits -> shfl_xor reduce over lm. Results staged to
    // Bs (reused as [64][256] bf16), then one contiguous coalesced write.
#pragma unroll
    for (int r = 0; r < 4; ++r) {
        float s = 0.f, q = 0.f;
#pragma unroll
        for (int j = 0; j < 16; ++j) { const float v = acc[j][r]; s += v; q += v * v; }
#pragma unroll
        for (int msk = 1; msk < 16; msk <<= 1) {
            s += __shfl_xor(s, msk);
            q += __shfl_xor(q, msk);
        }
        const float mean = s * (1.f / 256.f);
        const float var = q * (1.f / 256.f) - mean * mean;
        const float rs = rsqrtf(var + 1e-5f);
        __bf16* erow = Bs + (wave * 16 + lq * 4 + r) * 256;
#pragma unroll
        for (int j = 0; j < 16; ++j) {
            float v = (acc[j][r] - mean) * rs * gg[j] + bb[j];
            if (do_silu) v = v / (1.f + __expf(-v));
            erow[j * 16 + lm] = (__bf16)v;
        }
    }
    __syncthreads();
    {
        __bf16* cbase = (__bf16*)C + (size_t)m0 * 256;   // tile is contiguous
#pragma unroll
        for (int p = 0; p < 8; ++p) {
            const int ofs = (tid + p * 256) * 8;
            *(bf16x8*)(cbase + ofs) = *(const bf16x8*)(Bs + ofs);
        }
    }
}

// ---------------------------------------------------------------------------
// ln1 variant: A = RBF matrix generated ON THE FLY from d_csr (one scalar
// per row) directly into the swizzled LDS slots (R12-verified).
// ---------------------------------------------------------------------------
__global__ __launch_bounds__(256) void mfma_gemm_ln_rbf(
    const float* __restrict__ dcsr, const __bf16* __restrict__ Wt,
    const float* __restrict__ bias, const float* __restrict__ g,
    const float* __restrict__ b, bf16* __restrict__ C)
{
    __shared__ __align__(16) __bf16 As[64 * 64];
    __shared__ __align__(16) __bf16 Bs[256 * 64];
    const int tid = threadIdx.x;
    const int m0 = blockIdx.x * 64;
    const int wave = tid >> 6, lane = tid & 63;
    const int lm = lane & 15, lq = lane >> 4;
    const int lrow = lane >> 3;
    const int lcolsw = ((lane & 7) ^ lrow) * 8;

    const float step = 8.0f / 255.0f;
    const float gamma = 1.0f / (step * step);

    float dv[2];
#pragma unroll
    for (int p = 0; p < 2; ++p)
        dv[p] = dcsr[m0 + wave * 16 + p * 8 + lrow];

    f32x4 acc[16] = {};

    for (int k0 = 0; k0 < 256; k0 += 64) {
#pragma unroll
        for (int p = 0; p < 2; ++p) {
            const int r = wave * 16 + p * 8 + lrow;
            __bf16* dst8 = As + r * 64 + (lane & 7) * 8;
            const int cbase = k0 + lcolsw;
#pragma unroll
            for (int j = 0; j < 8; ++j) {
                const float t = dv[p] - (float)(cbase + j) * step;
                dst8[j] = (__bf16)__expf(-gamma * t * t);
            }
        }
#pragma unroll
        for (int p = 0; p < 8; ++p) {
            const int rbase = wave * 64 + p * 8;
            async_copy16(Wt + (size_t)(rbase + lrow) * 256 + k0 + lcolsw,
                         Bs + rbase * 64);
        }
        __syncthreads();
#pragma unroll
        for (int ks = 0; ks < 2; ++ks) {
            const int sw = ((ks * 4 + lq) ^ (lm & 7)) * 8;
            const bf16x8 a = *(const bf16x8*)(As + (wave * 16 + lm) * 64 + sw);
#pragma unroll
            for (int j = 0; j < 16; ++j) {
                const bf16x8 bf = *(const bf16x8*)(Bs + (j * 16 + lm) * 64 + sw);
                acc[j] = __builtin_amdgcn_mfma_f32_16x16x32_bf16(a, bf, acc[j], 0, 0, 0);
            }
        }
        __syncthreads();
    }

    float gg[16], bb[16];
#pragma unroll
    for (int j = 0; j < 16; ++j) {
        const float bv = bias[j * 16 + lm];
        gg[j] = g[j * 16 + lm];
        bb[j] = b[j * 16 + lm];
#pragma unroll
        for (int r = 0; r < 4; ++r) acc[j][r] += bv;
    }

#pragma unroll
    for (int r = 0; r < 4; ++r) {
        float s = 0.f, q = 0.f;
#pragma unroll
        for (int j = 0; j < 16; ++j) { const float v = acc[j][r]; s += v; q += v * v; }
#pragma unroll
        for (int msk = 1; msk < 16; msk <<= 1) {
            s += __shfl_xor(s, msk);
            q += __shfl_xor(q, msk);
        }
        const float mean = s * (1.f / 256.f);
        const float var = q * (1.f / 256.f) - mean * mean;
        const float rs = rsqrtf(var + 1e-5f);
        __bf16* erow = Bs + (wave * 16 + lq * 4 + r) * 256;
#pragma unroll
        for (int j = 0; j < 16; ++j) {
            float v = (acc[j][r] - mean) * rs * gg[j] + bb[j];
            v = v / (1.f + __expf(-v));   // silu (always on for ln1)
            erow[j * 16 + lm] = (__bf16)v;
        }
    }
    __syncthreads();
    {
        __bf16* cbase = (__bf16*)C + (size_t)m0 * 256;
#pragma unroll
        for (int p = 0; p < 8; ++p) {
            const int ofs = (tid + p * 256) * 8;
            *(bf16x8*)(cbase + ofs) = *(const bf16x8*)(Bs + ofs);
        }
    }
}

// ---------------------------------------------------------------------------
// Fused out-projection: node = LN(A@Wt + bias; g,b) + node (residual, fp32
// in-place). A now bf16 (msg written bf16 by attn — identical numerics since
// staging converted fp32->bf16 anyway). 64x256 tile.
// ---------------------------------------------------------------------------
__global__ __launch_bounds__(256) void mfma_gemm_ln_res(
    const bf16* __restrict__ A, const __bf16* __restrict__ Wt,
    const float* __restrict__ bias, const float* __restrict__ g,
    const float* __restrict__ b, float* __restrict__ node)
{
    __shared__ __align__(16) __bf16 As[64 * 72];   // padded: 2-way max (free)
    __shared__ __align__(16) __bf16 Bs[256 * 64];
    const int tid = threadIdx.x;
    const int m0 = blockIdx.x * 64;
    const int wave = tid >> 6, lane = tid & 63;
    const int lm = lane & 15, lq = lane >> 4;
    const int lrow = lane >> 3;
    const int lcolsw = ((lane & 7) ^ lrow) * 8;

    f32x4 acc[16] = {};
    const int srow = tid >> 3;          // 0..31
    const int scol = (tid & 7) * 8;

    for (int k0 = 0; k0 < 256; k0 += 64) {
#pragma unroll
        for (int p = 0; p < 2; ++p) {
            const int r = srow + 32 * p;
            *(bf16x8*)(As + r * 72 + scol) = ld8(A + (size_t)(m0 + r) * 256 + k0 + scol);
        }
#pragma unroll
        for (int p = 0; p < 8; ++p) {
            const int rbase = wave * 64 + p * 8;   // multiple of 8 -> row&7 == lrow
            async_copy16(Wt + (size_t)(rbase + lrow) * 256 + k0 + lcolsw,
                         Bs + rbase * 64);
        }
        __syncthreads();
#pragma unroll
        for (int ks = 0; ks < 2; ++ks) {
            const int sw = ((ks * 4 + lq) ^ (lm & 7)) * 8;
            const bf16x8 a = *(const bf16x8*)(As + (wave * 16 + lm) * 72 + ks * 32 + lq * 8);
#pragma unroll
            for (int j = 0; j < 16; ++j) {
                const bf16x8 bf = *(const bf16x8*)(Bs + (j * 16 + lm) * 64 + sw);
                acc[j] = __builtin_amdgcn_mfma_f32_16x16x32_bf16(a, bf, acc[j], 0, 0, 0);
            }
        }
        __syncthreads();
    }

    float gg[16], bb[16];
#pragma unroll
    for (int j = 0; j < 16; ++j) {
        const float bv = bias[j * 16 + lm];
        gg[j] = g[j * 16 + lm];
        bb[j] = b[j * 16 + lm];
#pragma unroll
        for (int r = 0; r < 4; ++r) acc[j][r] += bv;
    }

#pragma unroll
    for (int r = 0; r < 4; ++r) {
        float s = 0.f, q = 0.f;
#pragma unroll
        for (int j = 0; j < 16; ++j) { const float v = acc[j][r]; s += v; q += v * v; }
#pragma unroll
        for (int msk = 1; msk < 16; msk <<= 1) {
            s += __shfl_xor(s, msk);
            q += __shfl_xor(q, msk);
        }
        const float mean = s * (1.f / 256.f);
        const float var = q * (1.f / 256.f) - mean * mean;
        const float rs = rsqrtf(var + 1e-5f);
        float* crow = node + (size_t)(m0 + wave * 16 + lq * 4 + r) * 256;
#pragma unroll
        for (int j = 0; j < 16; ++j) {
            const float v = (acc[j][r] - mean) * rs * gg[j] + bb[j];
            crow[j * 16 + lm] += v;   // node = LN(...) + node_old (one lane per elem)
        }
    }
}

// ---------------------------------------------------------------------------
// GRID-FUSED ee GEMM + qkv GEMM (one dispatch): blocks < nblk_ee run the
// R8-verified ee path (XCD-grouped 128x128, swizzled staging + epilogue);
// remaining 768 blocks run the R14-verified 64x128 qkv GEMM. Both inputs
// (t_buf, node) are ready at launch; attn consumes both outputs after.
// The qkv tail fills ee's occupancy slack; saves 3 dispatches + gaps.
// ---------------------------------------------------------------------------
__global__ __launch_bounds__(256) void ee_qkv_fused(
    const bf16* __restrict__ A, const __bf16* __restrict__ Wte,
    const float* __restrict__ biase, bf16* __restrict__ Ce,
    int M, int Nn, int K, int nblk_ee,
    const float* __restrict__ nodeA, const __bf16* __restrict__ Wtq,
    const float* __restrict__ biasq, bf16* __restrict__ Cq)
{
    __shared__ __align__(16) __bf16 smem[128 * 128];   // 32 KB, aliased by both roles
    const int tid = threadIdx.x;
    const int wave = tid >> 6, lane = tid & 63;
    const int lm = lane & 15, lq = lane >> 4;

    if ((int)blockIdx.x < nblk_ee) {
        // ---------------- ee role (identical to mfma_gemm_ee) ----------------
        __bf16* As = smem;              // [128][64]
        __bf16* Bs = smem + 128 * 64;   // [128][64]
        const int nt_n = Nn >> 7;
        const int xcd = blockIdx.x & 7;
        const int local = blockIdx.x >> 3;
        const int per_xcd = (M >> 7) >> 3;
        const int m0 = (xcd * per_xcd + local / nt_n) * 128;
        const int n0 = (local % nt_n) * 128;

        const int wm = (wave & 1) * 64, wn = (wave >> 1) * 64;
        const int lrow = lane >> 3;
        const int lcolsw = ((lane & 7) ^ lrow) * 8;

        f32x4 acc[4][4] = {};

        for (int k0 = 0; k0 < K; k0 += 64) {
#pragma unroll
            for (int p = 0; p < 4; ++p) {
                const int rbase = wave * 32 + p * 8;
                async_copy16(A   + (size_t)(m0 + rbase + lrow) * K + k0 + lcolsw,
                             As + rbase * 64);
                async_copy16(Wte + (size_t)(n0 + rbase + lrow) * K + k0 + lcolsw,
                             Bs + rbase * 64);
            }
            __syncthreads();
#pragma unroll
            for (int ks = 0; ks < 2; ++ks) {
                const int sw = ((ks * 4 + lq) ^ (lm & 7)) * 8;
                bf16x8 a[4], b[4];
#pragma unroll
                for (int i = 0; i < 4; ++i) {
                    a[i] = *(const bf16x8*)(As + (wm + i * 16 + lm) * 64 + sw);
                    b[i] = *(const bf16x8*)(Bs + (wn + i * 16 + lm) * 64 + sw);
                }
#pragma unroll
                for (int i = 0; i < 4; ++i)
#pragma unroll
                    for (int j = 0; j < 4; ++j)
                        acc[i][j] = __builtin_amdgcn_mfma_f32_16x16x32_bf16(
                            a[i], b[j], acc[i][j], 0, 0, 0);
            }
            __syncthreads();
        }

#pragma unroll
        for (int i = 0; i < 4; ++i) {
            const int rl = wm + i * 16 + lq * 4;
#pragma unroll
            for (int j = 0; j < 4; ++j) {
                const int cl = wn + j * 16 + lm;
                const float bb = biase ? biase[n0 + cl] : 0.f;
#pragma unroll
                for (int r = 0; r < 4; ++r) {
                    const int row = rl + r;
                    smem[row * 128 + (cl ^ ((row & 7) << 3))] =
                        (__bf16)(acc[i][j][r] + bb);
                }
            }
        }
        __syncthreads();
#pragma unroll
        for (int p = 0; p < 8; ++p) {
            const int ch = tid + p * 256;
            const int row = ch >> 4;
            const int gcol = ch & 15;
            const int sg = gcol ^ (row & 7);
            *(bf16x8*)((__bf16*)Ce + (size_t)(m0 + row) * Nn + n0 + gcol * 8) =
                *(const bf16x8*)(smem + row * 128 + sg * 8);
        }
    } else {
        // ---------------- qkv role (identical to mfma_gemm64) ----------------
        const int bq = blockIdx.x - nblk_ee;        // 0..767
        const int m0 = (bq % (NN / 64)) * 64;
        const int n0 = (bq / (NN / 64)) * 128;
        __bf16* As = smem;                 // [64][72]
        __bf16* Bs = smem + 64 * 72;       // [128][72]  (total 27648 B < 32768)

        const int wm = (wave & 1) * 32, wn = (wave >> 1) * 64;
        f32x4 acc[2][4] = {};
        const int srow = tid >> 3;
        const int scol = (tid & 7) * 8;

        for (int k0 = 0; k0 < 256; k0 += 64) {
#pragma unroll
            for (int p = 0; p < 2; ++p) {
                const int r = srow + 32 * p;
                *(bf16x8*)(As + r * 72 + scol) =
                    ld8(nodeA + (size_t)(m0 + r) * 256 + k0 + scol);
            }
#pragma unroll
            for (int p = 0; p < 4; ++p) {
                const int r = srow + 32 * p;
                *(bf16x8*)(Bs + r * 72 + scol) =
                    *(const bf16x8*)(Wtq + (size_t)(n0 + r) * 256 + k0 + scol);
            }
            __syncthreads();
#pragma unroll
            for (int ks = 0; ks < 2; ++ks) {
                bf16x8 a[2], b[4];
#pragma unroll
                for (int i = 0; i < 2; ++i)
                    a[i] = *(const bf16x8*)(As + (wm + i * 16 + lm) * 72 + ks * 32 + lq * 8);
#pragma unroll
                for (int j = 0; j < 4; ++j)
                    b[j] = *(const bf16x8*)(Bs + (wn + j * 16 + lm) * 72 + ks * 32 + lq * 8);
#pragma unroll
                for (int i = 0; i < 2; ++i)
#pragma unroll
                    for (int j = 0; j < 4; ++j)
                        acc[i][j] = __builtin_amdgcn_mfma_f32_16x16x32_bf16(
                            a[i], b[j], acc[i][j], 0, 0, 0);
            }
            __syncthreads();
        }

#pragma unroll
        for (int i = 0; i < 2; ++i) {
            const int gm = m0 + wm + i * 16 + lq * 4;
#pragma unroll
            for (int j = 0; j < 4; ++j) {
                const int gn = n0 + wn + j * 16 + lm;
                const float bv = biasq[gn];
#pragma unroll
                for (int r = 0; r < 4; ++r)
                    store_v(&Cq[(size_t)(gm + r) * 768 + gn], acc[i][j][r] + bv);
            }
        }
    }
}

// ---------------------------------------------------------------------------
// MFMA GEMM, 64x128 tile (fp32 A, register-staged): C = A@Wt + bias.
// (R14-verified; used for atom aw2 and odd-layer qkv.)
// ---------------------------------------------------------------------------
template <typename CT>
__global__ __launch_bounds__(256) void mfma_gemm64(
    const float* __restrict__ A, const __bf16* __restrict__ Wt,
    const float* __restrict__ bias, CT* __restrict__ C,
    int M, int Nn, int K)
{
    __shared__ __align__(16) __bf16 As[64 * 72];
    __shared__ __align__(16) __bf16 Bs[128 * 72];
    const int tid = threadIdx.x;
    const int m0 = blockIdx.x * 64;
    const int n0 = blockIdx.y * 128;
    const int wave = tid >> 6, lane = tid & 63;
    const int wm = (wave & 1) * 32, wn = (wave >> 1) * 64;
    const int lm = lane & 15, lq = lane >> 4;

    f32x4 acc[2][4] = {};

    const int srow = tid >> 3;          // 0..31
    const int scol = (tid & 7) * 8;

    for (int k0 = 0; k0 < K; k0 += 64) {
#pragma unroll
        for (int p = 0; p < 2; ++p) {
            const int r = srow + 32 * p;
            *(bf16x8*)(As + r * 72 + scol) =
                ld8(A + (size_t)(m0 + r) * K + k0 + scol);
        }
#pragma unroll
        for (int p = 0; p < 4; ++p) {
            const int r = srow + 32 * p;
            *(bf16x8*)(Bs + r * 72 + scol) =
                *(const bf16x8*)(Wt + (size_t)(n0 + r) * K + k0 + scol);
        }
        __syncthreads();
#pragma unroll
        for (int ks = 0; ks < 2; ++ks) {
            bf16x8 a[2], b[4];
#pragma unroll
            for (int i = 0; i < 2; ++i)
                a[i] = *(const bf16x8*)(As + (wm + i * 16 + lm) * 72 + ks * 32 + lq * 8);
#pragma unroll
            for (int j = 0; j < 4; ++j)
                b[j] = *(const bf16x8*)(Bs + (wn + j * 16 + lm) * 72 + ks * 32 + lq * 8);
#pragma unroll
            for (int i = 0; i < 2; ++i)
#pragma unroll
                for (int j = 0; j < 4; ++j)
                    acc[i][j] = __builtin_amdgcn_mfma_f32_16x16x32_bf16(
                        a[i], b[j], acc[i][j], 0, 0, 0);
        }
        __syncthreads();
    }

#pragma unroll
    for (int i = 0; i < 2; ++i) {
        const int gm = m0 + wm + i * 16 + lq * 4;
#pragma unroll
        for (int j = 0; j < 4; ++j) {
            const int gn = n0 + wn + j * 16 + lm;
            const float bv = bias ? bias[gn] : 0.f;
#pragma unroll
            for (int r = 0; r < 4; ++r)
                store_v(&C[(size_t)(gm + r) * Nn + gn], acc[i][j][r] + bv);
        }
    }
}

// ---------------------------------------------------------------------------
// Fallback vector GEMM (K=92 aw1, fc head). Optional cntdiv: A-row gm is
// divided by max(cnt[gm],1) on load (fuses the pooled-mean division).
// ---------------------------------------------------------------------------
template <typename AT, typename CT>
__global__ __launch_bounds__(256) void gemm_bias(
    const AT* __restrict__ A, const float* __restrict__ W,
    const float* __restrict__ bias, CT* __restrict__ C,
    int M, int Nn, int K, const float* __restrict__ cntdiv)
{
    __shared__ float As[16][65];
    __shared__ float Ws[16][65];
    const int m0 = blockIdx.x * 64;
    const int n0 = blockIdx.y * 64;
    const int tid = threadIdx.x;
    const int tx = tid & 15, ty = tid >> 4;
    float acc[4][4] = {};

    for (int k0 = 0; k0 < K; k0 += 16) {
        {
            const int ar = tid >> 2;
            const int ac = (tid & 3) * 4;
            const int gm = m0 + ar;
            float inv = 1.f;
            if (cntdiv && gm < M) {
                float cc = cntdiv[gm];
                if (cc < 1.f) cc = 1.f;
                inv = 1.f / cc;
            }
#pragma unroll
            for (int j = 0; j < 4; ++j) {
                const int gk = k0 + ac + j;
                float v = 0.f;
                if (gm < M && gk < K) v = to_f(A[(size_t)gm * K + gk]) * inv;
                As[ac + j][ar] = v;
            }
        }
        {
            const int wr = tid >> 4;
            const int wc = (tid & 15) * 4;
            const int gk = k0 + wr;
#pragma unroll
            for (int j = 0; j < 4; ++j) {
                float v = 0.f;
                if (gk < K) v = W[(size_t)gk * Nn + n0 + wc + j];
                Ws[wr][wc + j] = v;
            }
        }
        __syncthreads();
#pragma unroll
        for (int kk = 0; kk < 16; ++kk) {
            float a[4], b[4];
#pragma unroll
            for (int i = 0; i < 4; ++i) a[i] = As[kk][ty * 4 + i];
#pragma unroll
            for (int j = 0; j < 4; ++j) b[j] = Ws[kk][tx * 4 + j];
#pragma unroll
            for (int i = 0; i < 4; ++i)
#pragma unroll
                for (int j = 0; j < 4; ++j) acc[i][j] += a[i] * b[j];
        }
        __syncthreads();
    }
#pragma unroll
    for (int i = 0; i < 4; ++i) {
        const int gm = m0 + ty * 4 + i;
        if (gm >= M) continue;
#pragma unroll
        for (int j = 0; j < 4; ++j) {
            const int gn = n0 + tx * 4 + j;
            float v = acc[i][j];
            if (bias) v += bias[gn];
            store_v(&C[(size_t)gm * Nn + gn], v);
        }
    }
}

// ---------------------------------------------------------------------------
// Row LayerNorm (+opt SiLU via __expf, +opt fp32 residual). Node-side only.
// ---------------------------------------------------------------------------
template <typename XT, typename YT>
__global__ __launch_bounds__(256) void ln_act_kernel(
    const XT* __restrict__ X, YT* __restrict__ Y,
    const float* __restrict__ g, const float* __restrict__ b,
    const float* __restrict__ resid, int rows, int do_silu)
{
    const int wave = threadIdx.x >> 6;
    const int lane = threadIdx.x & 63;
    const int r = blockIdx.x * 4 + wave;
    if (r >= rows) return;
    const float4 x = load4(X + (size_t)r * DD + lane * 4);
    float s = x.x + x.y + x.z + x.w;
    float q = x.x * x.x + x.y * x.y + x.z * x.z + x.w * x.w;
    for (int off = 32; off; off >>= 1) {
        s += __shfl_down(s, off);
        q += __shfl_down(q, off);
    }
    s = __shfl(s, 0);
    q = __shfl(q, 0);
    const float mean = s * (1.f / 256.f);
    const float var = q * (1.f / 256.f) - mean * mean;
    const float rs = rsqrtf(var + 1e-5f);
    const int c = lane * 4;
    float xs[4] = {x.x, x.y, x.z, x.w};
    float out[4];
#pragma unroll
    for (int i = 0; i < 4; ++i) {
        float v = (xs[i] - mean) * rs * g[c + i] + b[c + i];
        if (do_silu) v = v / (1.f + __expf(-v));
        out[i] = v;
    }
    if (resid) {
        const float4 rv = load4(resid + (size_t)r * DD + c);
        out[0] += rv.x; out[1] += rv.y; out[2] += rv.z; out[3] += rv.w;
    }
    store_f4(Y + (size_t)r * DD + c, make_float4(out[0], out[1], out[2], out[3]));
}

// ---------------------------------------------------------------------------
// CSR build: histogram, block-scan, fill (emits CSR-ordered src AND CSR
// edge lengths dcsr)
// ---------------------------------------------------------------------------
__global__ __launch_bounds__(256) void deg_kernel(
    const int* __restrict__ dst, int* __restrict__ deg)
{
    const int e = blockIdx.x * 256 + threadIdx.x;
    if (e < EE) atomicAdd(&deg[dst[e]], 1);
}

__global__ __launch_bounds__(256) void csr_scan(
    const int* __restrict__ deg, int* __restrict__ rowptr)
{
    __shared__ int part[256];
    const int t = threadIdx.x;
    int local[32];
    int s = 0;
#pragma unroll
    for (int i = 0; i < 32; ++i) { local[i] = deg[t * 32 + i]; s += local[i]; }
    part[t] = s;
    __syncthreads();
    if (t == 0) {
        int run = 0;
        for (int i = 0; i < 256; ++i) { const int v = part[i]; part[i] = run; run += v; }
    }
    __syncthreads();
    int run = part[t];
#pragma unroll
    for (int i = 0; i < 32; ++i) { rowptr[t * 32 + i] = run; run += local[i]; }
    if (t == 255) rowptr[NN] = run;
}

__global__ __launch_bounds__(256) void fill_kernel(
    const int* __restrict__ src, const int* __restrict__ dst,
    const float* __restrict__ ea, const int* __restrict__ rowptr,
    int* __restrict__ fill, int* __restrict__ eid,
    int* __restrict__ srcc, float* __restrict__ dcsr)
{
    const int e = blockIdx.x * 256 + threadIdx.x;
    if (e >= EE) return;
    const int d = dst[e];
    const int pos = atomicAdd(&fill[d], 1);
    const int q = rowptr[d] + pos;
    eid[q] = e;
    srcc[q] = src[e];
    const float ax = ea[e * 3 + 0];
    const float ay = ea[e * 3 + 1];
    const float az = ea[e * 3 + 2];
    dcsr[q] = sqrtf(ax * ax + ay * ay + az * az);
}

// ---------------------------------------------------------------------------
// Single-pass fused attention (flash-style online softmax), no atomics.
// CSR-ordered ee (sequential), 4 waves/node (R10-verified optimum), packed
// 16B K|V gather (R15), bf16 msg output (identical numerics: ln_res staged
// msg through bf16 anyway).
// ---------------------------------------------------------------------------
__global__ __launch_bounds__(256) void attn_kernel(
    const bf16* __restrict__ qkv, const bf16* __restrict__ ee, int estride,
    const int* __restrict__ rowptr, const int* __restrict__ srcc,
    bf16* __restrict__ msg)
{
    const int n = blockIdx.x;
    const int tid = threadIdx.x;
    const int wave = tid >> 6, lane = tid & 63;
    const int e0 = rowptr[n];
    const int deg = rowptr[n + 1] - e0;

    if (deg == 0) {  // uniform branch
        store_v(&msg[(size_t)n * DD + tid], 0.f);
        return;
    }

    __shared__ float wm[4][HH];
    __shared__ float wl[4][HH];
    __shared__ float wacc[4][DD];

    const float4 qreg = load4(qkv + (size_t)n * 768 + lane * 4);

    float m = -3.402823466e38f, l = 0.f;
    float4 acc = {0.f, 0.f, 0.f, 0.f};

    int j = wave;
    bf16x8 kvp = {};                      // k[0..3]|v[0..3] packed
    float4 ev = {0.f, 0.f, 0.f, 0.f};
    if (j < deg) {
        const int e = e0 + j;
        const bf16* srow = qkv + (size_t)srcc[e] * 768;
        kvp = ld8(srow + 256 + lane * 8);
        ev = load4(ee + (size_t)e * estride + lane * 4);
    }
    while (j < deg) {
        const int jn = j + 4;
        bf16x8 kvp2 = {};
        float4 ev2 = {0.f, 0.f, 0.f, 0.f};
        if (jn < deg) {
            const int e2 = e0 + jn;
            const bf16* srow2 = qkv + (size_t)srcc[e2] * 768;
            kvp2 = ld8(srow2 + 256 + lane * 8);
            ev2 = load4(ee + (size_t)e2 * estride + lane * 4);
        }
        const float kx = (float)kvp[0], ky = (float)kvp[1];
        const float kz = (float)kvp[2], kw = (float)kvp[3];
        const float vx = (float)kvp[4], vy = (float)kvp[5];
        const float vz = (float)kvp[6], vw = (float)kvp[7];
        float p = qreg.x * (kx + ev.x) + qreg.y * (ky + ev.y) +
                  qreg.z * (kz + ev.z) + qreg.w * (kw + ev.w);
        p += __shfl_down(p, 4);
        p += __shfl_down(p, 2);
        p += __shfl_down(p, 1);
        const float s = __shfl(p, lane & 56) * 0.17677669529663687f;
        const float mnew = fmaxf(m, s);
        const float scale = __expf(m - mnew);
        const float pe = __expf(s - mnew);
        l = l * scale + pe;
        acc.x = acc.x * scale + pe * (vx + ev.x);
        acc.y = acc.y * scale + pe * (vy + ev.y);
        acc.z = acc.z * scale + pe * (vz + ev.z);
        acc.w = acc.w * scale + pe * (vw + ev.w);
        m = mnew;
        kvp = kvp2; ev = ev2;
        j = jn;
    }

    if ((lane & 7) == 0) { wm[wave][lane >> 3] = m; wl[wave][lane >> 3] = l; }
    *(float4*)(&wacc[wave][lane * 4]) = acc;
    __syncthreads();

    {
        const int c = tid, h = tid >> 5;
        float M = wm[0][h];
#pragma unroll
        for (int i = 1; i < 4; ++i) M = fmaxf(M, wm[i][h]);
        float L = 0.f, num = 0.f;
#pragma unroll
        for (int i = 0; i < 4; ++i) {
            const float sc = __expf(wm[i][h] - M);
            L += wl[i][h] * sc;
            num += wacc[i][c] * sc;
        }
        store_v(&msg[(size_t)n * DD + c], num / (L + 1e-16f));
    }
}

__global__ __launch_bounds__(256) void zero_kernel(float* __restrict__ p, int n)
{
    const int i = blockIdx.x * 256 + threadIdx.x;
    if (i < n) p[i] = 0.f;
}

__global__ __launch_bounds__(256) void pool_kernel(
    const float* __restrict__ node, const int* __restrict__ batch,
    float* __restrict__ sums, float* __restrict__ cnt)
{
    const int n = blockIdx.x;
    const int c = threadIdx.x;
    const int b = batch[n];
    atomicAdd(&sums[b * DD + c], node[(size_t)n * DD + c]);
    if (c == 0) atomicAdd(&cnt[b], 1.0f);
}

__global__ __launch_bounds__(64) void final_kernel(
    const float* __restrict__ fc, const float* __restrict__ fow,
    const float* __restrict__ fob, float* __restrict__ out)
{
    const int b = blockIdx.x;
    const int lane = threadIdx.x;
    float s = 0.f;
#pragma unroll
    for (int i = lane; i < FCD; i += 64) s += fc[(size_t)b * FCD + i] * fow[i];
    for (int off = 32; off; off >>= 1) s += __shfl_down(s, off);
    if (lane == 0) out[b] = s + fob[0];
}

// ---------------------------------------------------------------------------
extern "C" void kernel_launch(void* const* d_in, const int* in_sizes, int n_in,
                              void* d_out, int out_size, void* d_ws,
                              size_t ws_size, hipStream_t stream)
{
    const float* x         = (const float*)d_in[0];
    const float* edge_attr = (const float*)d_in[1];
    const int*   eidx      = (const int*)d_in[2];
    const int*   batch     = (const int*)d_in[3];
    const float* aw1 = (const float*)d_in[4];
    const float* ab1 = (const float*)d_in[5];
    const float* ag1 = (const float*)d_in[6];
    const float* abt1 = (const float*)d_in[7];
    const float* aw2 = (const float*)d_in[8];
    const float* ab2 = (const float*)d_in[9];
    const float* rw1 = (const float*)d_in[10];
    const float* rb1 = (const float*)d_in[11];
    const float* rg1 = (const float*)d_in[12];
    const float* rbt1 = (const float*)d_in[13];
    const float* rw2 = (const float*)d_in[14];
    const float* rb2 = (const float*)d_in[15];
    const float* rg2 = (const float*)d_in[16];
    const float* rbt2 = (const float*)d_in[17];
    const float* rw3 = (const float*)d_in[18];
    const float* rb3 = (const float*)d_in[19];
    const float* Wq = (const float*)d_in[20];
    const float* bq = (const float*)d_in[21];
    const float* Wk = (const float*)d_in[22];
    const float* bk = (const float*)d_in[23];
    const float* Wv = (const float*)d_in[24];
    const float* bv = (const float*)d_in[25];
    const float* We_ = (const float*)d_in[26];
    const float* be_ = (const float*)d_in[27];
    const float* Wo = (const float*)d_in[28];
    const float* bo = (const float*)d_in[29];
    const float* lng = (const float*)d_in[30];
    const float* lnb = (const float*)d_in[31];
    const float* fw1 = (const float*)d_in[32];
    const float* fb1 = (const float*)d_in[33];
    const float* fow = (const float*)d_in[34];
    const float* fob = (const float*)d_in[35];

    const int* src = eidx;
    const int* dst = eidx + EE;

    // workspace carve-up. Fixed buffers first; the ee slab last with adaptive
    // group size G in {6,3,2,1} (ws_size ~268MB -> G=2 in practice).
    char* w = (char*)d_ws;
    size_t off = 0;
    auto alloc = [&](size_t bytes) -> void* {
        void* p = w + off;
        off += (bytes + 255) & ~(size_t)255;
        return p;
    };
    bf16* t_buf = (bf16*)alloc((size_t)EE * DD * 2);   // 64 MB — persistent edge (CSR order)
    float* node = (float*)alloc((size_t)NN * DD * 4);  // 8 MB
    bf16*  qkv  = (bf16*)alloc((size_t)NN * 768 * 2);  // 12 MB
    bf16*  msg  = (bf16*)alloc((size_t)NN * DD * 2);   // 4 MB (bf16, R16)
    float* outb = (float*)alloc((size_t)NN * DD * 4);  // 8 MB
    int* deg    = (int*)alloc((size_t)NN * 4);         // | contiguous zero
    int* fillc  = (int*)alloc((size_t)NN * 4);         // | region (deg+fill)
    int* rowptr = (int*)alloc((size_t)(NN + 1) * 4);
    int* eid    = (int*)alloc((size_t)EE * 4);         // 512 KB
    int* srcc   = (int*)alloc((size_t)EE * 4);         // 512 KB — CSR-ordered src
    float* dcsr = (float*)alloc((size_t)EE * 4);       // 512 KB — CSR edge lengths
    float* sums  = (float*)alloc((size_t)BB * DD * 4); // | contiguous with cnt
    float* cnt   = (float*)alloc((size_t)BB * 4);      // |
    float* fc    = (float*)alloc((size_t)BB * FCD * 4);
    __bf16* Wt  = (__bf16*)alloc((size_t)40 * 65536 * 2);  // 5.25 MB (34 + 6 combined)
    float* qkvb = (float*)alloc((size_t)LL * 768 * 4);     // 18 KB
    float* be_c = (float*)alloc((size_t)LL * 256 * 4);     // 6 KB — combined ee bias

    const size_t avail = (off <= ws_size) ? ws_size - off : 0;
    int G = 1;
    if      (avail >= (size_t)EE * (6 * DD) * 2 + 256) G = 6;
    else if (avail >= (size_t)EE * (3 * DD) * 2 + 256) G = 3;
    else if (avail >= (size_t)EE * (2 * DD) * 2 + 256) G = 2;
    bf16* e_slab = (bf16*)alloc((size_t)EE * (G * DD) * 2);  // also MLP ping buffer
    (void)n_in; (void)in_sizes; (void)out_size;

    const dim3 blk(256);
    auto WT = [&](int i) -> const __bf16* { return Wt + (size_t)i * 65536; };

    // ---- one-time prep: transposes, combined rw3@We, bias pack, CSR ----
    hipLaunchKernelGGL(transpose_weights, dim3(16, 34), blk, 0, stream,
                       rw1, rw2, rw3, aw2, Wq, Wk, Wv, We_, Wo, Wt);
    hipLaunchKernelGGL(combine_w3e, dim3(4, 4, LL), blk, 0, stream, rw3, We_, Wt + (size_t)34 * 65536);
    hipLaunchKernelGGL(combine_bias, dim3(LL), blk, 0, stream, rb3, We_, be_, be_c);
    hipLaunchKernelGGL(pack_qkv_bias, dim3((LL * 768 + 255) / 256), blk, 0, stream, bq, bk, bv, qkvb);
    hipLaunchKernelGGL(zero_kernel, dim3((2 * NN + 255) / 256), blk, 0, stream, (float*)deg, 2 * NN);
    hipLaunchKernelGGL(deg_kernel, dim3(EE / 256), blk, 0, stream, dst, deg);
    hipLaunchKernelGGL(csr_scan, dim3(1), blk, 0, stream, deg, rowptr);
    hipLaunchKernelGGL(fill_kernel, dim3(EE / 256), blk, 0, stream, src, dst, edge_attr, rowptr, fillc, eid, srcc, dcsr);

    // ---- edge MLP in CSR order: d_csr -> [RBF-gen GEMM+LN+SiLU] -> [GEMM+LN+SiLU]
    hipLaunchKernelGGL(mfma_gemm_ln_rbf, dim3(EE / 64), blk, 0, stream, dcsr, WT(0), rb1, rg1, rbt1, e_slab);
    hipLaunchKernelGGL(mfma_gemm_ln, dim3(EE / 64), blk, 0, stream, e_slab, WT(1), rb2, rg2, rbt2, t_buf, 1);
    // t_buf now holds the persistent edge features (pre-rw3), CSR row order

    // ---- atom embedding: x@aw1 -> LN+SiLU -> @aw2 ----
    {
        dim3 gn64(NN / 64, DD / 64);
        hipLaunchKernelGGL((gemm_bias<float, float>), gn64, blk, 0, stream, x, aw1, ab1, outb, NN, DD, F_AT, (const float*)nullptr);
        hipLaunchKernelGGL((ln_act_kernel<float, float>), dim3(NN / 4), blk, 0, stream, outb, outb, ag1, abt1, (const float*)nullptr, NN, 1);
        hipLaunchKernelGGL((mfma_gemm64<float>), dim3(NN / 64, DD / 128), blk, 0, stream, outb, WT(3), ab2, node, NN, DD, DD);
    }

    // ---- L attention layers ----
    const int nblk_ee = (EE / 128) * ((G * DD) / 128);
    for (int l = 0; l < LL; ++l) {
        const size_t bo_ = (size_t)l * DD;
        if (l % G == 0) {
            // grid-fused: ee for layers l..l+G-1 + this layer's qkv GEMM
            hipLaunchKernelGGL(ee_qkv_fused, dim3(nblk_ee + (NN / 64) * (768 / 128)), blk, 0, stream,
                               t_buf, WT(34 + l), be_c + (size_t)l * 256, e_slab, EE, G * DD, DD, nblk_ee,
                               node, WT(4 + 5 * l), qkvb + (size_t)l * 768, qkv);
        } else {
            hipLaunchKernelGGL((mfma_gemm64<bf16>), dim3(NN / 64, 768 / 128), blk, 0, stream,
                               node, WT(4 + 5 * l), qkvb + (size_t)l * 768, qkv, NN, 768, DD);
        }
        const bf16* ee_l = e_slab + (size_t)(l % G) * DD;
        hipLaunchKernelGGL(attn_kernel, dim3(NN), blk, 0, stream, qkv, ee_l, G * DD, rowptr, srcc, msg);
        // fused: node = LN(msg@Wo + bo) + node
        hipLaunchKernelGGL(mfma_gemm_ln_res, dim3(NN / 64), blk, 0, stream,
                           msg, WT(8 + 5 * l), bo + bo_, lng + bo_, lnb + bo_, node);
    }

    // ---- pooling + FC head (pooled-mean division fused into fc GEMM) ----
    const int PZ = BB * DD + BB;
    hipLaunchKernelGGL(zero_kernel, dim3((PZ + 255) / 256), blk, 0, stream, sums, PZ);
    hipLaunchKernelGGL(pool_kernel, dim3(NN), blk, 0, stream, node, batch, sums, cnt);
    {
        dim3 gf(BB / 64, FCD / 64);
        hipLaunchKernelGGL((gemm_bias<float, float>), gf, blk, 0, stream, sums, fw1, fb1, fc, BB, FCD, DD, cnt);
    }
    hipLaunchKernelGGL(final_kernel, dim3(BB), dim3(64), 0, stream, fc, fow, fob, (float*)d_out);
}

// Round 17
// 915.511 us; speedup vs baseline: 1.0131x; 1.0083x over previous
//
#include <hip/hip_runtime.h>
#include <hip/hip_bf16.h>
#include <cstddef>

// Problem constants (Prdnet_3324304687823)
#define NN    8192
#define EE    131072
#define BB    256
#define F_AT  92
#define DD    256
#define HH    8
#define HDIM  32
#define LL    6
#define FCD   512

typedef __hip_bfloat16 bf16;
typedef __attribute__((ext_vector_type(8))) __bf16 bf16x8;
typedef __attribute__((ext_vector_type(4))) float f32x4;

__device__ __forceinline__ float to_f(float x) { return x; }
__device__ __forceinline__ float to_f(bf16 x) { return __bfloat162float(x); }
__device__ __forceinline__ float bfu(unsigned short u) {
    return __uint_as_float(((unsigned)u) << 16);
}
__device__ __forceinline__ unsigned short bfbits(float x) {
    bf16 h = __float2bfloat16(x);
    return *(unsigned short*)&h;
}
__device__ __forceinline__ void store_v(float* p, float v) { *p = v; }
__device__ __forceinline__ void store_v(bf16* p, float v) { *p = __float2bfloat16(v); }

__device__ __forceinline__ float4 load4(const float* p) { return *(const float4*)p; }
__device__ __forceinline__ float4 load4(const bf16* p) {
    const ushort4 r = *(const ushort4*)p;
    return make_float4(bfu(r.x), bfu(r.y), bfu(r.z), bfu(r.w));
}

__device__ __forceinline__ void store_f4(float* p, const float4& f) {
    *(float4*)p = f;
}
__device__ __forceinline__ void store_f4(bf16* p, const float4& f) {
    ushort4 u = {bfbits(f.x), bfbits(f.y), bfbits(f.z), bfbits(f.w)};
    *(ushort4*)p = u;
}

__device__ __forceinline__ bf16x8 ld8(const bf16* p) { return *(const bf16x8*)p; }
__device__ __forceinline__ bf16x8 ld8(const float* p) {
    const float4 f0 = *(const float4*)p;
    const float4 f1 = *(const float4*)(p + 4);
    bf16x8 r;
    r[0] = (__bf16)f0.x; r[1] = (__bf16)f0.y; r[2] = (__bf16)f0.z; r[3] = (__bf16)f0.w;
    r[4] = (__bf16)f1.x; r[5] = (__bf16)f1.y; r[6] = (__bf16)f1.z; r[7] = (__bf16)f1.w;
    return r;
}

// async global->LDS, 16 B per lane; LDS dest = wave-uniform base + lane*16
__device__ __forceinline__ void async_copy16(const void* g, void* l) {
    __builtin_amdgcn_global_load_lds(
        (const __attribute__((address_space(1))) unsigned int*)g,
        (__attribute__((address_space(3))) unsigned int*)l, 16, 0, 0);
}

// ---------------------------------------------------------------------------
// Batched weight transpose: out[midx][n][k] = (bf16) src[midx][k][n]
// midx: 0=rw1 1=rw2 2=rw3 3=aw2, then per layer l: 4+5l+{0:q,1:k,2:v,3:e,4:o}
// K/V weight rows interleaved (R15-verified correct): k col c ->
// 256+(c>>2)*8+(c&3), v col c -> 256+(c>>2)*8+4+(c&3).
// Slots 34..39 are the combined rw3@We weights (filled by combine_w3e).
// ---------------------------------------------------------------------------
__global__ __launch_bounds__(256) void transpose_weights(
    const float* __restrict__ rw1, const float* __restrict__ rw2,
    const float* __restrict__ rw3, const float* __restrict__ aw2,
    const float* __restrict__ Wq, const float* __restrict__ Wk,
    const float* __restrict__ Wv, const float* __restrict__ We,
    const float* __restrict__ Wo, __bf16* __restrict__ out)
{
    __shared__ float tile[64][65];
    const int midx = blockIdx.y;
    const float* src;
    int fam = 0, s = 0;
    if (midx == 0) src = rw1;
    else if (midx == 1) src = rw2;
    else if (midx == 2) src = rw3;
    else if (midx == 3) src = aw2;
    else {
        fam = (midx - 4) / 5; s = (midx - 4) % 5;
        const float* bases[5] = {Wq, Wk, Wv, We, Wo};
        src = bases[s] + (size_t)fam * 65536;
    }
    const bool isqkv = (midx >= 4) && (s < 3);
    __bf16* dstb = isqkv ? (out + (size_t)(4 + 5 * fam) * 65536)
                         : (out + (size_t)midx * 65536);
    const int k0 = (blockIdx.x >> 2) * 64;
    const int n0 = (blockIdx.x & 3) * 64;
    const int c = threadIdx.x & 63;
    const int r0 = threadIdx.x >> 6;
#pragma unroll
    for (int p = 0; p < 16; ++p) {
        const int r = r0 + p * 4;
        tile[r][c] = src[(size_t)(k0 + r) * 256 + n0 + c];
    }
    __syncthreads();
#pragma unroll
    for (int p = 0; p < 16; ++p) {
        const int n = r0 + p * 4;
        const int gr = n0 + n;
        int row = gr;
        if (isqkv) {
            if (s == 1)      row = 256 + ((gr >> 2) << 3) + (gr & 3);
            else if (s == 2) row = 256 + ((gr >> 2) << 3) + 4 + (gr & 3);
        }
        dstb[(size_t)row * 256 + k0 + c] = (__bf16)tile[c][n];
    }
}

// pack per-layer [bq|bk-interleaved-bv] -> qkvb[l*768 + ...]
__global__ __launch_bounds__(256) void pack_qkv_bias(
    const float* __restrict__ bq, const float* __restrict__ bk,
    const float* __restrict__ bv, float* __restrict__ out)
{
    const int i = blockIdx.x * 256 + threadIdx.x;
    if (i >= LL * 768) return;
    const int l = i / 768, r = i % 768;
    float val; int pos;
    if (r < 256)      { val = bq[l * 256 + r];        pos = r; }
    else if (r < 512) { const int c = r - 256; val = bk[l * 256 + c];
                        pos = 256 + ((c >> 2) << 3) + (c & 3); }
    else              { const int c = r - 512; val = bv[l * 256 + c];
                        pos = 256 + ((c >> 2) << 3) + 4 + (c & 3); }
    out[l * 768 + pos] = val;
}

// ---------------------------------------------------------------------------
// combine_w3e: Wt_out[l][n][k] = bf16( sum_m rw3[k][m] * We[l][m][n] )
// ---------------------------------------------------------------------------
__global__ __launch_bounds__(256) void combine_w3e(
    const float* __restrict__ rw3, const float* __restrict__ We,
    __bf16* __restrict__ Wt_out)
{
    __shared__ float As[16][65];
    __shared__ float Ws[16][65];
    const int l = blockIdx.z;
    const float* W = We + (size_t)l * 65536;
    __bf16* dst = Wt_out + (size_t)l * 65536;
    const int m0 = blockIdx.x * 64;   // k index of combined weight
    const int n0 = blockIdx.y * 64;
    const int tid = threadIdx.x;
    const int tx = tid & 15, ty = tid >> 4;
    float acc[4][4] = {};

    for (int k0 = 0; k0 < 256; k0 += 16) {
        {
            const int ar = tid >> 2;
            const int ac = (tid & 3) * 4;
#pragma unroll
            for (int j = 0; j < 4; ++j)
                As[ac + j][ar] = rw3[(size_t)(m0 + ar) * 256 + k0 + ac + j];
        }
        {
            const int wr = tid >> 4;
            const int wc = (tid & 15) * 4;
#pragma unroll
            for (int j = 0; j < 4; ++j)
                Ws[wr][wc + j] = W[(size_t)(k0 + wr) * 256 + n0 + wc + j];
        }
        __syncthreads();
#pragma unroll
        for (int kk = 0; kk < 16; ++kk) {
            float a[4], b[4];
#pragma unroll
            for (int i = 0; i < 4; ++i) a[i] = As[kk][ty * 4 + i];
#pragma unroll
            for (int j = 0; j < 4; ++j) b[j] = Ws[kk][tx * 4 + j];
#pragma unroll
            for (int i = 0; i < 4; ++i)
#pragma unroll
                for (int j = 0; j < 4; ++j) acc[i][j] += a[i] * b[j];
        }
        __syncthreads();
    }
#pragma unroll
    for (int i = 0; i < 4; ++i) {
        const int gk = m0 + ty * 4 + i;
#pragma unroll
        for (int j = 0; j < 4; ++j) {
            const int gn = n0 + tx * 4 + j;
            dst[(size_t)gn * 256 + gk] = (__bf16)acc[i][j];  // transposed store
        }
    }
}

// be_c[l][n] = sum_m rb3[m] * We[l][m][n] + be[l][n]
__global__ __launch_bounds__(256) void combine_bias(
    const float* __restrict__ rb3, const float* __restrict__ We,
    const float* __restrict__ be, float* __restrict__ out)
{
    const int l = blockIdx.x;
    const int n = threadIdx.x;
    const float* W = We + (size_t)l * 65536;
    float s = be[l * 256 + n];
    for (int m = 0; m < 256; ++m) s += rb3[m] * W[m * 256 + n];
    out[l * 256 + n] = s;
}

// ---------------------------------------------------------------------------
// Fused MFMA GEMM + LayerNorm + SiLU: C = silu(LN(A@W + bias)), Nn=K=256.
// 64x256 tile, both-sides XOR-swizzle, 4 blocks/CU. Coalesced LDS epilogue.
// ---------------------------------------------------------------------------
__global__ __launch_bounds__(256) void mfma_gemm_ln(
    const bf16* __restrict__ A, const __bf16* __restrict__ Wt,
    const float* __restrict__ bias, const float* __restrict__ g,
    const float* __restrict__ b, bf16* __restrict__ C, int do_silu)
{
    __shared__ __align__(16) __bf16 As[64 * 64];
    __shared__ __align__(16) __bf16 Bs[256 * 64];
    const int tid = threadIdx.x;
    const int m0 = blockIdx.x * 64;
    const int wave = tid >> 6, lane = tid & 63;
    const int lm = lane & 15, lq = lane >> 4;
    const int lrow = lane >> 3;
    const int lcolsw = ((lane & 7) ^ lrow) * 8;   // pre-swizzled source col-group

    f32x4 acc[16] = {};

    for (int k0 = 0; k0 < 256; k0 += 64) {
#pragma unroll
        for (int p = 0; p < 2; ++p) {
            const int rbase = wave * 16 + p * 8;   // multiple of 8 -> row&7 == lrow
            async_copy16(A + (size_t)(m0 + rbase + lrow) * 256 + k0 + lcolsw,
                         As + rbase * 64);
        }
#pragma unroll
        for (int p = 0; p < 8; ++p) {
            const int rbase = wave * 64 + p * 8;
            async_copy16(Wt + (size_t)(rbase + lrow) * 256 + k0 + lcolsw,
                         Bs + rbase * 64);
        }
        __syncthreads();
#pragma unroll
        for (int ks = 0; ks < 2; ++ks) {
            const int sw = ((ks * 4 + lq) ^ (lm & 7)) * 8;  // swizzled read slot
            const bf16x8 a = *(const bf16x8*)(As + (wave * 16 + lm) * 64 + sw);
#pragma unroll
            for (int j = 0; j < 16; ++j) {
                const bf16x8 bf = *(const bf16x8*)(Bs + (j * 16 + lm) * 64 + sw);
                acc[j] = __builtin_amdgcn_mfma_f32_16x16x32_bf16(a, bf, acc[j], 0, 0, 0);
            }
        }
        __syncthreads();
    }

    float gg[16], bb[16];
#pragma unroll
    for (int j = 0; j < 16; ++j) {
        const float bv = bias[j * 16 + lm];
        gg[j] = g[j * 16 + lm];
        bb[j] = b[j * 16 + lm];
#pragma unroll
        for (int r = 0; r < 4; ++r) acc[j][r] += bv;
    }

    // each lane holds 4 rows (lq*4+r) x 16 cols (j*16+lm); lanes sharing a row
    // differ only in low-4 bits -> shfl_xor reduce over lm. Results staged to
    // Bs (reused as [64][256] bf16), then one contiguous coalesced write.
#pragma unroll
    for (int r = 0; r < 4; ++r) {
        float s = 0.f, q = 0.f;
#pragma unroll
        for (int j = 0; j < 16; ++j) { const float v = acc[j][r]; s += v; q += v * v; }
#pragma unroll
        for (int msk = 1; msk < 16; msk <<= 1) {
            s += __shfl_xor(s, msk);
            q += __shfl_xor(q, msk);
        }
        const float mean = s * (1.f / 256.f);
        const float var = q * (1.f / 256.f) - mean * mean;
        const float rs = rsqrtf(var + 1e-5f);
        __bf16* erow = Bs + (wave * 16 + lq * 4 + r) * 256;
#pragma unroll
        for (int j = 0; j < 16; ++j) {
            float v = (acc[j][r] - mean) * rs * gg[j] + bb[j];
            if (do_silu) v = v / (1.f + __expf(-v));
            erow[j * 16 + lm] = (__bf16)v;
        }
    }
    __syncthreads();
    {
        __bf16* cbase = (__bf16*)C + (size_t)m0 * 256;   // tile is contiguous
#pragma unroll
        for (int p = 0; p < 8; ++p) {
            const int ofs = (tid + p * 256) * 8;
            *(bf16x8*)(cbase + ofs) = *(const bf16x8*)(Bs + ofs);
        }
    }
}

// ---------------------------------------------------------------------------
// ln1 variant: A = RBF matrix generated ON THE FLY from d_csr (one scalar
// per row) directly into the swizzled LDS slots (R12-verified).
// ---------------------------------------------------------------------------
__global__ __launch_bounds__(256) void mfma_gemm_ln_rbf(
    const float* __restrict__ dcsr, const __bf16* __restrict__ Wt,
    const float* __restrict__ bias, const float* __restrict__ g,
    const float* __restrict__ b, bf16* __restrict__ C)
{
    __shared__ __align__(16) __bf16 As[64 * 64];
    __shared__ __align__(16) __bf16 Bs[256 * 64];
    const int tid = threadIdx.x;
    const int m0 = blockIdx.x * 64;
    const int wave = tid >> 6, lane = tid & 63;
    const int lm = lane & 15, lq = lane >> 4;
    const int lrow = lane >> 3;
    const int lcolsw = ((lane & 7) ^ lrow) * 8;

    const float step = 8.0f / 255.0f;
    const float gamma = 1.0f / (step * step);

    float dv[2];
#pragma unroll
    for (int p = 0; p < 2; ++p)
        dv[p] = dcsr[m0 + wave * 16 + p * 8 + lrow];

    f32x4 acc[16] = {};

    for (int k0 = 0; k0 < 256; k0 += 64) {
#pragma unroll
        for (int p = 0; p < 2; ++p) {
            const int r = wave * 16 + p * 8 + lrow;
            __bf16* dst8 = As + r * 64 + (lane & 7) * 8;
            const int cbase = k0 + lcolsw;
#pragma unroll
            for (int j = 0; j < 8; ++j) {
                const float t = dv[p] - (float)(cbase + j) * step;
                dst8[j] = (__bf16)__expf(-gamma * t * t);
            }
        }
#pragma unroll
        for (int p = 0; p < 8; ++p) {
            const int rbase = wave * 64 + p * 8;
            async_copy16(Wt + (size_t)(rbase + lrow) * 256 + k0 + lcolsw,
                         Bs + rbase * 64);
        }
        __syncthreads();
#pragma unroll
        for (int ks = 0; ks < 2; ++ks) {
            const int sw = ((ks * 4 + lq) ^ (lm & 7)) * 8;
            const bf16x8 a = *(const bf16x8*)(As + (wave * 16 + lm) * 64 + sw);
#pragma unroll
            for (int j = 0; j < 16; ++j) {
                const bf16x8 bf = *(const bf16x8*)(Bs + (j * 16 + lm) * 64 + sw);
                acc[j] = __builtin_amdgcn_mfma_f32_16x16x32_bf16(a, bf, acc[j], 0, 0, 0);
            }
        }
        __syncthreads();
    }

    float gg[16], bb[16];
#pragma unroll
    for (int j = 0; j < 16; ++j) {
        const float bv = bias[j * 16 + lm];
        gg[j] = g[j * 16 + lm];
        bb[j] = b[j * 16 + lm];
#pragma unroll
        for (int r = 0; r < 4; ++r) acc[j][r] += bv;
    }

#pragma unroll
    for (int r = 0; r < 4; ++r) {
        float s = 0.f, q = 0.f;
#pragma unroll
        for (int j = 0; j < 16; ++j) { const float v = acc[j][r]; s += v; q += v * v; }
#pragma unroll
        for (int msk = 1; msk < 16; msk <<= 1) {
            s += __shfl_xor(s, msk);
            q += __shfl_xor(q, msk);
        }
        const float mean = s * (1.f / 256.f);
        const float var = q * (1.f / 256.f) - mean * mean;
        const float rs = rsqrtf(var + 1e-5f);
        __bf16* erow = Bs + (wave * 16 + lq * 4 + r) * 256;
#pragma unroll
        for (int j = 0; j < 16; ++j) {
            float v = (acc[j][r] - mean) * rs * gg[j] + bb[j];
            v = v / (1.f + __expf(-v));   // silu (always on for ln1)
            erow[j * 16 + lm] = (__bf16)v;
        }
    }
    __syncthreads();
    {
        __bf16* cbase = (__bf16*)C + (size_t)m0 * 256;
#pragma unroll
        for (int p = 0; p < 8; ++p) {
            const int ofs = (tid + p * 256) * 8;
            *(bf16x8*)(cbase + ofs) = *(const bf16x8*)(Bs + ofs);
        }
    }
}

// ---------------------------------------------------------------------------
// Fused out-projection: node = LN(A@Wt + bias; g,b) + node (residual, fp32
// in-place). A bf16 (msg). 64x256 tile.
// ---------------------------------------------------------------------------
__global__ __launch_bounds__(256) void mfma_gemm_ln_res(
    const bf16* __restrict__ A, const __bf16* __restrict__ Wt,
    const float* __restrict__ bias, const float* __restrict__ g,
    const float* __restrict__ b, float* __restrict__ node)
{
    __shared__ __align__(16) __bf16 As[64 * 72];   // padded: 2-way max (free)
    __shared__ __align__(16) __bf16 Bs[256 * 64];
    const int tid = threadIdx.x;
    const int m0 = blockIdx.x * 64;
    const int wave = tid >> 6, lane = tid & 63;
    const int lm = lane & 15, lq = lane >> 4;
    const int lrow = lane >> 3;
    const int lcolsw = ((lane & 7) ^ lrow) * 8;

    f32x4 acc[16] = {};
    const int srow = tid >> 3;          // 0..31
    const int scol = (tid & 7) * 8;

    for (int k0 = 0; k0 < 256; k0 += 64) {
#pragma unroll
        for (int p = 0; p < 2; ++p) {
            const int r = srow + 32 * p;
            *(bf16x8*)(As + r * 72 + scol) = ld8(A + (size_t)(m0 + r) * 256 + k0 + scol);
        }
#pragma unroll
        for (int p = 0; p < 8; ++p) {
            const int rbase = wave * 64 + p * 8;   // multiple of 8 -> row&7 == lrow
            async_copy16(Wt + (size_t)(rbase + lrow) * 256 + k0 + lcolsw,
                         Bs + rbase * 64);
        }
        __syncthreads();
#pragma unroll
        for (int ks = 0; ks < 2; ++ks) {
            const int sw = ((ks * 4 + lq) ^ (lm & 7)) * 8;
            const bf16x8 a = *(const bf16x8*)(As + (wave * 16 + lm) * 72 + ks * 32 + lq * 8);
#pragma unroll
            for (int j = 0; j < 16; ++j) {
                const bf16x8 bf = *(const bf16x8*)(Bs + (j * 16 + lm) * 64 + sw);
                acc[j] = __builtin_amdgcn_mfma_f32_16x16x32_bf16(a, bf, acc[j], 0, 0, 0);
            }
        }
        __syncthreads();
    }

    float gg[16], bb[16];
#pragma unroll
    for (int j = 0; j < 16; ++j) {
        const float bv = bias[j * 16 + lm];
        gg[j] = g[j * 16 + lm];
        bb[j] = b[j * 16 + lm];
#pragma unroll
        for (int r = 0; r < 4; ++r) acc[j][r] += bv;
    }

#pragma unroll
    for (int r = 0; r < 4; ++r) {
        float s = 0.f, q = 0.f;
#pragma unroll
        for (int j = 0; j < 16; ++j) { const float v = acc[j][r]; s += v; q += v * v; }
#pragma unroll
        for (int msk = 1; msk < 16; msk <<= 1) {
            s += __shfl_xor(s, msk);
            q += __shfl_xor(q, msk);
        }
        const float mean = s * (1.f / 256.f);
        const float var = q * (1.f / 256.f) - mean * mean;
        const float rs = rsqrtf(var + 1e-5f);
        float* crow = node + (size_t)(m0 + wave * 16 + lq * 4 + r) * 256;
#pragma unroll
        for (int j = 0; j < 16; ++j) {
            const float v = (acc[j][r] - mean) * rs * gg[j] + bb[j];
            crow[j * 16 + lm] += v;   // node = LN(...) + node_old (one lane per elem)
        }
    }
}

// ---------------------------------------------------------------------------
// GRID-FUSED ee GEMM + qkv GEMM (one dispatch, R16-verified): blocks <
// nblk_ee run the ee path; remaining 768 run the 64x128 qkv GEMM.
// ---------------------------------------------------------------------------
__global__ __launch_bounds__(256) void ee_qkv_fused(
    const bf16* __restrict__ A, const __bf16* __restrict__ Wte,
    const float* __restrict__ biase, bf16* __restrict__ Ce,
    int M, int Nn, int K, int nblk_ee,
    const float* __restrict__ nodeA, const __bf16* __restrict__ Wtq,
    const float* __restrict__ biasq, bf16* __restrict__ Cq)
{
    __shared__ __align__(16) __bf16 smem[128 * 128];   // 32 KB, aliased by both roles
    const int tid = threadIdx.x;
    const int wave = tid >> 6, lane = tid & 63;
    const int lm = lane & 15, lq = lane >> 4;

    if ((int)blockIdx.x < nblk_ee) {
        // ---------------- ee role (identical to mfma_gemm_ee) ----------------
        __bf16* As = smem;              // [128][64]
        __bf16* Bs = smem + 128 * 64;   // [128][64]
        const int nt_n = Nn >> 7;
        const int xcd = blockIdx.x & 7;
        const int local = blockIdx.x >> 3;
        const int per_xcd = (M >> 7) >> 3;
        const int m0 = (xcd * per_xcd + local / nt_n) * 128;
        const int n0 = (local % nt_n) * 128;

        const int wm = (wave & 1) * 64, wn = (wave >> 1) * 64;
        const int lrow = lane >> 3;
        const int lcolsw = ((lane & 7) ^ lrow) * 8;

        f32x4 acc[4][4] = {};

        for (int k0 = 0; k0 < K; k0 += 64) {
#pragma unroll
            for (int p = 0; p < 4; ++p) {
                const int rbase = wave * 32 + p * 8;
                async_copy16(A   + (size_t)(m0 + rbase + lrow) * K + k0 + lcolsw,
                             As + rbase * 64);
                async_copy16(Wte + (size_t)(n0 + rbase + lrow) * K + k0 + lcolsw,
                             Bs + rbase * 64);
            }
            __syncthreads();
#pragma unroll
            for (int ks = 0; ks < 2; ++ks) {
                const int sw = ((ks * 4 + lq) ^ (lm & 7)) * 8;
                bf16x8 a[4], b[4];
#pragma unroll
                for (int i = 0; i < 4; ++i) {
                    a[i] = *(const bf16x8*)(As + (wm + i * 16 + lm) * 64 + sw);
                    b[i] = *(const bf16x8*)(Bs + (wn + i * 16 + lm) * 64 + sw);
                }
#pragma unroll
                for (int i = 0; i < 4; ++i)
#pragma unroll
                    for (int j = 0; j < 4; ++j)
                        acc[i][j] = __builtin_amdgcn_mfma_f32_16x16x32_bf16(
                            a[i], b[j], acc[i][j], 0, 0, 0);
            }
            __syncthreads();
        }

#pragma unroll
        for (int i = 0; i < 4; ++i) {
            const int rl = wm + i * 16 + lq * 4;
#pragma unroll
            for (int j = 0; j < 4; ++j) {
                const int cl = wn + j * 16 + lm;
                const float bb = biase ? biase[n0 + cl] : 0.f;
#pragma unroll
                for (int r = 0; r < 4; ++r) {
                    const int row = rl + r;
                    smem[row * 128 + (cl ^ ((row & 7) << 3))] =
                        (__bf16)(acc[i][j][r] + bb);
                }
            }
        }
        __syncthreads();
#pragma unroll
        for (int p = 0; p < 8; ++p) {
            const int ch = tid + p * 256;
            const int row = ch >> 4;
            const int gcol = ch & 15;
            const int sg = gcol ^ (row & 7);
            *(bf16x8*)((__bf16*)Ce + (size_t)(m0 + row) * Nn + n0 + gcol * 8) =
                *(const bf16x8*)(smem + row * 128 + sg * 8);
        }
    } else {
        // ---------------- qkv role (identical to mfma_gemm64) ----------------
        const int bq = blockIdx.x - nblk_ee;        // 0..767
        const int m0 = (bq % (NN / 64)) * 64;
        const int n0 = (bq / (NN / 64)) * 128;
        __bf16* As = smem;                 // [64][72]
        __bf16* Bs = smem + 64 * 72;       // [128][72]  (total 27648 B < 32768)

        const int wm = (wave & 1) * 32, wn = (wave >> 1) * 64;
        f32x4 acc[2][4] = {};
        const int srow = tid >> 3;
        const int scol = (tid & 7) * 8;

        for (int k0 = 0; k0 < 256; k0 += 64) {
#pragma unroll
            for (int p = 0; p < 2; ++p) {
                const int r = srow + 32 * p;
                *(bf16x8*)(As + r * 72 + scol) =
                    ld8(nodeA + (size_t)(m0 + r) * 256 + k0 + scol);
            }
#pragma unroll
            for (int p = 0; p < 4; ++p) {
                const int r = srow + 32 * p;
                *(bf16x8*)(Bs + r * 72 + scol) =
                    *(const bf16x8*)(Wtq + (size_t)(n0 + r) * 256 + k0 + scol);
            }
            __syncthreads();
#pragma unroll
            for (int ks = 0; ks < 2; ++ks) {
                bf16x8 a[2], b[4];
#pragma unroll
                for (int i = 0; i < 2; ++i)
                    a[i] = *(const bf16x8*)(As + (wm + i * 16 + lm) * 72 + ks * 32 + lq * 8);
#pragma unroll
                for (int j = 0; j < 4; ++j)
                    b[j] = *(const bf16x8*)(Bs + (wn + j * 16 + lm) * 72 + ks * 32 + lq * 8);
#pragma unroll
                for (int i = 0; i < 2; ++i)
#pragma unroll
                    for (int j = 0; j < 4; ++j)
                        acc[i][j] = __builtin_amdgcn_mfma_f32_16x16x32_bf16(
                            a[i], b[j], acc[i][j], 0, 0, 0);
            }
            __syncthreads();
        }

#pragma unroll
        for (int i = 0; i < 2; ++i) {
            const int gm = m0 + wm + i * 16 + lq * 4;
#pragma unroll
            for (int j = 0; j < 4; ++j) {
                const int gn = n0 + wn + j * 16 + lm;
                const float bv = biasq[gn];
#pragma unroll
                for (int r = 0; r < 4; ++r)
                    store_v(&Cq[(size_t)(gm + r) * 768 + gn], acc[i][j][r] + bv);
            }
        }
    }
}

// ---------------------------------------------------------------------------
// MFMA GEMM, 64x128 tile (fp32 A, register-staged): C = A@Wt + bias.
// (R14-verified; used for atom aw2 and odd-layer qkv.)
// ---------------------------------------------------------------------------
template <typename CT>
__global__ __launch_bounds__(256) void mfma_gemm64(
    const float* __restrict__ A, const __bf16* __restrict__ Wt,
    const float* __restrict__ bias, CT* __restrict__ C,
    int M, int Nn, int K)
{
    __shared__ __align__(16) __bf16 As[64 * 72];
    __shared__ __align__(16) __bf16 Bs[128 * 72];
    const int tid = threadIdx.x;
    const int m0 = blockIdx.x * 64;
    const int n0 = blockIdx.y * 128;
    const int wave = tid >> 6, lane = tid & 63;
    const int wm = (wave & 1) * 32, wn = (wave >> 1) * 64;
    const int lm = lane & 15, lq = lane >> 4;

    f32x4 acc[2][4] = {};

    const int srow = tid >> 3;          // 0..31
    const int scol = (tid & 7) * 8;

    for (int k0 = 0; k0 < K; k0 += 64) {
#pragma unroll
        for (int p = 0; p < 2; ++p) {
            const int r = srow + 32 * p;
            *(bf16x8*)(As + r * 72 + scol) =
                ld8(A + (size_t)(m0 + r) * K + k0 + scol);
        }
#pragma unroll
        for (int p = 0; p < 4; ++p) {
            const int r = srow + 32 * p;
            *(bf16x8*)(Bs + r * 72 + scol) =
                *(const bf16x8*)(Wt + (size_t)(n0 + r) * K + k0 + scol);
        }
        __syncthreads();
#pragma unroll
        for (int ks = 0; ks < 2; ++ks) {
            bf16x8 a[2], b[4];
#pragma unroll
            for (int i = 0; i < 2; ++i)
                a[i] = *(const bf16x8*)(As + (wm + i * 16 + lm) * 72 + ks * 32 + lq * 8);
#pragma unroll
            for (int j = 0; j < 4; ++j)
                b[j] = *(const bf16x8*)(Bs + (wn + j * 16 + lm) * 72 + ks * 32 + lq * 8);
#pragma unroll
            for (int i = 0; i < 2; ++i)
#pragma unroll
                for (int j = 0; j < 4; ++j)
                    acc[i][j] = __builtin_amdgcn_mfma_f32_16x16x32_bf16(
                        a[i], b[j], acc[i][j], 0, 0, 0);
        }
        __syncthreads();
    }

#pragma unroll
    for (int i = 0; i < 2; ++i) {
        const int gm = m0 + wm + i * 16 + lq * 4;
#pragma unroll
        for (int j = 0; j < 4; ++j) {
            const int gn = n0 + wn + j * 16 + lm;
            const float bv = bias ? bias[gn] : 0.f;
#pragma unroll
            for (int r = 0; r < 4; ++r)
                store_v(&C[(size_t)(gm + r) * Nn + gn], acc[i][j][r] + bv);
        }
    }
}

// ---------------------------------------------------------------------------
// Fallback vector GEMM (K=92 aw1, fc head). Optional cntdiv: A-row gm is
// divided by max(cnt[gm],1) on load (fuses the pooled-mean division).
// ---------------------------------------------------------------------------
template <typename AT, typename CT>
__global__ __launch_bounds__(256) void gemm_bias(
    const AT* __restrict__ A, const float* __restrict__ W,
    const float* __restrict__ bias, CT* __restrict__ C,
    int M, int Nn, int K, const float* __restrict__ cntdiv)
{
    __shared__ float As[16][65];
    __shared__ float Ws[16][65];
    const int m0 = blockIdx.x * 64;
    const int n0 = blockIdx.y * 64;
    const int tid = threadIdx.x;
    const int tx = tid & 15, ty = tid >> 4;
    float acc[4][4] = {};

    for (int k0 = 0; k0 < K; k0 += 16) {
        {
            const int ar = tid >> 2;
            const int ac = (tid & 3) * 4;
            const int gm = m0 + ar;
            float inv = 1.f;
            if (cntdiv && gm < M) {
                float cc = cntdiv[gm];
                if (cc < 1.f) cc = 1.f;
                inv = 1.f / cc;
            }
#pragma unroll
            for (int j = 0; j < 4; ++j) {
                const int gk = k0 + ac + j;
                float v = 0.f;
                if (gm < M && gk < K) v = to_f(A[(size_t)gm * K + gk]) * inv;
                As[ac + j][ar] = v;
            }
        }
        {
            const int wr = tid >> 4;
            const int wc = (tid & 15) * 4;
            const int gk = k0 + wr;
#pragma unroll
            for (int j = 0; j < 4; ++j) {
                float v = 0.f;
                if (gk < K) v = W[(size_t)gk * Nn + n0 + wc + j];
                Ws[wr][wc + j] = v;
            }
        }
        __syncthreads();
#pragma unroll
        for (int kk = 0; kk < 16; ++kk) {
            float a[4], b[4];
#pragma unroll
            for (int i = 0; i < 4; ++i) a[i] = As[kk][ty * 4 + i];
#pragma unroll
            for (int j = 0; j < 4; ++j) b[j] = Ws[kk][tx * 4 + j];
#pragma unroll
            for (int i = 0; i < 4; ++i)
#pragma unroll
                for (int j = 0; j < 4; ++j) acc[i][j] += a[i] * b[j];
        }
        __syncthreads();
    }
#pragma unroll
    for (int i = 0; i < 4; ++i) {
        const int gm = m0 + ty * 4 + i;
        if (gm >= M) continue;
#pragma unroll
        for (int j = 0; j < 4; ++j) {
            const int gn = n0 + tx * 4 + j;
            float v = acc[i][j];
            if (bias) v += bias[gn];
            store_v(&C[(size_t)gm * Nn + gn], v);
        }
    }
}

// ---------------------------------------------------------------------------
// Row LayerNorm (+opt SiLU via __expf, +opt fp32 residual). Node-side only.
// ---------------------------------------------------------------------------
template <typename XT, typename YT>
__global__ __launch_bounds__(256) void ln_act_kernel(
    const XT* __restrict__ X, YT* __restrict__ Y,
    const float* __restrict__ g, const float* __restrict__ b,
    const float* __restrict__ resid, int rows, int do_silu)
{
    const int wave = threadIdx.x >> 6;
    const int lane = threadIdx.x & 63;
    const int r = blockIdx.x * 4 + wave;
    if (r >= rows) return;
    const float4 x = load4(X + (size_t)r * DD + lane * 4);
    float s = x.x + x.y + x.z + x.w;
    float q = x.x * x.x + x.y * x.y + x.z * x.z + x.w * x.w;
    for (int off = 32; off; off >>= 1) {
        s += __shfl_down(s, off);
        q += __shfl_down(q, off);
    }
    s = __shfl(s, 0);
    q = __shfl(q, 0);
    const float mean = s * (1.f / 256.f);
    const float var = q * (1.f / 256.f) - mean * mean;
    const float rs = rsqrtf(var + 1e-5f);
    const int c = lane * 4;
    float xs[4] = {x.x, x.y, x.z, x.w};
    float out[4];
#pragma unroll
    for (int i = 0; i < 4; ++i) {
        float v = (xs[i] - mean) * rs * g[c + i] + b[c + i];
        if (do_silu) v = v / (1.f + __expf(-v));
        out[i] = v;
    }
    if (resid) {
        const float4 rv = load4(resid + (size_t)r * DD + c);
        out[0] += rv.x; out[1] += rv.y; out[2] += rv.z; out[3] += rv.w;
    }
    store_f4(Y + (size_t)r * DD + c, make_float4(out[0], out[1], out[2], out[3]));
}

// ---------------------------------------------------------------------------
// CSR build: histogram, block-scan, fill (emits CSR-ordered src AND CSR
// edge lengths dcsr)
// ---------------------------------------------------------------------------
__global__ __launch_bounds__(256) void deg_kernel(
    const int* __restrict__ dst, int* __restrict__ deg)
{
    const int e = blockIdx.x * 256 + threadIdx.x;
    if (e < EE) atomicAdd(&deg[dst[e]], 1);
}

__global__ __launch_bounds__(256) void csr_scan(
    const int* __restrict__ deg, int* __restrict__ rowptr)
{
    __shared__ int part[256];
    const int t = threadIdx.x;
    int local[32];
    int s = 0;
#pragma unroll
    for (int i = 0; i < 32; ++i) { local[i] = deg[t * 32 + i]; s += local[i]; }
    part[t] = s;
    __syncthreads();
    if (t == 0) {
        int run = 0;
        for (int i = 0; i < 256; ++i) { const int v = part[i]; part[i] = run; run += v; }
    }
    __syncthreads();
    int run = part[t];
#pragma unroll
    for (int i = 0; i < 32; ++i) { rowptr[t * 32 + i] = run; run += local[i]; }
    if (t == 255) rowptr[NN] = run;
}

__global__ __launch_bounds__(256) void fill_kernel(
    const int* __restrict__ src, const int* __restrict__ dst,
    const float* __restrict__ ea, const int* __restrict__ rowptr,
    int* __restrict__ fill, int* __restrict__ eid,
    int* __restrict__ srcc, float* __restrict__ dcsr)
{
    const int e = blockIdx.x * 256 + threadIdx.x;
    if (e >= EE) return;
    const int d = dst[e];
    const int pos = atomicAdd(&fill[d], 1);
    const int q = rowptr[d] + pos;
    eid[q] = e;
    srcc[q] = src[e];
    const float ax = ea[e * 3 + 0];
    const float ay = ea[e * 3 + 1];
    const float az = ea[e * 3 + 2];
    dcsr[q] = sqrtf(ax * ax + ay * ay + az * az);
}

// ---------------------------------------------------------------------------
// Single-pass fused attention (flash-style online softmax), no atomics.
// CSR-ordered ee (sequential), 4 waves/node (R10-verified), packed 16B K|V
// gather (R15), bf16 msg output (R16).
// R17: XCD-GROUPED node mapping — n = (bid&7)*(NN/8) + (bid>>3). batch is
// sorted, so a node's neighbors lie in its own graph (~32-node window);
// contiguous node ranges per XCD concentrate the qkv gather working set
// (~1.5 MB) in that XCD's private L2 (same mechanism as R8's ee fix).
// ---------------------------------------------------------------------------
__global__ __launch_bounds__(256) void attn_kernel(
    const bf16* __restrict__ qkv, const bf16* __restrict__ ee, int estride,
    const int* __restrict__ rowptr, const int* __restrict__ srcc,
    bf16* __restrict__ msg)
{
    const int n = (blockIdx.x & 7) * (NN / 8) + (blockIdx.x >> 3);
    const int tid = threadIdx.x;
    const int wave = tid >> 6, lane = tid & 63;
    const int e0 = rowptr[n];
    const int deg = rowptr[n + 1] - e0;

    if (deg == 0) {  // uniform branch
        store_v(&msg[(size_t)n * DD + tid], 0.f);
        return;
    }

    __shared__ float wm[4][HH];
    __shared__ float wl[4][HH];
    __shared__ float wacc[4][DD];

    const float4 qreg = load4(qkv + (size_t)n * 768 + lane * 4);

    float m = -3.402823466e38f, l = 0.f;
    float4 acc = {0.f, 0.f, 0.f, 0.f};

    int j = wave;
    bf16x8 kvp = {};                      // k[0..3]|v[0..3] packed
    float4 ev = {0.f, 0.f, 0.f, 0.f};
    if (j < deg) {
        const int e = e0 + j;
        const bf16* srow = qkv + (size_t)srcc[e] * 768;
        kvp = ld8(srow + 256 + lane * 8);
        ev = load4(ee + (size_t)e * estride + lane * 4);
    }
    while (j < deg) {
        const int jn = j + 4;
        bf16x8 kvp2 = {};
        float4 ev2 = {0.f, 0.f, 0.f, 0.f};
        if (jn < deg) {
            const int e2 = e0 + jn;
            const bf16* srow2 = qkv + (size_t)srcc[e2] * 768;
            kvp2 = ld8(srow2 + 256 + lane * 8);
            ev2 = load4(ee + (size_t)e2 * estride + lane * 4);
        }
        const float kx = (float)kvp[0], ky = (float)kvp[1];
        const float kz = (float)kvp[2], kw = (float)kvp[3];
        const float vx = (float)kvp[4], vy = (float)kvp[5];
        const float vz = (float)kvp[6], vw = (float)kvp[7];
        float p = qreg.x * (kx + ev.x) + qreg.y * (ky + ev.y) +
                  qreg.z * (kz + ev.z) + qreg.w * (kw + ev.w);
        p += __shfl_down(p, 4);
        p += __shfl_down(p, 2);
        p += __shfl_down(p, 1);
        const float s = __shfl(p, lane & 56) * 0.17677669529663687f;
        const float mnew = fmaxf(m, s);
        const float scale = __expf(m - mnew);
        const float pe = __expf(s - mnew);
        l = l * scale + pe;
        acc.x = acc.x * scale + pe * (vx + ev.x);
        acc.y = acc.y * scale + pe * (vy + ev.y);
        acc.z = acc.z * scale + pe * (vz + ev.z);
        acc.w = acc.w * scale + pe * (vw + ev.w);
        m = mnew;
        kvp = kvp2; ev = ev2;
        j = jn;
    }

    if ((lane & 7) == 0) { wm[wave][lane >> 3] = m; wl[wave][lane >> 3] = l; }
    *(float4*)(&wacc[wave][lane * 4]) = acc;
    __syncthreads();

    {
        const int c = tid, h = tid >> 5;
        float M = wm[0][h];
#pragma unroll
        for (int i = 1; i < 4; ++i) M = fmaxf(M, wm[i][h]);
        float L = 0.f, num = 0.f;
#pragma unroll
        for (int i = 0; i < 4; ++i) {
            const float sc = __expf(wm[i][h] - M);
            L += wl[i][h] * sc;
            num += wacc[i][c] * sc;
        }
        store_v(&msg[(size_t)n * DD + c], num / (L + 1e-16f));
    }
}

__global__ __launch_bounds__(256) void zero_kernel(float* __restrict__ p, int n)
{
    const int i = blockIdx.x * 256 + threadIdx.x;
    if (i < n) p[i] = 0.f;
}

__global__ __launch_bounds__(256) void pool_kernel(
    const float* __restrict__ node, const int* __restrict__ batch,
    float* __restrict__ sums, float* __restrict__ cnt)
{
    const int n = blockIdx.x;
    const int c = threadIdx.x;
    const int b = batch[n];
    atomicAdd(&sums[b * DD + c], node[(size_t)n * DD + c]);
    if (c == 0) atomicAdd(&cnt[b], 1.0f);
}

__global__ __launch_bounds__(64) void final_kernel(
    const float* __restrict__ fc, const float* __restrict__ fow,
    const float* __restrict__ fob, float* __restrict__ out)
{
    const int b = blockIdx.x;
    const int lane = threadIdx.x;
    float s = 0.f;
#pragma unroll
    for (int i = lane; i < FCD; i += 64) s += fc[(size_t)b * FCD + i] * fow[i];
    for (int off = 32; off; off >>= 1) s += __shfl_down(s, off);
    if (lane == 0) out[b] = s + fob[0];
}

// ---------------------------------------------------------------------------
extern "C" void kernel_launch(void* const* d_in, const int* in_sizes, int n_in,
                              void* d_out, int out_size, void* d_ws,
                              size_t ws_size, hipStream_t stream)
{
    const float* x         = (const float*)d_in[0];
    const float* edge_attr = (const float*)d_in[1];
    const int*   eidx      = (const int*)d_in[2];
    const int*   batch     = (const int*)d_in[3];
    const float* aw1 = (const float*)d_in[4];
    const float* ab1 = (const float*)d_in[5];
    const float* ag1 = (const float*)d_in[6];
    const float* abt1 = (const float*)d_in[7];
    const float* aw2 = (const float*)d_in[8];
    const float* ab2 = (const float*)d_in[9];
    const float* rw1 = (const float*)d_in[10];
    const float* rb1 = (const float*)d_in[11];
    const float* rg1 = (const float*)d_in[12];
    const float* rbt1 = (const float*)d_in[13];
    const float* rw2 = (const float*)d_in[14];
    const float* rb2 = (const float*)d_in[15];
    const float* rg2 = (const float*)d_in[16];
    const float* rbt2 = (const float*)d_in[17];
    const float* rw3 = (const float*)d_in[18];
    const float* rb3 = (const float*)d_in[19];
    const float* Wq = (const float*)d_in[20];
    const float* bq = (const float*)d_in[21];
    const float* Wk = (const float*)d_in[22];
    const float* bk = (const float*)d_in[23];
    const float* Wv = (const float*)d_in[24];
    const float* bv = (const float*)d_in[25];
    const float* We_ = (const float*)d_in[26];
    const float* be_ = (const float*)d_in[27];
    const float* Wo = (const float*)d_in[28];
    const float* bo = (const float*)d_in[29];
    const float* lng = (const float*)d_in[30];
    const float* lnb = (const float*)d_in[31];
    const float* fw1 = (const float*)d_in[32];
    const float* fb1 = (const float*)d_in[33];
    const float* fow = (const float*)d_in[34];
    const float* fob = (const float*)d_in[35];

    const int* src = eidx;
    const int* dst = eidx + EE;

    // workspace carve-up. Fixed buffers first; the ee slab last with adaptive
    // group size G in {6,3,2,1} (ws_size ~268MB -> G=2 in practice).
    char* w = (char*)d_ws;
    size_t off = 0;
    auto alloc = [&](size_t bytes) -> void* {
        void* p = w + off;
        off += (bytes + 255) & ~(size_t)255;
        return p;
    };
    bf16* t_buf = (bf16*)alloc((size_t)EE * DD * 2);   // 64 MB — persistent edge (CSR order)
    float* node = (float*)alloc((size_t)NN * DD * 4);  // 8 MB
    bf16*  qkv  = (bf16*)alloc((size_t)NN * 768 * 2);  // 12 MB
    bf16*  msg  = (bf16*)alloc((size_t)NN * DD * 2);   // 4 MB (bf16)
    float* outb = (float*)alloc((size_t)NN * DD * 4);  // 8 MB
    int* deg    = (int*)alloc((size_t)NN * 4);         // | contiguous zero
    int* fillc  = (int*)alloc((size_t)NN * 4);         // | region (deg+fill)
    int* rowptr = (int*)alloc((size_t)(NN + 1) * 4);
    int* eid    = (int*)alloc((size_t)EE * 4);         // 512 KB
    int* srcc   = (int*)alloc((size_t)EE * 4);         // 512 KB — CSR-ordered src
    float* dcsr = (float*)alloc((size_t)EE * 4);       // 512 KB — CSR edge lengths
    float* sums  = (float*)alloc((size_t)BB * DD * 4); // | contiguous with cnt
    float* cnt   = (float*)alloc((size_t)BB * 4);      // |
    float* fc    = (float*)alloc((size_t)BB * FCD * 4);
    __bf16* Wt  = (__bf16*)alloc((size_t)40 * 65536 * 2);  // 5.25 MB (34 + 6 combined)
    float* qkvb = (float*)alloc((size_t)LL * 768 * 4);     // 18 KB
    float* be_c = (float*)alloc((size_t)LL * 256 * 4);     // 6 KB — combined ee bias

    const size_t avail = (off <= ws_size) ? ws_size - off : 0;
    int G = 1;
    if      (avail >= (size_t)EE * (6 * DD) * 2 + 256) G = 6;
    else if (avail >= (size_t)EE * (3 * DD) * 2 + 256) G = 3;
    else if (avail >= (size_t)EE * (2 * DD) * 2 + 256) G = 2;
    bf16* e_slab = (bf16*)alloc((size_t)EE * (G * DD) * 2);  // also MLP ping buffer
    (void)n_in; (void)in_sizes; (void)out_size;

    const dim3 blk(256);
    auto WT = [&](int i) -> const __bf16* { return Wt + (size_t)i * 65536; };

    // ---- one-time prep: transposes, combined rw3@We, bias pack, CSR ----
    hipLaunchKernelGGL(transpose_weights, dim3(16, 34), blk, 0, stream,
                       rw1, rw2, rw3, aw2, Wq, Wk, Wv, We_, Wo, Wt);
    hipLaunchKernelGGL(combine_w3e, dim3(4, 4, LL), blk, 0, stream, rw3, We_, Wt + (size_t)34 * 65536);
    hipLaunchKernelGGL(combine_bias, dim3(LL), blk, 0, stream, rb3, We_, be_, be_c);
    hipLaunchKernelGGL(pack_qkv_bias, dim3((LL * 768 + 255) / 256), blk, 0, stream, bq, bk, bv, qkvb);
    hipLaunchKernelGGL(zero_kernel, dim3((2 * NN + 255) / 256), blk, 0, stream, (float*)deg, 2 * NN);
    hipLaunchKernelGGL(deg_kernel, dim3(EE / 256), blk, 0, stream, dst, deg);
    hipLaunchKernelGGL(csr_scan, dim3(1), blk, 0, stream, deg, rowptr);
    hipLaunchKernelGGL(fill_kernel, dim3(EE / 256), blk, 0, stream, src, dst, edge_attr, rowptr, fillc, eid, srcc, dcsr);

    // ---- edge MLP in CSR order: d_csr -> [RBF-gen GEMM+LN+SiLU] -> [GEMM+LN+SiLU]
    hipLaunchKernelGGL(mfma_gemm_ln_rbf, dim3(EE / 64), blk, 0, stream, dcsr, WT(0), rb1, rg1, rbt1, e_slab);
    hipLaunchKernelGGL(mfma_gemm_ln, dim3(EE / 64), blk, 0, stream, e_slab, WT(1), rb2, rg2, rbt2, t_buf, 1);
    // t_buf now holds the persistent edge features (pre-rw3), CSR row order

    // ---- atom embedding: x@aw1 -> LN+SiLU -> @aw2 ----
    {
        dim3 gn64(NN / 64, DD / 64);
        hipLaunchKernelGGL((gemm_bias<float, float>), gn64, blk, 0, stream, x, aw1, ab1, outb, NN, DD, F_AT, (const float*)nullptr);
        hipLaunchKernelGGL((ln_act_kernel<float, float>), dim3(NN / 4), blk, 0, stream, outb, outb, ag1, abt1, (const float*)nullptr, NN, 1);
        hipLaunchKernelGGL((mfma_gemm64<float>), dim3(NN / 64, DD / 128), blk, 0, stream, outb, WT(3), ab2, node, NN, DD, DD);
    }

    // ---- L attention layers ----
    const int nblk_ee = (EE / 128) * ((G * DD) / 128);
    for (int l = 0; l < LL; ++l) {
        const size_t bo_ = (size_t)l * DD;
        if (l % G == 0) {
            // grid-fused: ee for layers l..l+G-1 + this layer's qkv GEMM
            hipLaunchKernelGGL(ee_qkv_fused, dim3(nblk_ee + (NN / 64) * (768 / 128)), blk, 0, stream,
                               t_buf, WT(34 + l), be_c + (size_t)l * 256, e_slab, EE, G * DD, DD, nblk_ee,
                               node, WT(4 + 5 * l), qkvb + (size_t)l * 768, qkv);
        } else {
            hipLaunchKernelGGL((mfma_gemm64<bf16>), dim3(NN / 64, 768 / 128), blk, 0, stream,
                               node, WT(4 + 5 * l), qkvb + (size_t)l * 768, qkv, NN, 768, DD);
        }
        const bf16* ee_l = e_slab + (size_t)(l % G) * DD;
        hipLaunchKernelGGL(attn_kernel, dim3(NN), blk, 0, stream, qkv, ee_l, G * DD, rowptr, srcc, msg);
        // fused: node = LN(msg@Wo + bo) + node
        hipLaunchKernelGGL(mfma_gemm_ln_res, dim3(NN / 64), blk, 0, stream,
                           msg, WT(8 + 5 * l), bo + bo_, lng + bo_, lnb + bo_, node);
    }

    // ---- pooling + FC head (pooled-mean division fused into fc GEMM) ----
    const int PZ = BB * DD + BB;
    hipLaunchKernelGGL(zero_kernel, dim3((PZ + 255) / 256), blk, 0, stream, sums, PZ);
    hipLaunchKernelGGL(pool_kernel, dim3(NN), blk, 0, stream, node, batch, sums, cnt);
    {
        dim3 gf(BB / 64, FCD / 64);
        hipLaunchKernelGGL((gemm_bias<float, float>), gf, blk, 0, stream, sums, fw1, fb1, fc, BB, FCD, DD, cnt);
    }
    hipLaunchKernelGGL(final_kernel, dim3(BB), dim3(64), 0, stream, fc, fow, fob, (float*)d_out);
}

// Round 18
// 887.546 us; speedup vs baseline: 1.0451x; 1.0315x over previous
//
#include <hip/hip_runtime.h>
#include <hip/hip_bf16.h>
#include <cstddef>

// Problem constants (Prdnet_3324304687823)
#define NN    8192
#define EE    131072
#define BB    256
#define F_AT  92
#define DD    256
#define HH    8
#define HDIM  32
#define LL    6
#define FCD   512

typedef __hip_bfloat16 bf16;
typedef __attribute__((ext_vector_type(8))) __bf16 bf16x8;
typedef __attribute__((ext_vector_type(4))) float f32x4;

__device__ __forceinline__ float to_f(float x) { return x; }
__device__ __forceinline__ float to_f(bf16 x) { return __bfloat162float(x); }
__device__ __forceinline__ float bfu(unsigned short u) {
    return __uint_as_float(((unsigned)u) << 16);
}
__device__ __forceinline__ unsigned short bfbits(float x) {
    bf16 h = __float2bfloat16(x);
    return *(unsigned short*)&h;
}
__device__ __forceinline__ void store_v(float* p, float v) { *p = v; }
__device__ __forceinline__ void store_v(bf16* p, float v) { *p = __float2bfloat16(v); }

__device__ __forceinline__ float4 load4(const float* p) { return *(const float4*)p; }
__device__ __forceinline__ float4 load4(const bf16* p) {
    const ushort4 r = *(const ushort4*)p;
    return make_float4(bfu(r.x), bfu(r.y), bfu(r.z), bfu(r.w));
}

__device__ __forceinline__ void store_f4(float* p, const float4& f) {
    *(float4*)p = f;
}
__device__ __forceinline__ void store_f4(bf16* p, const float4& f) {
    ushort4 u = {bfbits(f.x), bfbits(f.y), bfbits(f.z), bfbits(f.w)};
    *(ushort4*)p = u;
}

__device__ __forceinline__ bf16x8 ld8(const bf16* p) { return *(const bf16x8*)p; }
__device__ __forceinline__ bf16x8 ld8(const float* p) {
    const float4 f0 = *(const float4*)p;
    const float4 f1 = *(const float4*)(p + 4);
    bf16x8 r;
    r[0] = (__bf16)f0.x; r[1] = (__bf16)f0.y; r[2] = (__bf16)f0.z; r[3] = (__bf16)f0.w;
    r[4] = (__bf16)f1.x; r[5] = (__bf16)f1.y; r[6] = (__bf16)f1.z; r[7] = (__bf16)f1.w;
    return r;
}

// async global->LDS, 16 B per lane; LDS dest = wave-uniform base + lane*16
__device__ __forceinline__ void async_copy16(const void* g, void* l) {
    __builtin_amdgcn_global_load_lds(
        (const __attribute__((address_space(1))) unsigned int*)g,
        (__attribute__((address_space(3))) unsigned int*)l, 16, 0, 0);
}

// XCD-grouped m-tile remap for 128-tile grids (16 tiles per XCD): tile t ->
// contiguous row range per XCD, matching attn's node partition.
__device__ __forceinline__ int xcd_mtile(int t) {
    return (t & 7) * 16 + (t >> 3);
}

// ---------------------------------------------------------------------------
// Batched weight transpose: out[midx][n][k] = (bf16) src[midx][k][n]
// midx: 0=rw1 1=rw2 2=rw3 3=aw2, then per layer l: 4+5l+{0:q,1:k,2:v,3:e,4:o}
// K/V weight rows interleaved (R15-verified correct): k col c ->
// 256+(c>>2)*8+(c&3), v col c -> 256+(c>>2)*8+4+(c&3).
// Slots 34..39 are the combined rw3@We weights (filled by combine_w3e).
// ---------------------------------------------------------------------------
__global__ __launch_bounds__(256) void transpose_weights(
    const float* __restrict__ rw1, const float* __restrict__ rw2,
    const float* __restrict__ rw3, const float* __restrict__ aw2,
    const float* __restrict__ Wq, const float* __restrict__ Wk,
    const float* __restrict__ Wv, const float* __restrict__ We,
    const float* __restrict__ Wo, __bf16* __restrict__ out)
{
    __shared__ float tile[64][65];
    const int midx = blockIdx.y;
    const float* src;
    int fam = 0, s = 0;
    if (midx == 0) src = rw1;
    else if (midx == 1) src = rw2;
    else if (midx == 2) src = rw3;
    else if (midx == 3) src = aw2;
    else {
        fam = (midx - 4) / 5; s = (midx - 4) % 5;
        const float* bases[5] = {Wq, Wk, Wv, We, Wo};
        src = bases[s] + (size_t)fam * 65536;
    }
    const bool isqkv = (midx >= 4) && (s < 3);
    __bf16* dstb = isqkv ? (out + (size_t)(4 + 5 * fam) * 65536)
                         : (out + (size_t)midx * 65536);
    const int k0 = (blockIdx.x >> 2) * 64;
    const int n0 = (blockIdx.x & 3) * 64;
    const int c = threadIdx.x & 63;
    const int r0 = threadIdx.x >> 6;
#pragma unroll
    for (int p = 0; p < 16; ++p) {
        const int r = r0 + p * 4;
        tile[r][c] = src[(size_t)(k0 + r) * 256 + n0 + c];
    }
    __syncthreads();
#pragma unroll
    for (int p = 0; p < 16; ++p) {
        const int n = r0 + p * 4;
        const int gr = n0 + n;
        int row = gr;
        if (isqkv) {
            if (s == 1)      row = 256 + ((gr >> 2) << 3) + (gr & 3);
            else if (s == 2) row = 256 + ((gr >> 2) << 3) + 4 + (gr & 3);
        }
        dstb[(size_t)row * 256 + k0 + c] = (__bf16)tile[c][n];
    }
}

// pack per-layer [bq|bk-interleaved-bv] -> qkvb[l*768 + ...]
__global__ __launch_bounds__(256) void pack_qkv_bias(
    const float* __restrict__ bq, const float* __restrict__ bk,
    const float* __restrict__ bv, float* __restrict__ out)
{
    const int i = blockIdx.x * 256 + threadIdx.x;
    if (i >= LL * 768) return;
    const int l = i / 768, r = i % 768;
    float val; int pos;
    if (r < 256)      { val = bq[l * 256 + r];        pos = r; }
    else if (r < 512) { const int c = r - 256; val = bk[l * 256 + c];
                        pos = 256 + ((c >> 2) << 3) + (c & 3); }
    else              { const int c = r - 512; val = bv[l * 256 + c];
                        pos = 256 + ((c >> 2) << 3) + 4 + (c & 3); }
    out[l * 768 + pos] = val;
}

// ---------------------------------------------------------------------------
// combine_w3e: Wt_out[l][n][k] = bf16( sum_m rw3[k][m] * We[l][m][n] )
// ---------------------------------------------------------------------------
__global__ __launch_bounds__(256) void combine_w3e(
    const float* __restrict__ rw3, const float* __restrict__ We,
    __bf16* __restrict__ Wt_out)
{
    __shared__ float As[16][65];
    __shared__ float Ws[16][65];
    const int l = blockIdx.z;
    const float* W = We + (size_t)l * 65536;
    __bf16* dst = Wt_out + (size_t)l * 65536;
    const int m0 = blockIdx.x * 64;   // k index of combined weight
    const int n0 = blockIdx.y * 64;
    const int tid = threadIdx.x;
    const int tx = tid & 15, ty = tid >> 4;
    float acc[4][4] = {};

    for (int k0 = 0; k0 < 256; k0 += 16) {
        {
            const int ar = tid >> 2;
            const int ac = (tid & 3) * 4;
#pragma unroll
            for (int j = 0; j < 4; ++j)
                As[ac + j][ar] = rw3[(size_t)(m0 + ar) * 256 + k0 + ac + j];
        }
        {
            const int wr = tid >> 4;
            const int wc = (tid & 15) * 4;
#pragma unroll
            for (int j = 0; j < 4; ++j)
                Ws[wr][wc + j] = W[(size_t)(k0 + wr) * 256 + n0 + wc + j];
        }
        __syncthreads();
#pragma unroll
        for (int kk = 0; kk < 16; ++kk) {
            float a[4], b[4];
#pragma unroll
            for (int i = 0; i < 4; ++i) a[i] = As[kk][ty * 4 + i];
#pragma unroll
            for (int j = 0; j < 4; ++j) b[j] = Ws[kk][tx * 4 + j];
#pragma unroll
            for (int i = 0; i < 4; ++i)
#pragma unroll
                for (int j = 0; j < 4; ++j) acc[i][j] += a[i] * b[j];
        }
        __syncthreads();
    }
#pragma unroll
    for (int i = 0; i < 4; ++i) {
        const int gk = m0 + ty * 4 + i;
#pragma unroll
        for (int j = 0; j < 4; ++j) {
            const int gn = n0 + tx * 4 + j;
            dst[(size_t)gn * 256 + gk] = (__bf16)acc[i][j];  // transposed store
        }
    }
}

// be_c[l][n] = sum_m rb3[m] * We[l][m][n] + be[l][n]
__global__ __launch_bounds__(256) void combine_bias(
    const float* __restrict__ rb3, const float* __restrict__ We,
    const float* __restrict__ be, float* __restrict__ out)
{
    const int l = blockIdx.x;
    const int n = threadIdx.x;
    const float* W = We + (size_t)l * 65536;
    float s = be[l * 256 + n];
    for (int m = 0; m < 256; ++m) s += rb3[m] * W[m * 256 + n];
    out[l * 256 + n] = s;
}

// ---------------------------------------------------------------------------
// Fused MFMA GEMM + LayerNorm + SiLU: C = silu(LN(A@W + bias)), Nn=K=256.
// 64x256 tile, both-sides XOR-swizzle, 4 blocks/CU. Coalesced LDS epilogue.
// ---------------------------------------------------------------------------
__global__ __launch_bounds__(256) void mfma_gemm_ln(
    const bf16* __restrict__ A, const __bf16* __restrict__ Wt,
    const float* __restrict__ bias, const float* __restrict__ g,
    const float* __restrict__ b, bf16* __restrict__ C, int do_silu)
{
    __shared__ __align__(16) __bf16 As[64 * 64];
    __shared__ __align__(16) __bf16 Bs[256 * 64];
    const int tid = threadIdx.x;
    const int m0 = blockIdx.x * 64;
    const int wave = tid >> 6, lane = tid & 63;
    const int lm = lane & 15, lq = lane >> 4;
    const int lrow = lane >> 3;
    const int lcolsw = ((lane & 7) ^ lrow) * 8;   // pre-swizzled source col-group

    f32x4 acc[16] = {};

    for (int k0 = 0; k0 < 256; k0 += 64) {
#pragma unroll
        for (int p = 0; p < 2; ++p) {
            const int rbase = wave * 16 + p * 8;   // multiple of 8 -> row&7 == lrow
            async_copy16(A + (size_t)(m0 + rbase + lrow) * 256 + k0 + lcolsw,
                         As + rbase * 64);
        }
#pragma unroll
        for (int p = 0; p < 8; ++p) {
            const int rbase = wave * 64 + p * 8;
            async_copy16(Wt + (size_t)(rbase + lrow) * 256 + k0 + lcolsw,
                         Bs + rbase * 64);
        }
        __syncthreads();
#pragma unroll
        for (int ks = 0; ks < 2; ++ks) {
            const int sw = ((ks * 4 + lq) ^ (lm & 7)) * 8;  // swizzled read slot
            const bf16x8 a = *(const bf16x8*)(As + (wave * 16 + lm) * 64 + sw);
#pragma unroll
            for (int j = 0; j < 16; ++j) {
                const bf16x8 bf = *(const bf16x8*)(Bs + (j * 16 + lm) * 64 + sw);
                acc[j] = __builtin_amdgcn_mfma_f32_16x16x32_bf16(a, bf, acc[j], 0, 0, 0);
            }
        }
        __syncthreads();
    }

    float gg[16], bb[16];
#pragma unroll
    for (int j = 0; j < 16; ++j) {
        const float bv = bias[j * 16 + lm];
        gg[j] = g[j * 16 + lm];
        bb[j] = b[j * 16 + lm];
#pragma unroll
        for (int r = 0; r < 4; ++r) acc[j][r] += bv;
    }

    // each lane holds 4 rows (lq*4+r) x 16 cols (j*16+lm); lanes sharing a row
    // differ only in low-4 bits -> shfl_xor reduce over lm. Results staged to
    // Bs (reused as [64][256] bf16), then one contiguous coalesced write.
#pragma unroll
    for (int r = 0; r < 4; ++r) {
        float s = 0.f, q = 0.f;
#pragma unroll
        for (int j = 0; j < 16; ++j) { const float v = acc[j][r]; s += v; q += v * v; }
#pragma unroll
        for (int msk = 1; msk < 16; msk <<= 1) {
            s += __shfl_xor(s, msk);
            q += __shfl_xor(q, msk);
        }
        const float mean = s * (1.f / 256.f);
        const float var = q * (1.f / 256.f) - mean * mean;
        const float rs = rsqrtf(var + 1e-5f);
        __bf16* erow = Bs + (wave * 16 + lq * 4 + r) * 256;
#pragma unroll
        for (int j = 0; j < 16; ++j) {
            float v = (acc[j][r] - mean) * rs * gg[j] + bb[j];
            if (do_silu) v = v / (1.f + __expf(-v));
            erow[j * 16 + lm] = (__bf16)v;
        }
    }
    __syncthreads();
    {
        __bf16* cbase = (__bf16*)C + (size_t)m0 * 256;   // tile is contiguous
#pragma unroll
        for (int p = 0; p < 8; ++p) {
            const int ofs = (tid + p * 256) * 8;
            *(bf16x8*)(cbase + ofs) = *(const bf16x8*)(Bs + ofs);
        }
    }
}

// ---------------------------------------------------------------------------
// ln1 variant: A = RBF matrix generated ON THE FLY from d_csr (one scalar
// per row) directly into the swizzled LDS slots (R12-verified).
// ---------------------------------------------------------------------------
__global__ __launch_bounds__(256) void mfma_gemm_ln_rbf(
    const float* __restrict__ dcsr, const __bf16* __restrict__ Wt,
    const float* __restrict__ bias, const float* __restrict__ g,
    const float* __restrict__ b, bf16* __restrict__ C)
{
    __shared__ __align__(16) __bf16 As[64 * 64];
    __shared__ __align__(16) __bf16 Bs[256 * 64];
    const int tid = threadIdx.x;
    const int m0 = blockIdx.x * 64;
    const int wave = tid >> 6, lane = tid & 63;
    const int lm = lane & 15, lq = lane >> 4;
    const int lrow = lane >> 3;
    const int lcolsw = ((lane & 7) ^ lrow) * 8;

    const float step = 8.0f / 255.0f;
    const float gamma = 1.0f / (step * step);

    float dv[2];
#pragma unroll
    for (int p = 0; p < 2; ++p)
        dv[p] = dcsr[m0 + wave * 16 + p * 8 + lrow];

    f32x4 acc[16] = {};

    for (int k0 = 0; k0 < 256; k0 += 64) {
#pragma unroll
        for (int p = 0; p < 2; ++p) {
            const int r = wave * 16 + p * 8 + lrow;
            __bf16* dst8 = As + r * 64 + (lane & 7) * 8;
            const int cbase = k0 + lcolsw;
#pragma unroll
            for (int j = 0; j < 8; ++j) {
                const float t = dv[p] - (float)(cbase + j) * step;
                dst8[j] = (__bf16)__expf(-gamma * t * t);
            }
        }
#pragma unroll
        for (int p = 0; p < 8; ++p) {
            const int rbase = wave * 64 + p * 8;
            async_copy16(Wt + (size_t)(rbase + lrow) * 256 + k0 + lcolsw,
                         Bs + rbase * 64);
        }
        __syncthreads();
#pragma unroll
        for (int ks = 0; ks < 2; ++ks) {
            const int sw = ((ks * 4 + lq) ^ (lm & 7)) * 8;
            const bf16x8 a = *(const bf16x8*)(As + (wave * 16 + lm) * 64 + sw);
#pragma unroll
            for (int j = 0; j < 16; ++j) {
                const bf16x8 bf = *(const bf16x8*)(Bs + (j * 16 + lm) * 64 + sw);
                acc[j] = __builtin_amdgcn_mfma_f32_16x16x32_bf16(a, bf, acc[j], 0, 0, 0);
            }
        }
        __syncthreads();
    }

    float gg[16], bb[16];
#pragma unroll
    for (int j = 0; j < 16; ++j) {
        const float bv = bias[j * 16 + lm];
        gg[j] = g[j * 16 + lm];
        bb[j] = b[j * 16 + lm];
#pragma unroll
        for (int r = 0; r < 4; ++r) acc[j][r] += bv;
    }

#pragma unroll
    for (int r = 0; r < 4; ++r) {
        float s = 0.f, q = 0.f;
#pragma unroll
        for (int j = 0; j < 16; ++j) { const float v = acc[j][r]; s += v; q += v * v; }
#pragma unroll
        for (int msk = 1; msk < 16; msk <<= 1) {
            s += __shfl_xor(s, msk);
            q += __shfl_xor(q, msk);
        }
        const float mean = s * (1.f / 256.f);
        const float var = q * (1.f / 256.f) - mean * mean;
        const float rs = rsqrtf(var + 1e-5f);
        __bf16* erow = Bs + (wave * 16 + lq * 4 + r) * 256;
#pragma unroll
        for (int j = 0; j < 16; ++j) {
            float v = (acc[j][r] - mean) * rs * gg[j] + bb[j];
            v = v / (1.f + __expf(-v));   // silu (always on for ln1)
            erow[j * 16 + lm] = (__bf16)v;
        }
    }
    __syncthreads();
    {
        __bf16* cbase = (__bf16*)C + (size_t)m0 * 256;
#pragma unroll
        for (int p = 0; p < 8; ++p) {
            const int ofs = (tid + p * 256) * 8;
            *(bf16x8*)(cbase + ofs) = *(const bf16x8*)(Bs + ofs);
        }
    }
}

// ---------------------------------------------------------------------------
// Fused out-projection: node = LN(A@Wt + bias; g,b) + node (residual, fp32
// in-place). A bf16 (msg). 64x256 tile.
// R18: XCD-grouped m-tile (matches attn's msg-write locality: XCD k owns
// rows [k*1024, (k+1)*1024)).
// ---------------------------------------------------------------------------
__global__ __launch_bounds__(256) void mfma_gemm_ln_res(
    const bf16* __restrict__ A, const __bf16* __restrict__ Wt,
    const float* __restrict__ bias, const float* __restrict__ g,
    const float* __restrict__ b, float* __restrict__ node)
{
    __shared__ __align__(16) __bf16 As[64 * 72];   // padded: 2-way max (free)
    __shared__ __align__(16) __bf16 Bs[256 * 64];
    const int tid = threadIdx.x;
    const int m0 = xcd_mtile(blockIdx.x) * 64;
    const int wave = tid >> 6, lane = tid & 63;
    const int lm = lane & 15, lq = lane >> 4;
    const int lrow = lane >> 3;
    const int lcolsw = ((lane & 7) ^ lrow) * 8;

    f32x4 acc[16] = {};
    const int srow = tid >> 3;          // 0..31
    const int scol = (tid & 7) * 8;

    for (int k0 = 0; k0 < 256; k0 += 64) {
#pragma unroll
        for (int p = 0; p < 2; ++p) {
            const int r = srow + 32 * p;
            *(bf16x8*)(As + r * 72 + scol) = ld8(A + (size_t)(m0 + r) * 256 + k0 + scol);
        }
#pragma unroll
        for (int p = 0; p < 8; ++p) {
            const int rbase = wave * 64 + p * 8;   // multiple of 8 -> row&7 == lrow
            async_copy16(Wt + (size_t)(rbase + lrow) * 256 + k0 + lcolsw,
                         Bs + rbase * 64);
        }
        __syncthreads();
#pragma unroll
        for (int ks = 0; ks < 2; ++ks) {
            const int sw = ((ks * 4 + lq) ^ (lm & 7)) * 8;
            const bf16x8 a = *(const bf16x8*)(As + (wave * 16 + lm) * 72 + ks * 32 + lq * 8);
#pragma unroll
            for (int j = 0; j < 16; ++j) {
                const bf16x8 bf = *(const bf16x8*)(Bs + (j * 16 + lm) * 64 + sw);
                acc[j] = __builtin_amdgcn_mfma_f32_16x16x32_bf16(a, bf, acc[j], 0, 0, 0);
            }
        }
        __syncthreads();
    }

    float gg[16], bb[16];
#pragma unroll
    for (int j = 0; j < 16; ++j) {
        const float bv = bias[j * 16 + lm];
        gg[j] = g[j * 16 + lm];
        bb[j] = b[j * 16 + lm];
#pragma unroll
        for (int r = 0; r < 4; ++r) acc[j][r] += bv;
    }

#pragma unroll
    for (int r = 0; r < 4; ++r) {
        float s = 0.f, q = 0.f;
#pragma unroll
        for (int j = 0; j < 16; ++j) { const float v = acc[j][r]; s += v; q += v * v; }
#pragma unroll
        for (int msk = 1; msk < 16; msk <<= 1) {
            s += __shfl_xor(s, msk);
            q += __shfl_xor(q, msk);
        }
        const float mean = s * (1.f / 256.f);
        const float var = q * (1.f / 256.f) - mean * mean;
        const float rs = rsqrtf(var + 1e-5f);
        float* crow = node + (size_t)(m0 + wave * 16 + lq * 4 + r) * 256;
#pragma unroll
        for (int j = 0; j < 16; ++j) {
            const float v = (acc[j][r] - mean) * rs * gg[j] + bb[j];
            crow[j * 16 + lm] += v;   // node = LN(...) + node_old (one lane per elem)
        }
    }
}

// ---------------------------------------------------------------------------
// GRID-FUSED ee GEMM + qkv GEMM (one dispatch, R16-verified): blocks <
// nblk_ee run the ee path; remaining 768 run the 64x128 qkv GEMM.
// R18: qkv role m-tile XCD-grouped (writes land in consumer attn's XCD L2).
// ---------------------------------------------------------------------------
__global__ __launch_bounds__(256) void ee_qkv_fused(
    const bf16* __restrict__ A, const __bf16* __restrict__ Wte,
    const float* __restrict__ biase, bf16* __restrict__ Ce,
    int M, int Nn, int K, int nblk_ee,
    const float* __restrict__ nodeA, const __bf16* __restrict__ Wtq,
    const float* __restrict__ biasq, bf16* __restrict__ Cq)
{
    __shared__ __align__(16) __bf16 smem[128 * 128];   // 32 KB, aliased by both roles
    const int tid = threadIdx.x;
    const int wave = tid >> 6, lane = tid & 63;
    const int lm = lane & 15, lq = lane >> 4;

    if ((int)blockIdx.x < nblk_ee) {
        // ---------------- ee role (identical to mfma_gemm_ee) ----------------
        __bf16* As = smem;              // [128][64]
        __bf16* Bs = smem + 128 * 64;   // [128][64]
        const int nt_n = Nn >> 7;
        const int xcd = blockIdx.x & 7;
        const int local = blockIdx.x >> 3;
        const int per_xcd = (M >> 7) >> 3;
        const int m0 = (xcd * per_xcd + local / nt_n) * 128;
        const int n0 = (local % nt_n) * 128;

        const int wm = (wave & 1) * 64, wn = (wave >> 1) * 64;
        const int lrow = lane >> 3;
        const int lcolsw = ((lane & 7) ^ lrow) * 8;

        f32x4 acc[4][4] = {};

        for (int k0 = 0; k0 < K; k0 += 64) {
#pragma unroll
            for (int p = 0; p < 4; ++p) {
                const int rbase = wave * 32 + p * 8;
                async_copy16(A   + (size_t)(m0 + rbase + lrow) * K + k0 + lcolsw,
                             As + rbase * 64);
                async_copy16(Wte + (size_t)(n0 + rbase + lrow) * K + k0 + lcolsw,
                             Bs + rbase * 64);
            }
            __syncthreads();
#pragma unroll
            for (int ks = 0; ks < 2; ++ks) {
                const int sw = ((ks * 4 + lq) ^ (lm & 7)) * 8;
                bf16x8 a[4], b[4];
#pragma unroll
                for (int i = 0; i < 4; ++i) {
                    a[i] = *(const bf16x8*)(As + (wm + i * 16 + lm) * 64 + sw);
                    b[i] = *(const bf16x8*)(Bs + (wn + i * 16 + lm) * 64 + sw);
                }
#pragma unroll
                for (int i = 0; i < 4; ++i)
#pragma unroll
                    for (int j = 0; j < 4; ++j)
                        acc[i][j] = __builtin_amdgcn_mfma_f32_16x16x32_bf16(
                            a[i], b[j], acc[i][j], 0, 0, 0);
            }
            __syncthreads();
        }

#pragma unroll
        for (int i = 0; i < 4; ++i) {
            const int rl = wm + i * 16 + lq * 4;
#pragma unroll
            for (int j = 0; j < 4; ++j) {
                const int cl = wn + j * 16 + lm;
                const float bb = biase ? biase[n0 + cl] : 0.f;
#pragma unroll
                for (int r = 0; r < 4; ++r) {
                    const int row = rl + r;
                    smem[row * 128 + (cl ^ ((row & 7) << 3))] =
                        (__bf16)(acc[i][j][r] + bb);
                }
            }
        }
        __syncthreads();
#pragma unroll
        for (int p = 0; p < 8; ++p) {
            const int ch = tid + p * 256;
            const int row = ch >> 4;
            const int gcol = ch & 15;
            const int sg = gcol ^ (row & 7);
            *(bf16x8*)((__bf16*)Ce + (size_t)(m0 + row) * Nn + n0 + gcol * 8) =
                *(const bf16x8*)(smem + row * 128 + sg * 8);
        }
    } else {
        // ---------------- qkv role (identical to mfma_gemm64) ----------------
        const int bq = blockIdx.x - nblk_ee;        // 0..767
        const int m0 = xcd_mtile(bq % (NN / 64)) * 64;
        const int n0 = (bq / (NN / 64)) * 128;
        __bf16* As = smem;                 // [64][72]
        __bf16* Bs = smem + 64 * 72;       // [128][72]  (total 27648 B < 32768)

        const int wm = (wave & 1) * 32, wn = (wave >> 1) * 64;
        f32x4 acc[2][4] = {};
        const int srow = tid >> 3;
        const int scol = (tid & 7) * 8;

        for (int k0 = 0; k0 < 256; k0 += 64) {
#pragma unroll
            for (int p = 0; p < 2; ++p) {
                const int r = srow + 32 * p;
                *(bf16x8*)(As + r * 72 + scol) =
                    ld8(nodeA + (size_t)(m0 + r) * 256 + k0 + scol);
            }
#pragma unroll
            for (int p = 0; p < 4; ++p) {
                const int r = srow + 32 * p;
                *(bf16x8*)(Bs + r * 72 + scol) =
                    *(const bf16x8*)(Wtq + (size_t)(n0 + r) * 256 + k0 + scol);
            }
            __syncthreads();
#pragma unroll
            for (int ks = 0; ks < 2; ++ks) {
                bf16x8 a[2], b[4];
#pragma unroll
                for (int i = 0; i < 2; ++i)
                    a[i] = *(const bf16x8*)(As + (wm + i * 16 + lm) * 72 + ks * 32 + lq * 8);
#pragma unroll
                for (int j = 0; j < 4; ++j)
                    b[j] = *(const bf16x8*)(Bs + (wn + j * 16 + lm) * 72 + ks * 32 + lq * 8);
#pragma unroll
                for (int i = 0; i < 2; ++i)
#pragma unroll
                    for (int j = 0; j < 4; ++j)
                        acc[i][j] = __builtin_amdgcn_mfma_f32_16x16x32_bf16(
                            a[i], b[j], acc[i][j], 0, 0, 0);
            }
            __syncthreads();
        }

#pragma unroll
        for (int i = 0; i < 2; ++i) {
            const int gm = m0 + wm + i * 16 + lq * 4;
#pragma unroll
            for (int j = 0; j < 4; ++j) {
                const int gn = n0 + wn + j * 16 + lm;
                const float bv = biasq[gn];
#pragma unroll
                for (int r = 0; r < 4; ++r)
                    store_v(&Cq[(size_t)(gm + r) * 768 + gn], acc[i][j][r] + bv);
            }
        }
    }
}

// ---------------------------------------------------------------------------
// MFMA GEMM, 64x128 tile (fp32 A, register-staged): C = A@Wt + bias.
// (R14-verified; used for atom aw2 and odd-layer qkv.)
// R18: m-tile XCD-grouped when (M/64)%8==0 (always true here: M=NN).
// ---------------------------------------------------------------------------
template <typename CT>
__global__ __launch_bounds__(256) void mfma_gemm64(
    const float* __restrict__ A, const __bf16* __restrict__ Wt,
    const float* __restrict__ bias, CT* __restrict__ C,
    int M, int Nn, int K)
{
    __shared__ __align__(16) __bf16 As[64 * 72];
    __shared__ __align__(16) __bf16 Bs[128 * 72];
    const int tid = threadIdx.x;
    const int nmt = M / 64;
    const int m0 = ((nmt & 7) == 0 ? ((blockIdx.x & 7) * (nmt >> 3) + (blockIdx.x >> 3))
                                   : blockIdx.x) * 64;
    const int n0 = blockIdx.y * 128;
    const int wave = tid >> 6, lane = tid & 63;
    const int wm = (wave & 1) * 32, wn = (wave >> 1) * 64;
    const int lm = lane & 15, lq = lane >> 4;

    f32x4 acc[2][4] = {};

    const int srow = tid >> 3;          // 0..31
    const int scol = (tid & 7) * 8;

    for (int k0 = 0; k0 < K; k0 += 64) {
#pragma unroll
        for (int p = 0; p < 2; ++p) {
            const int r = srow + 32 * p;
            *(bf16x8*)(As + r * 72 + scol) =
                ld8(A + (size_t)(m0 + r) * K + k0 + scol);
        }
#pragma unroll
        for (int p = 0; p < 4; ++p) {
            const int r = srow + 32 * p;
            *(bf16x8*)(Bs + r * 72 + scol) =
                *(const bf16x8*)(Wt + (size_t)(n0 + r) * K + k0 + scol);
        }
        __syncthreads();
#pragma unroll
        for (int ks = 0; ks < 2; ++ks) {
            bf16x8 a[2], b[4];
#pragma unroll
            for (int i = 0; i < 2; ++i)
                a[i] = *(const bf16x8*)(As + (wm + i * 16 + lm) * 72 + ks * 32 + lq * 8);
#pragma unroll
            for (int j = 0; j < 4; ++j)
                b[j] = *(const bf16x8*)(Bs + (wn + j * 16 + lm) * 72 + ks * 32 + lq * 8);
#pragma unroll
            for (int i = 0; i < 2; ++i)
#pragma unroll
                for (int j = 0; j < 4; ++j)
                    acc[i][j] = __builtin_amdgcn_mfma_f32_16x16x32_bf16(
                        a[i], b[j], acc[i][j], 0, 0, 0);
        }
        __syncthreads();
    }

#pragma unroll
    for (int i = 0; i < 2; ++i) {
        const int gm = m0 + wm + i * 16 + lq * 4;
#pragma unroll
        for (int j = 0; j < 4; ++j) {
            const int gn = n0 + wn + j * 16 + lm;
            const float bv = bias ? bias[gn] : 0.f;
#pragma unroll
            for (int r = 0; r < 4; ++r)
                store_v(&C[(size_t)(gm + r) * Nn + gn], acc[i][j][r] + bv);
        }
    }
}

// ---------------------------------------------------------------------------
// Fallback vector GEMM (K=92 aw1, fc head). Optional cntdiv: A-row gm is
// divided by max(cnt[gm],1) on load (fuses the pooled-mean division).
// ---------------------------------------------------------------------------
template <typename AT, typename CT>
__global__ __launch_bounds__(256) void gemm_bias(
    const AT* __restrict__ A, const float* __restrict__ W,
    const float* __restrict__ bias, CT* __restrict__ C,
    int M, int Nn, int K, const float* __restrict__ cntdiv)
{
    __shared__ float As[16][65];
    __shared__ float Ws[16][65];
    const int m0 = blockIdx.x * 64;
    const int n0 = blockIdx.y * 64;
    const int tid = threadIdx.x;
    const int tx = tid & 15, ty = tid >> 4;
    float acc[4][4] = {};

    for (int k0 = 0; k0 < K; k0 += 16) {
        {
            const int ar = tid >> 2;
            const int ac = (tid & 3) * 4;
            const int gm = m0 + ar;
            float inv = 1.f;
            if (cntdiv && gm < M) {
                float cc = cntdiv[gm];
                if (cc < 1.f) cc = 1.f;
                inv = 1.f / cc;
            }
#pragma unroll
            for (int j = 0; j < 4; ++j) {
                const int gk = k0 + ac + j;
                float v = 0.f;
                if (gm < M && gk < K) v = to_f(A[(size_t)gm * K + gk]) * inv;
                As[ac + j][ar] = v;
            }
        }
        {
            const int wr = tid >> 4;
            const int wc = (tid & 15) * 4;
            const int gk = k0 + wr;
#pragma unroll
            for (int j = 0; j < 4; ++j) {
                float v = 0.f;
                if (gk < K) v = W[(size_t)gk * Nn + n0 + wc + j];
                Ws[wr][wc + j] = v;
            }
        }
        __syncthreads();
#pragma unroll
        for (int kk = 0; kk < 16; ++kk) {
            float a[4], b[4];
#pragma unroll
            for (int i = 0; i < 4; ++i) a[i] = As[kk][ty * 4 + i];
#pragma unroll
            for (int j = 0; j < 4; ++j) b[j] = Ws[kk][tx * 4 + j];
#pragma unroll
            for (int i = 0; i < 4; ++i)
#pragma unroll
                for (int j = 0; j < 4; ++j) acc[i][j] += a[i] * b[j];
        }
        __syncthreads();
    }
#pragma unroll
    for (int i = 0; i < 4; ++i) {
        const int gm = m0 + ty * 4 + i;
        if (gm >= M) continue;
#pragma unroll
        for (int j = 0; j < 4; ++j) {
            const int gn = n0 + tx * 4 + j;
            float v = acc[i][j];
            if (bias) v += bias[gn];
            store_v(&C[(size_t)gm * Nn + gn], v);
        }
    }
}

// ---------------------------------------------------------------------------
// Row LayerNorm (+opt SiLU via __expf, +opt fp32 residual). Node-side only.
// ---------------------------------------------------------------------------
template <typename XT, typename YT>
__global__ __launch_bounds__(256) void ln_act_kernel(
    const XT* __restrict__ X, YT* __restrict__ Y,
    const float* __restrict__ g, const float* __restrict__ b,
    const float* __restrict__ resid, int rows, int do_silu)
{
    const int wave = threadIdx.x >> 6;
    const int lane = threadIdx.x & 63;
    const int r = blockIdx.x * 4 + wave;
    if (r >= rows) return;
    const float4 x = load4(X + (size_t)r * DD + lane * 4);
    float s = x.x + x.y + x.z + x.w;
    float q = x.x * x.x + x.y * x.y + x.z * x.z + x.w * x.w;
    for (int off = 32; off; off >>= 1) {
        s += __shfl_down(s, off);
        q += __shfl_down(q, off);
    }
    s = __shfl(s, 0);
    q = __shfl(q, 0);
    const float mean = s * (1.f / 256.f);
    const float var = q * (1.f / 256.f) - mean * mean;
    const float rs = rsqrtf(var + 1e-5f);
    const int c = lane * 4;
    float xs[4] = {x.x, x.y, x.z, x.w};
    float out[4];
#pragma unroll
    for (int i = 0; i < 4; ++i) {
        float v = (xs[i] - mean) * rs * g[c + i] + b[c + i];
        if (do_silu) v = v / (1.f + __expf(-v));
        out[i] = v;
    }
    if (resid) {
        const float4 rv = load4(resid + (size_t)r * DD + c);
        out[0] += rv.x; out[1] += rv.y; out[2] += rv.z; out[3] += rv.w;
    }
    store_f4(Y + (size_t)r * DD + c, make_float4(out[0], out[1], out[2], out[3]));
}

// ---------------------------------------------------------------------------
// CSR build: histogram, block-scan, fill (emits CSR-ordered src AND CSR
// edge lengths dcsr)
// ---------------------------------------------------------------------------
__global__ __launch_bounds__(256) void deg_kernel(
    const int* __restrict__ dst, int* __restrict__ deg)
{
    const int e = blockIdx.x * 256 + threadIdx.x;
    if (e < EE) atomicAdd(&deg[dst[e]], 1);
}

__global__ __launch_bounds__(256) void csr_scan(
    const int* __restrict__ deg, int* __restrict__ rowptr)
{
    __shared__ int part[256];
    const int t = threadIdx.x;
    int local[32];
    int s = 0;
#pragma unroll
    for (int i = 0; i < 32; ++i) { local[i] = deg[t * 32 + i]; s += local[i]; }
    part[t] = s;
    __syncthreads();
    if (t == 0) {
        int run = 0;
        for (int i = 0; i < 256; ++i) { const int v = part[i]; part[i] = run; run += v; }
    }
    __syncthreads();
    int run = part[t];
#pragma unroll
    for (int i = 0; i < 32; ++i) { rowptr[t * 32 + i] = run; run += local[i]; }
    if (t == 255) rowptr[NN] = run;
}

__global__ __launch_bounds__(256) void fill_kernel(
    const int* __restrict__ src, const int* __restrict__ dst,
    const float* __restrict__ ea, const int* __restrict__ rowptr,
    int* __restrict__ fill, int* __restrict__ eid,
    int* __restrict__ srcc, float* __restrict__ dcsr)
{
    const int e = blockIdx.x * 256 + threadIdx.x;
    if (e >= EE) return;
    const int d = dst[e];
    const int pos = atomicAdd(&fill[d], 1);
    const int q = rowptr[d] + pos;
    eid[q] = e;
    srcc[q] = src[e];
    const float ax = ea[e * 3 + 0];
    const float ay = ea[e * 3 + 1];
    const float az = ea[e * 3 + 2];
    dcsr[q] = sqrtf(ax * ax + ay * ay + az * az);
}

// ---------------------------------------------------------------------------
// Single-pass fused attention (flash-style online softmax), no atomics.
// CSR-ordered ee (sequential), 4 waves/node (R10-verified), packed 16B K|V
// gather (R15), bf16 msg output (R16), XCD-grouped node mapping (R17: -8us).
// ---------------------------------------------------------------------------
__global__ __launch_bounds__(256) void attn_kernel(
    const bf16* __restrict__ qkv, const bf16* __restrict__ ee, int estride,
    const int* __restrict__ rowptr, const int* __restrict__ srcc,
    bf16* __restrict__ msg)
{
    const int n = (blockIdx.x & 7) * (NN / 8) + (blockIdx.x >> 3);
    const int tid = threadIdx.x;
    const int wave = tid >> 6, lane = tid & 63;
    const int e0 = rowptr[n];
    const int deg = rowptr[n + 1] - e0;

    if (deg == 0) {  // uniform branch
        store_v(&msg[(size_t)n * DD + tid], 0.f);
        return;
    }

    __shared__ float wm[4][HH];
    __shared__ float wl[4][HH];
    __shared__ float wacc[4][DD];

    const float4 qreg = load4(qkv + (size_t)n * 768 + lane * 4);

    float m = -3.402823466e38f, l = 0.f;
    float4 acc = {0.f, 0.f, 0.f, 0.f};

    int j = wave;
    bf16x8 kvp = {};                      // k[0..3]|v[0..3] packed
    float4 ev = {0.f, 0.f, 0.f, 0.f};
    if (j < deg) {
        const int e = e0 + j;
        const bf16* srow = qkv + (size_t)srcc[e] * 768;
        kvp = ld8(srow + 256 + lane * 8);
        ev = load4(ee + (size_t)e * estride + lane * 4);
    }
    while (j < deg) {
        const int jn = j + 4;
        bf16x8 kvp2 = {};
        float4 ev2 = {0.f, 0.f, 0.f, 0.f};
        if (jn < deg) {
            const int e2 = e0 + jn;
            const bf16* srow2 = qkv + (size_t)srcc[e2] * 768;
            kvp2 = ld8(srow2 + 256 + lane * 8);
            ev2 = load4(ee + (size_t)e2 * estride + lane * 4);
        }
        const float kx = (float)kvp[0], ky = (float)kvp[1];
        const float kz = (float)kvp[2], kw = (float)kvp[3];
        const float vx = (float)kvp[4], vy = (float)kvp[5];
        const float vz = (float)kvp[6], vw = (float)kvp[7];
        float p = qreg.x * (kx + ev.x) + qreg.y * (ky + ev.y) +
                  qreg.z * (kz + ev.z) + qreg.w * (kw + ev.w);
        p += __shfl_down(p, 4);
        p += __shfl_down(p, 2);
        p += __shfl_down(p, 1);
        const float s = __shfl(p, lane & 56) * 0.17677669529663687f;
        const float mnew = fmaxf(m, s);
        const float scale = __expf(m - mnew);
        const float pe = __expf(s - mnew);
        l = l * scale + pe;
        acc.x = acc.x * scale + pe * (vx + ev.x);
        acc.y = acc.y * scale + pe * (vy + ev.y);
        acc.z = acc.z * scale + pe * (vz + ev.z);
        acc.w = acc.w * scale + pe * (vw + ev.w);
        m = mnew;
        kvp = kvp2; ev = ev2;
        j = jn;
    }

    if ((lane & 7) == 0) { wm[wave][lane >> 3] = m; wl[wave][lane >> 3] = l; }
    *(float4*)(&wacc[wave][lane * 4]) = acc;
    __syncthreads();

    {
        const int c = tid, h = tid >> 5;
        float M = wm[0][h];
#pragma unroll
        for (int i = 1; i < 4; ++i) M = fmaxf(M, wm[i][h]);
        float L = 0.f, num = 0.f;
#pragma unroll
        for (int i = 0; i < 4; ++i) {
            const float sc = __expf(wm[i][h] - M);
            L += wl[i][h] * sc;
            num += wacc[i][c] * sc;
        }
        store_v(&msg[(size_t)n * DD + c], num / (L + 1e-16f));
    }
}

__global__ __launch_bounds__(256) void zero_kernel(float* __restrict__ p, int n)
{
    const int i = blockIdx.x * 256 + threadIdx.x;
    if (i < n) p[i] = 0.f;
}

__global__ __launch_bounds__(256) void pool_kernel(
    const float* __restrict__ node, const int* __restrict__ batch,
    float* __restrict__ sums, float* __restrict__ cnt)
{
    const int n = blockIdx.x;
    const int c = threadIdx.x;
    const int b = batch[n];
    atomicAdd(&sums[b * DD + c], node[(size_t)n * DD + c]);
    if (c == 0) atomicAdd(&cnt[b], 1.0f);
}

__global__ __launch_bounds__(64) void final_kernel(
    const float* __restrict__ fc, const float* __restrict__ fow,
    const float* __restrict__ fob, float* __restrict__ out)
{
    const int b = blockIdx.x;
    const int lane = threadIdx.x;
    float s = 0.f;
#pragma unroll
    for (int i = lane; i < FCD; i += 64) s += fc[(size_t)b * FCD + i] * fow[i];
    for (int off = 32; off; off >>= 1) s += __shfl_down(s, off);
    if (lane == 0) out[b] = s + fob[0];
}

// ---------------------------------------------------------------------------
extern "C" void kernel_launch(void* const* d_in, const int* in_sizes, int n_in,
                              void* d_out, int out_size, void* d_ws,
                              size_t ws_size, hipStream_t stream)
{
    const float* x         = (const float*)d_in[0];
    const float* edge_attr = (const float*)d_in[1];
    const int*   eidx      = (const int*)d_in[2];
    const int*   batch     = (const int*)d_in[3];
    const float* aw1 = (const float*)d_in[4];
    const float* ab1 = (const float*)d_in[5];
    const float* ag1 = (const float*)d_in[6];
    const float* abt1 = (const float*)d_in[7];
    const float* aw2 = (const float*)d_in[8];
    const float* ab2 = (const float*)d_in[9];
    const float* rw1 = (const float*)d_in[10];
    const float* rb1 = (const float*)d_in[11];
    const float* rg1 = (const float*)d_in[12];
    const float* rbt1 = (const float*)d_in[13];
    const float* rw2 = (const float*)d_in[14];
    const float* rb2 = (const float*)d_in[15];
    const float* rg2 = (const float*)d_in[16];
    const float* rbt2 = (const float*)d_in[17];
    const float* rw3 = (const float*)d_in[18];
    const float* rb3 = (const float*)d_in[19];
    const float* Wq = (const float*)d_in[20];
    const float* bq = (const float*)d_in[21];
    const float* Wk = (const float*)d_in[22];
    const float* bk = (const float*)d_in[23];
    const float* Wv = (const float*)d_in[24];
    const float* bv = (const float*)d_in[25];
    const float* We_ = (const float*)d_in[26];
    const float* be_ = (const float*)d_in[27];
    const float* Wo = (const float*)d_in[28];
    const float* bo = (const float*)d_in[29];
    const float* lng = (const float*)d_in[30];
    const float* lnb = (const float*)d_in[31];
    const float* fw1 = (const float*)d_in[32];
    const float* fb1 = (const float*)d_in[33];
    const float* fow = (const float*)d_in[34];
    const float* fob = (const float*)d_in[35];

    const int* src = eidx;
    const int* dst = eidx + EE;

    // workspace carve-up. Fixed buffers first; the ee slab last with adaptive
    // group size G in {6,3,2,1} (ws_size ~268MB -> G=2 in practice).
    char* w = (char*)d_ws;
    size_t off = 0;
    auto alloc = [&](size_t bytes) -> void* {
        void* p = w + off;
        off += (bytes + 255) & ~(size_t)255;
        return p;
    };
    bf16* t_buf = (bf16*)alloc((size_t)EE * DD * 2);   // 64 MB — persistent edge (CSR order)
    float* node = (float*)alloc((size_t)NN * DD * 4);  // 8 MB
    bf16*  qkv  = (bf16*)alloc((size_t)NN * 768 * 2);  // 12 MB
    bf16*  msg  = (bf16*)alloc((size_t)NN * DD * 2);   // 4 MB (bf16)
    float* outb = (float*)alloc((size_t)NN * DD * 4);  // 8 MB
    int* deg    = (int*)alloc((size_t)NN * 4);         // | contiguous zero
    int* fillc  = (int*)alloc((size_t)NN * 4);         // | region (deg+fill)
    int* rowptr = (int*)alloc((size_t)(NN + 1) * 4);
    int* eid    = (int*)alloc((size_t)EE * 4);         // 512 KB
    int* srcc   = (int*)alloc((size_t)EE * 4);         // 512 KB — CSR-ordered src
    float* dcsr = (float*)alloc((size_t)EE * 4);       // 512 KB — CSR edge lengths
    float* sums  = (float*)alloc((size_t)BB * DD * 4); // | contiguous with cnt
    float* cnt   = (float*)alloc((size_t)BB * 4);      // |
    float* fc    = (float*)alloc((size_t)BB * FCD * 4);
    __bf16* Wt  = (__bf16*)alloc((size_t)40 * 65536 * 2);  // 5.25 MB (34 + 6 combined)
    float* qkvb = (float*)alloc((size_t)LL * 768 * 4);     // 18 KB
    float* be_c = (float*)alloc((size_t)LL * 256 * 4);     // 6 KB — combined ee bias

    const size_t avail = (off <= ws_size) ? ws_size - off : 0;
    int G = 1;
    if      (avail >= (size_t)EE * (6 * DD) * 2 + 256) G = 6;
    else if (avail >= (size_t)EE * (3 * DD) * 2 + 256) G = 3;
    else if (avail >= (size_t)EE * (2 * DD) * 2 + 256) G = 2;
    bf16* e_slab = (bf16*)alloc((size_t)EE * (G * DD) * 2);  // also MLP ping buffer
    (void)n_in; (void)in_sizes; (void)out_size;

    const dim3 blk(256);
    auto WT = [&](int i) -> const __bf16* { return Wt + (size_t)i * 65536; };

    // ---- one-time prep: transposes, combined rw3@We, bias pack, CSR ----
    hipLaunchKernelGGL(transpose_weights, dim3(16, 34), blk, 0, stream,
                       rw1, rw2, rw3, aw2, Wq, Wk, Wv, We_, Wo, Wt);
    hipLaunchKernelGGL(combine_w3e, dim3(4, 4, LL), blk, 0, stream, rw3, We_, Wt + (size_t)34 * 65536);
    hipLaunchKernelGGL(combine_bias, dim3(LL), blk, 0, stream, rb3, We_, be_, be_c);
    hipLaunchKernelGGL(pack_qkv_bias, dim3((LL * 768 + 255) / 256), blk, 0, stream, bq, bk, bv, qkvb);
    hipLaunchKernelGGL(zero_kernel, dim3((2 * NN + 255) / 256), blk, 0, stream, (float*)deg, 2 * NN);
    hipLaunchKernelGGL(deg_kernel, dim3(EE / 256), blk, 0, stream, dst, deg);
    hipLaunchKernelGGL(csr_scan, dim3(1), blk, 0, stream, deg, rowptr);
    hipLaunchKernelGGL(fill_kernel, dim3(EE / 256), blk, 0, stream, src, dst, edge_attr, rowptr, fillc, eid, srcc, dcsr);

    // ---- edge MLP in CSR order: d_csr -> [RBF-gen GEMM+LN+SiLU] -> [GEMM+LN+SiLU]
    hipLaunchKernelGGL(mfma_gemm_ln_rbf, dim3(EE / 64), blk, 0, stream, dcsr, WT(0), rb1, rg1, rbt1, e_slab);
    hipLaunchKernelGGL(mfma_gemm_ln, dim3(EE / 64), blk, 0, stream, e_slab, WT(1), rb2, rg2, rbt2, t_buf, 1);
    // t_buf now holds the persistent edge features (pre-rw3), CSR row order

    // ---- atom embedding: x@aw1 -> LN+SiLU -> @aw2 ----
    {
        dim3 gn64(NN / 64, DD / 64);
        hipLaunchKernelGGL((gemm_bias<float, float>), gn64, blk, 0, stream, x, aw1, ab1, outb, NN, DD, F_AT, (const float*)nullptr);
        hipLaunchKernelGGL((ln_act_kernel<float, float>), dim3(NN / 4), blk, 0, stream, outb, outb, ag1, abt1, (const float*)nullptr, NN, 1);
        hipLaunchKernelGGL((mfma_gemm64<float>), dim3(NN / 64, DD / 128), blk, 0, stream, outb, WT(3), ab2, node, NN, DD, DD);
    }

    // ---- L attention layers ----
    const int nblk_ee = (EE / 128) * ((G * DD) / 128);
    for (int l = 0; l < LL; ++l) {
        const size_t bo_ = (size_t)l * DD;
        if (l % G == 0) {
            // grid-fused: ee for layers l..l+G-1 + this layer's qkv GEMM
            hipLaunchKernelGGL(ee_qkv_fused, dim3(nblk_ee + (NN / 64) * (768 / 128)), blk, 0, stream,
                               t_buf, WT(34 + l), be_c + (size_t)l * 256, e_slab, EE, G * DD, DD, nblk_ee,
                               node, WT(4 + 5 * l), qkvb + (size_t)l * 768, qkv);
        } else {
            hipLaunchKernelGGL((mfma_gemm64<bf16>), dim3(NN / 64, 768 / 128), blk, 0, stream,
                               node, WT(4 + 5 * l), qkvb + (size_t)l * 768, qkv, NN, 768, DD);
        }
        const bf16* ee_l = e_slab + (size_t)(l % G) * DD;
        hipLaunchKernelGGL(attn_kernel, dim3(NN), blk, 0, stream, qkv, ee_l, G * DD, rowptr, srcc, msg);
        // fused: node = LN(msg@Wo + bo) + node
        hipLaunchKernelGGL(mfma_gemm_ln_res, dim3(NN / 64), blk, 0, stream,
                           msg, WT(8 + 5 * l), bo + bo_, lng + bo_, lnb + bo_, node);
    }

    // ---- pooling + FC head (pooled-mean division fused into fc GEMM) ----
    const int PZ = BB * DD + BB;
    hipLaunchKernelGGL(zero_kernel, dim3((PZ + 255) / 256), blk, 0, stream, sums, PZ);
    hipLaunchKernelGGL(pool_kernel, dim3(NN), blk, 0, stream, node, batch, sums, cnt);
    {
        dim3 gf(BB / 64, FCD / 64);
        hipLaunchKernelGGL((gemm_bias<float, float>), gf, blk, 0, stream, sums, fw1, fb1, fc, BB, FCD, DD, cnt);
    }
    hipLaunchKernelGGL(final_kernel, dim3(BB), dim3(64), 0, stream, fc, fow, fob, (float*)d_out);
}